// Round 1
// baseline (1120.561 us; speedup 1.0000x reference)
//
#include <hip/hip_runtime.h>
#include <math.h>

// ---------------- problem constants ----------------
constexpr int NN  = 65536;     // nodes (256 graphs x 256 nodes)
constexpr int EE  = 1048576;   // edges (N * 16)
constexpr int NC1 = 16384;     // clusters after pool1 (256 graphs x 64)
constexpr int NC2 = 4096;      // clusters after pool2 (256 graphs x 16)

// ---------------- workspace layout (bytes) ----------------
constexpr size_t O_SCAL = 0;                                  // m1,m2,m3 floats
constexpr size_t O_DEG1 = 256;
constexpr size_t O_CL1  = O_DEG1 + (size_t)NN*4;
constexpr size_t O_CNT1 = O_CL1  + (size_t)NN*4;
constexpr size_t O_PS1  = O_CNT1 + (size_t)NC1*4;
constexpr size_t O_XM1  = O_PS1  + (size_t)NC1*8;
constexpr size_t O_XP1  = O_XM1  + (size_t)NC1*32*4;
constexpr size_t O_POS1 = O_XP1  + (size_t)NC1*32*4;
constexpr size_t O_NV1  = O_POS1 + (size_t)NC1*8;
constexpr size_t O_R2E  = O_NV1  + (size_t)NC1*4;
constexpr size_t O_C2E  = O_R2E  + (size_t)EE*4;
constexpr size_t O_EV2E = O_C2E  + (size_t)EE*4;
constexpr size_t O_BM1  = O_EV2E + (size_t)EE;                // 2^20 bits
constexpr size_t O_DEG2 = O_BM1  + 131072;
constexpr size_t O_H2   = O_DEG2 + (size_t)NC1*4;
constexpr size_t O_CL2  = O_H2   + (size_t)NC1*64*4;
constexpr size_t O_CNT2 = O_CL2  + (size_t)NC1*4;
constexpr size_t O_PS2  = O_CNT2 + (size_t)NC2*4;
constexpr size_t O_XM2  = O_PS2  + (size_t)NC2*8;
constexpr size_t O_XP2  = O_XM2  + (size_t)NC2*64*4;
constexpr size_t O_POS2 = O_XP2  + (size_t)NC2*64*4;
constexpr size_t O_NV2  = O_POS2 + (size_t)NC2*8;
constexpr size_t O_R3E  = O_NV2  + (size_t)NC2*4;
constexpr size_t O_C3E  = O_R3E  + (size_t)EE*4;
constexpr size_t O_EV3E = O_C3E  + (size_t)EE*4;
constexpr size_t O_BM2  = O_EV3E + (size_t)EE;                // 2^16 bits
constexpr size_t O_DEG3 = O_BM2  + 8192;
constexpr size_t O_H3   = O_DEG3 + (size_t)NC2*4;
constexpr size_t O_PERS = O_H3   + (size_t)NC2*128*4;
// arena (reused): acc1+h1 -> acc2 -> acc3
constexpr size_t A_ACC1_B = (size_t)NN*25*4;                  // 6.55 MB
constexpr size_t A_H1_OFF = A_ACC1_B;
constexpr size_t ACC2_B   = (size_t)NC1*25*32*4;              // 52.4 MB
constexpr size_t ACC3_B   = (size_t)NC2*25*64*4;              // 26.2 MB

// ---------------- device helpers ----------------
__device__ __forceinline__ float eluf(float x){ return x > 0.f ? x : expm1f(x); }

// atomic max for non-negative floats (bit pattern monotone)
__device__ __forceinline__ void atomic_max_pos(float* a, float v){
    atomicMax((unsigned int*)a, __float_as_uint(v));
}
// atomic max for arbitrary floats; init must be -inf bits (0xFF800000)
__device__ __forceinline__ void atomic_max_f32(float* a, float v){
    unsigned int b = __float_as_uint(v);
    if (b & 0x80000000u) atomicMin((unsigned int*)a, b);
    else                 atomicMax((int*)a, (int)b);
}

struct Crn { int ix, iy; float fx, fy; };
__device__ __forceinline__ Crn mk_corners(float dx, float dy, float m){
    float inv = 1.0f / (2.0f*m + 1e-12f);
    float vx = (dx*inv + 0.5f) * 4.0f;   // (K1-1)=4
    float vy = (dy*inv + 0.5f) * 4.0f;
    Crn c;
    c.ix = min(max((int)floorf(vx), 0), 3);
    c.iy = min(max((int)floorf(vy), 0), 3);
    c.fx = vx - (float)c.ix;
    c.fy = vy - (float)c.iy;
    return c;
}

#define BLOCK_MAX_AND_ATOMIC(val, dst)                                   \
    {   __shared__ float _s[256];                                        \
        _s[threadIdx.x] = (val); __syncthreads();                        \
        for (int _w = 128; _w > 0; _w >>= 1){                            \
            if (threadIdx.x < _w)                                        \
                _s[threadIdx.x] = fmaxf(_s[threadIdx.x], _s[threadIdx.x+_w]); \
            __syncthreads();                                             \
        }                                                                \
        if (threadIdx.x == 0) atomic_max_pos((dst), _s[0]); }

// ---------------- kernels ----------------
__global__ void k_neginf(unsigned int* a, int n1, unsigned int* b, int n2){
    int i = blockIdx.x*blockDim.x + threadIdx.x;
    if (i < n1) a[i] = 0xFF800000u;
    else if (i < n1 + n2) b[i - n1] = 0xFF800000u;
}

__global__ void k_m1(const float* __restrict__ pos, const int* __restrict__ ei,
                     int E, float* m1){
    float loc = 0.f;
    for (int e = blockIdx.x*blockDim.x + threadIdx.x; e < E; e += gridDim.x*blockDim.x){
        int r = ei[e], c = ei[E + e];
        float dx = pos[2*c]   - pos[2*r];
        float dy = pos[2*c+1] - pos[2*r+1];
        loc = fmaxf(loc, fmaxf(fabsf(dx), fabsf(dy)));
    }
    BLOCK_MAX_AND_ATOMIC(loc, m1);
}

__global__ void k_conv1_scatter(const float* __restrict__ x, const float* __restrict__ pos,
                                const int* __restrict__ ei, int E, const float* m1,
                                float* acc1, float* deg1){
    int e = blockIdx.x*blockDim.x + threadIdx.x;
    if (e >= E) return;
    int r = ei[e], c = ei[E + e];
    float dx = pos[2*c]   - pos[2*r];
    float dy = pos[2*c+1] - pos[2*r+1];
    Crn cr = mk_corners(dx, dy, *m1);
    float xin = x[c];
    float w00 = (1.f-cr.fx)*(1.f-cr.fy), w01 = (1.f-cr.fx)*cr.fy;
    float w10 = cr.fx*(1.f-cr.fy),       w11 = cr.fx*cr.fy;
    int base = r*25 + cr.ix*5 + cr.iy;
    atomicAdd(&acc1[base],     w00*xin);
    atomicAdd(&acc1[base+1],   w01*xin);
    atomicAdd(&acc1[base+5],   w10*xin);
    atomicAdd(&acc1[base+6],   w11*xin);
    atomicAdd(&deg1[r], 1.f);
}

__global__ void k_conv1_fin(const float* __restrict__ acc1, const float* __restrict__ deg1,
                            const float* __restrict__ x, const float* __restrict__ W1,
                            const float* __restrict__ root1, const float* __restrict__ b1,
                            float* h1, int N){
    int gid = blockIdx.x*blockDim.x + threadIdx.x;
    if (gid >= N*32) return;
    int n = gid >> 5, o = gid & 31;
    float s = 0.f;
    #pragma unroll
    for (int k = 0; k < 25; k++) s += acc1[n*25 + k] * W1[k*32 + o];
    float out = s / fmaxf(deg1[n], 1.f) + x[n]*root1[o] + b1[o];
    h1[gid] = eluf(out);
}

__global__ void k_pool1_node(const float* __restrict__ pos, const float* __restrict__ h1,
                             int* cl1, float* cnt1, float* ps1, float* xm1, int N){
    int gid = blockIdx.x*blockDim.x + threadIdx.x;
    if (gid >= N*32) return;
    int n = gid >> 5, o = gid & 31;
    float px = pos[2*n], py = pos[2*n+1];
    int cx = min(max((int)floorf(px*0.25f), 0), 7);
    int cy = min(max((int)floorf(py*0.25f), 0), 7);
    int cl = (n >> 8)*64 + cx*8 + cy;
    if (o == 0){
        cl1[n] = cl;
        atomicAdd(&cnt1[cl], 1.f);
        atomicAdd(&ps1[2*cl],   px);
        atomicAdd(&ps1[2*cl+1], py);
    }
    atomic_max_f32(&xm1[cl*32 + o], h1[n*32 + o]);
}

__global__ void k_pool1_fin(const float* __restrict__ cnt1, const float* __restrict__ ps1,
                            const float* __restrict__ xm1, float* xp1, float* pos1,
                            float* nv1){
    int gid = blockIdx.x*blockDim.x + threadIdx.x;
    if (gid >= NC1*32) return;
    int c = gid >> 5, o = gid & 31;
    float cnt = cnt1[c];
    xp1[gid] = (cnt > 0.f) ? xm1[gid] : 0.f;
    if (o == 0){
        float inv = 1.f / fmaxf(cnt, 1.f);
        pos1[2*c]   = ps1[2*c]   * inv;
        pos1[2*c+1] = ps1[2*c+1] * inv;
        nv1[c] = (cnt > 0.f) ? 1.f : 0.f;
    }
}

__global__ void k_remap1(const int* __restrict__ ei, int E, const int* __restrict__ cl1,
                         const float* __restrict__ pos1, int* r2e, int* c2e,
                         unsigned char* ev2e, unsigned int* bm1, float* m2){
    int e = blockIdx.x*blockDim.x + threadIdx.x;
    float loc = 0.f;
    if (e < E){
        int r2 = cl1[ei[e]], c2 = cl1[ei[E + e]];
        r2e[e] = r2; c2e[e] = c2;
        float dx = pos1[2*c2]   - pos1[2*r2];
        float dy = pos1[2*c2+1] - pos1[2*r2+1];
        loc = fmaxf(fabsf(dx), fabsf(dy));
        unsigned char valid = 0;
        if (r2 != c2){
            int g   = r2 >> 6;
            int bit = (g << 12) | ((r2 & 63) << 6) | (c2 & 63);
            unsigned int old = atomicOr(&bm1[bit >> 5], 1u << (bit & 31));
            valid = ((old >> (bit & 31)) & 1u) ? 0 : 1;
        }
        ev2e[e] = valid;
    }
    BLOCK_MAX_AND_ATOMIC(loc, m2);
}

__global__ void k_conv2_scatter(const int* __restrict__ r2e, const int* __restrict__ c2e,
                                const unsigned char* __restrict__ ev2e, int E,
                                const float* __restrict__ pos1, const float* m2,
                                const float* __restrict__ xp1, float* acc2, float* deg2){
    int gid = blockIdx.x*blockDim.x + threadIdx.x;
    int e = gid >> 5;
    if (e >= E) return;
    if (!ev2e[e]) return;
    int i = gid & 31;
    int r = r2e[e], c = c2e[e];
    float dx = pos1[2*c]   - pos1[2*r];
    float dy = pos1[2*c+1] - pos1[2*r+1];
    Crn cr = mk_corners(dx, dy, *m2);
    float w00 = (1.f-cr.fx)*(1.f-cr.fy), w01 = (1.f-cr.fx)*cr.fy;
    float w10 = cr.fx*(1.f-cr.fy),       w11 = cr.fx*cr.fy;
    float xin = xp1[c*32 + i];
    int base = (r*25 + cr.ix*5 + cr.iy)*32 + i;
    atomicAdd(&acc2[base],        w00*xin);
    atomicAdd(&acc2[base+32],     w01*xin);
    atomicAdd(&acc2[base+5*32],   w10*xin);
    atomicAdd(&acc2[base+6*32],   w11*xin);
    if (i == 0) atomicAdd(&deg2[r], 1.f);
}

__global__ __launch_bounds__(256) void k_conv2_fin(
        const float* __restrict__ acc2, const float* __restrict__ deg2,
        const float* __restrict__ xp1, const float* __restrict__ W2,
        const float* __restrict__ root2, const float* __restrict__ b2, float* h2){
    __shared__ float la[16*800];
    int nb = blockIdx.x * 16;
    for (int idx = threadIdx.x; idx < 16*800; idx += 256)
        la[idx] = acc2[(size_t)nb*800 + idx];
    __syncthreads();
    int o = threadIdx.x & 63, g = threadIdx.x >> 6;   // g in 0..3
    float s0=0.f, s1=0.f, s2=0.f, s3=0.f;
    const float* a0 = &la[(g*4+0)*800];
    const float* a1 = &la[(g*4+1)*800];
    const float* a2 = &la[(g*4+2)*800];
    const float* a3 = &la[(g*4+3)*800];
    for (int kk = 0; kk < 800; kk++){
        float w = W2[kk*64 + o];
        s0 += a0[kk]*w; s1 += a1[kk]*w; s2 += a2[kk]*w; s3 += a3[kk]*w;
    }
    float acc[4] = {s0, s1, s2, s3};
    for (int inner = 0; inner < 4; inner++){
        int n = nb + g*4 + inner;
        float rt = 0.f;
        #pragma unroll
        for (int i = 0; i < 32; i++) rt += xp1[n*32 + i]*root2[i*64 + o];
        float out = acc[inner]/fmaxf(deg2[n], 1.f) + rt + b2[o];
        h2[n*64 + o] = eluf(out);
    }
}

__global__ void k_pool2_node(const float* __restrict__ pos1, const float* __restrict__ nv1,
                             const float* __restrict__ h2, int* cl2, float* cnt2,
                             float* ps2, float* xm2){
    int gid = blockIdx.x*blockDim.x + threadIdx.x;
    if (gid >= NC1*64) return;
    int n = gid >> 6, o = gid & 63;
    float px = pos1[2*n], py = pos1[2*n+1];
    int cx = min(max((int)floorf(px*0.125f), 0), 3);
    int cy = min(max((int)floorf(py*0.125f), 0), 3);
    int cl = (n >> 6)*16 + cx*4 + cy;
    if (o == 0) cl2[n] = cl;
    if (nv1[n] > 0.f){
        if (o == 0){
            atomicAdd(&cnt2[cl], 1.f);
            atomicAdd(&ps2[2*cl],   px);
            atomicAdd(&ps2[2*cl+1], py);
        }
        atomic_max_f32(&xm2[cl*64 + o], h2[n*64 + o]);
    }
}

__global__ void k_pool2_fin(const float* __restrict__ cnt2, const float* __restrict__ ps2,
                            const float* __restrict__ xm2, float* xp2, float* pos2,
                            float* nv2){
    int gid = blockIdx.x*blockDim.x + threadIdx.x;
    if (gid >= NC2*64) return;
    int c = gid >> 6, o = gid & 63;
    float cnt = cnt2[c];
    xp2[gid] = (cnt > 0.f) ? xm2[gid] : 0.f;
    if (o == 0){
        float inv = 1.f / fmaxf(cnt, 1.f);
        pos2[2*c]   = ps2[2*c]   * inv;
        pos2[2*c+1] = ps2[2*c+1] * inv;
        nv2[c] = (cnt > 0.f) ? 1.f : 0.f;
    }
}

__global__ void k_remap2(const int* __restrict__ r2e, const int* __restrict__ c2e,
                         const unsigned char* __restrict__ ev2e, int E,
                         const int* __restrict__ cl2, const float* __restrict__ pos2,
                         int* r3e, int* c3e, unsigned char* ev3e,
                         unsigned int* bm2, float* m3){
    int e = blockIdx.x*blockDim.x + threadIdx.x;
    float loc = 0.f;
    if (e < E){
        int r3 = cl2[r2e[e]], c3 = cl2[c2e[e]];
        r3e[e] = r3; c3e[e] = c3;
        float dx = pos2[2*c3]   - pos2[2*r3];
        float dy = pos2[2*c3+1] - pos2[2*r3+1];
        loc = fmaxf(fabsf(dx), fabsf(dy));
        unsigned char valid = 0;
        if (ev2e[e] && r3 != c3){
            int g   = r3 >> 4;
            int bit = (g << 8) | ((r3 & 15) << 4) | (c3 & 15);
            unsigned int old = atomicOr(&bm2[bit >> 5], 1u << (bit & 31));
            valid = ((old >> (bit & 31)) & 1u) ? 0 : 1;
        }
        ev3e[e] = valid;
    }
    BLOCK_MAX_AND_ATOMIC(loc, m3);
}

__global__ void k_conv3_scatter(const int* __restrict__ r3e, const int* __restrict__ c3e,
                                const unsigned char* __restrict__ ev3e, int E,
                                const float* __restrict__ pos2, const float* m3,
                                const float* __restrict__ xp2, float* acc3, float* deg3){
    int gid = blockIdx.x*blockDim.x + threadIdx.x;
    int e = gid >> 6;
    if (e >= E) return;
    if (!ev3e[e]) return;
    int i = gid & 63;
    int r = r3e[e], c = c3e[e];
    float dx = pos2[2*c]   - pos2[2*r];
    float dy = pos2[2*c+1] - pos2[2*r+1];
    Crn cr = mk_corners(dx, dy, *m3);
    float w00 = (1.f-cr.fx)*(1.f-cr.fy), w01 = (1.f-cr.fx)*cr.fy;
    float w10 = cr.fx*(1.f-cr.fy),       w11 = cr.fx*cr.fy;
    float xin = xp2[c*64 + i];
    int base = (r*25 + cr.ix*5 + cr.iy)*64 + i;
    atomicAdd(&acc3[base],        w00*xin);
    atomicAdd(&acc3[base+64],     w01*xin);
    atomicAdd(&acc3[base+5*64],   w10*xin);
    atomicAdd(&acc3[base+6*64],   w11*xin);
    if (i == 0) atomicAdd(&deg3[r], 1.f);
}

__global__ __launch_bounds__(256) void k_conv3_fin(
        const float* __restrict__ acc3, const float* __restrict__ deg3,
        const float* __restrict__ xp2, const float* __restrict__ W3,
        const float* __restrict__ root3, const float* __restrict__ b3, float* h3){
    __shared__ float la[8*1600];
    int nb = blockIdx.x * 8;
    for (int idx = threadIdx.x; idx < 8*1600; idx += 256)
        la[idx] = acc3[(size_t)nb*1600 + idx];
    __syncthreads();
    int o = threadIdx.x & 127, g = threadIdx.x >> 7;  // g in 0..1
    float s0=0.f, s1=0.f, s2=0.f, s3=0.f;
    const float* a0 = &la[(g*4+0)*1600];
    const float* a1 = &la[(g*4+1)*1600];
    const float* a2 = &la[(g*4+2)*1600];
    const float* a3 = &la[(g*4+3)*1600];
    for (int kk = 0; kk < 1600; kk++){
        float w = W3[kk*128 + o];
        s0 += a0[kk]*w; s1 += a1[kk]*w; s2 += a2[kk]*w; s3 += a3[kk]*w;
    }
    float acc[4] = {s0, s1, s2, s3};
    for (int inner = 0; inner < 4; inner++){
        int n = nb + g*4 + inner;
        float rt = 0.f;
        #pragma unroll
        for (int i = 0; i < 64; i++) rt += xp2[n*64 + i]*root3[i*128 + o];
        float out = acc[inner]/fmaxf(deg3[n], 1.f) + rt + b3[o];
        h3[n*128 + o] = eluf(out);
    }
}

__global__ void k_readout(const float* __restrict__ h3, const float* __restrict__ nv2,
                          const float* __restrict__ fcw, const float* __restrict__ fcb,
                          float* out){
    int g = blockIdx.x, t = threadIdx.x;     // 128 threads
    __shared__ float gf[128];
    __shared__ float lg[10];
    __shared__ float lse;
    float s = 0.f, cnt = 0.f;
    for (int j = 0; j < 16; j++){
        int c = g*16 + j;
        float nv = nv2[c];
        s += h3[c*128 + t] * nv;
        cnt += nv;
    }
    gf[t] = s / fmaxf(cnt, 1.f);
    __syncthreads();
    if (t < 10){
        float l = fcb[t];
        for (int f = 0; f < 128; f++) l += gf[f]*fcw[f*10 + t];
        lg[t] = l;
    }
    __syncthreads();
    if (t == 0){
        float mx = -INFINITY;
        for (int o = 0; o < 10; o++) mx = fmaxf(mx, lg[o]);
        float ss = 0.f;
        for (int o = 0; o < 10; o++) ss += expf(lg[o] - mx);
        lse = mx + logf(ss);
    }
    __syncthreads();
    if (t < 10) out[g*10 + t] = lg[t] - lse;
}

// ---------------- launch ----------------
static inline int GS(long long n){ return (int)((n + 255) / 256); }

extern "C" void kernel_launch(void* const* d_in, const int* in_sizes, int n_in,
                              void* d_out, int out_size, void* d_ws, size_t ws_size,
                              hipStream_t stream){
    const float* x     = (const float*)d_in[0];
    const float* posi  = (const float*)d_in[1];
    const int*   ei    = (const int*)  d_in[2];
    const float* W1    = (const float*)d_in[4];
    const float* root1 = (const float*)d_in[5];
    const float* b1    = (const float*)d_in[6];
    const float* W2    = (const float*)d_in[7];
    const float* root2 = (const float*)d_in[8];
    const float* b2    = (const float*)d_in[9];
    const float* W3    = (const float*)d_in[10];
    const float* root3 = (const float*)d_in[11];
    const float* b3    = (const float*)d_in[12];
    const float* fcw   = (const float*)d_in[13];
    const float* fcb   = (const float*)d_in[14];
    float* out = (float*)d_out;
    const int N = in_sizes[0];       // 65536
    const int E = in_sizes[2] / 2;   // 1048576

    char* ws = (char*)d_ws;
    float*         m1   = (float*)(ws + O_SCAL);
    float*         m2   = m1 + 1;
    float*         m3   = m1 + 2;
    float*         deg1 = (float*)(ws + O_DEG1);
    int*           cl1  = (int*)  (ws + O_CL1);
    float*         cnt1 = (float*)(ws + O_CNT1);
    float*         ps1  = (float*)(ws + O_PS1);
    float*         xm1  = (float*)(ws + O_XM1);
    float*         xp1  = (float*)(ws + O_XP1);
    float*         pos1 = (float*)(ws + O_POS1);
    float*         nv1  = (float*)(ws + O_NV1);
    int*           r2e  = (int*)  (ws + O_R2E);
    int*           c2e  = (int*)  (ws + O_C2E);
    unsigned char* ev2e = (unsigned char*)(ws + O_EV2E);
    unsigned int*  bm1  = (unsigned int*)(ws + O_BM1);
    float*         deg2 = (float*)(ws + O_DEG2);
    float*         h2   = (float*)(ws + O_H2);
    int*           cl2  = (int*)  (ws + O_CL2);
    float*         cnt2 = (float*)(ws + O_CNT2);
    float*         ps2  = (float*)(ws + O_PS2);
    float*         xm2  = (float*)(ws + O_XM2);
    float*         xp2  = (float*)(ws + O_XP2);
    float*         pos2 = (float*)(ws + O_POS2);
    float*         nv2  = (float*)(ws + O_NV2);
    int*           r3e  = (int*)  (ws + O_R3E);
    int*           c3e  = (int*)  (ws + O_C3E);
    unsigned char* ev3e = (unsigned char*)(ws + O_EV3E);
    unsigned int*  bm2  = (unsigned int*)(ws + O_BM2);
    float*         deg3 = (float*)(ws + O_DEG3);
    float*         h3   = (float*)(ws + O_H3);

    float* arena = (float*)(ws + O_PERS);
    float* acc1  = arena;
    float* h1    = (float*)((char*)arena + A_H1_OFF);
    float* acc2  = arena;
    float* acc3  = arena;

    // zero persistent accumulators/bitmaps/scalars + acc1
    hipMemsetAsync(ws, 0, O_PERS, stream);
    hipMemsetAsync(arena, 0, A_ACC1_B, stream);
    k_neginf<<<GS(NC1*32 + NC2*64), 256, 0, stream>>>((unsigned int*)xm1, NC1*32,
                                                      (unsigned int*)xm2, NC2*64);

    // ---- layer 1 ----
    k_m1<<<1024, 256, 0, stream>>>(posi, ei, E, m1);
    k_conv1_scatter<<<GS(E), 256, 0, stream>>>(x, posi, ei, E, m1, acc1, deg1);
    k_conv1_fin<<<GS((long long)N*32), 256, 0, stream>>>(acc1, deg1, x, W1, root1, b1, h1, N);
    k_pool1_node<<<GS((long long)N*32), 256, 0, stream>>>(posi, h1, cl1, cnt1, ps1, xm1, N);
    k_pool1_fin<<<GS((long long)NC1*32), 256, 0, stream>>>(cnt1, ps1, xm1, xp1, pos1, nv1);
    k_remap1<<<GS(E), 256, 0, stream>>>(ei, E, cl1, pos1, r2e, c2e, ev2e, bm1, m2);

    // ---- layer 2 ----
    hipMemsetAsync(arena, 0, ACC2_B, stream);
    k_conv2_scatter<<<GS((long long)E*32), 256, 0, stream>>>(r2e, c2e, ev2e, E, pos1, m2,
                                                             xp1, acc2, deg2);
    k_conv2_fin<<<NC1/16, 256, 0, stream>>>(acc2, deg2, xp1, W2, root2, b2, h2);
    k_pool2_node<<<GS((long long)NC1*64), 256, 0, stream>>>(pos1, nv1, h2, cl2, cnt2, ps2, xm2);
    k_pool2_fin<<<GS((long long)NC2*64), 256, 0, stream>>>(cnt2, ps2, xm2, xp2, pos2, nv2);
    k_remap2<<<GS(E), 256, 0, stream>>>(r2e, c2e, ev2e, E, cl2, pos2, r3e, c3e, ev3e, bm2, m3);

    // ---- layer 3 ----
    hipMemsetAsync(arena, 0, ACC3_B, stream);
    k_conv3_scatter<<<GS((long long)E*64), 256, 0, stream>>>(r3e, c3e, ev3e, E, pos2, m3,
                                                             xp2, acc3, deg3);
    k_conv3_fin<<<NC2/8, 256, 0, stream>>>(acc3, deg3, xp2, W3, root3, b3, h3);

    // ---- readout ----
    k_readout<<<256, 128, 0, stream>>>(h3, nv2, fcw, fcb, out);
}

// Round 2
// 1059.191 us; speedup vs baseline: 1.0579x; 1.0579x over previous
//
#include <hip/hip_runtime.h>
#include <math.h>

// ---------------- problem constants ----------------
constexpr int NN  = 65536;     // nodes (256 graphs x 256 nodes)
constexpr int EE  = 1048576;   // edges (N * 16)
constexpr int NC1 = 16384;     // clusters after pool1 (256 graphs x 64)
constexpr int NC2 = 4096;      // clusters after pool2 (256 graphs x 16)

// ---------------- workspace layout (bytes) ----------------
// Z region (zeroed each launch)
constexpr size_t O_SCAL = 0;                         // m1,m2,m3
constexpr size_t O_CNT1 = 256;
constexpr size_t O_PS1  = O_CNT1 + (size_t)NC1*4;
constexpr size_t O_CNT2 = O_PS1  + (size_t)NC1*8;
constexpr size_t O_PS2  = O_CNT2 + (size_t)NC2*4;
constexpr size_t O_IDG1 = O_PS2  + (size_t)NC2*8;
constexpr size_t O_IDG2 = O_IDG1 + (size_t)NN*4;
constexpr size_t O_IDG3 = O_IDG2 + (size_t)NC1*4;
constexpr size_t O_BM1  = O_IDG3 + (size_t)NC2*4;    // 2^20 bits
constexpr size_t O_BM2  = O_BM1  + 131072;           // 2^16 bits
constexpr size_t Z_END  = O_BM2  + 8192;
// neg-inf region
constexpr size_t O_XM1  = Z_END;                     // NC1*32 f32
constexpr size_t O_XM2  = O_XM1 + (size_t)NC1*32*4;  // NC2*64 f32
constexpr size_t NEG_N  = (size_t)NC1*32 + (size_t)NC2*64;
// uninit region (fully written before read)
constexpr size_t O_CL1  = O_XM2 + (size_t)NC2*64*4;
constexpr size_t O_XP1  = O_CL1  + (size_t)NN*4;
constexpr size_t O_POS1 = O_XP1  + (size_t)NC1*32*4;
constexpr size_t O_NV1  = O_POS1 + (size_t)NC1*8;
constexpr size_t O_CL2  = O_NV1  + (size_t)NC1*4;
constexpr size_t O_XP2  = O_CL2  + (size_t)NC1*4;
constexpr size_t O_POS2 = O_XP2  + (size_t)NC2*64*4;
constexpr size_t O_NV2  = O_POS2 + (size_t)NC2*8;
constexpr size_t O_OFF1 = O_NV2  + (size_t)NC2*4;
constexpr size_t O_CUR1 = O_OFF1 + (((size_t)(NN+1)*4 + 255) & ~(size_t)255);
constexpr size_t O_ADJ1 = O_CUR1 + (size_t)NN*4;
constexpr size_t O_EV2  = O_ADJ1 + (size_t)EE*4;
constexpr size_t O_OFF2 = O_EV2  + (size_t)EE;
constexpr size_t O_CUR2 = O_OFF2 + (((size_t)(NC1+1)*4 + 255) & ~(size_t)255);
constexpr size_t O_ADJ2 = O_CUR2 + (size_t)NC1*4;
constexpr size_t O_RR2  = O_ADJ2 + (size_t)EE*4;
constexpr size_t O_EV3  = O_RR2  + (size_t)EE*4;
constexpr size_t O_OFF3 = O_EV3  + (size_t)EE;
constexpr size_t O_CUR3 = O_OFF3 + (((size_t)(NC2+1)*4 + 255) & ~(size_t)255);
constexpr size_t O_ADJ3 = O_CUR3 + (size_t)NC2*4;
constexpr size_t O_H3   = O_ADJ3 + (size_t)EE*4;

// ---------------- device helpers ----------------
__device__ __forceinline__ float eluf(float x){ return x > 0.f ? x : expm1f(x); }

__device__ __forceinline__ void atomic_max_pos(float* a, float v){
    atomicMax((unsigned int*)a, __float_as_uint(v));
}
// arbitrary-sign float atomic max; target init = -inf bits
__device__ __forceinline__ void atomic_max_f32(float* a, float v){
    unsigned int b = __float_as_uint(v);
    if (b & 0x80000000u) atomicMin((unsigned int*)a, b);
    else                 atomicMax((int*)a, (int)b);
}

struct Crn { int ix, iy; float fx, fy; };
__device__ __forceinline__ Crn mk_corners(float dx, float dy, float m){
    float inv = 1.0f / (2.0f*m + 1e-12f);
    float vx = (dx*inv + 0.5f) * 4.0f;   // (K1-1)=4
    float vy = (dy*inv + 0.5f) * 4.0f;
    Crn c;
    c.ix = min(max((int)floorf(vx), 0), 3);
    c.iy = min(max((int)floorf(vy), 0), 3);
    c.fx = vx - (float)c.ix;
    c.fy = vy - (float)c.iy;
    return c;
}

#define BLOCK_MAX_AND_ATOMIC(val, dst)                                   \
    {   __shared__ float _s[256];                                        \
        _s[threadIdx.x] = (val); __syncthreads();                        \
        for (int _w = 128; _w > 0; _w >>= 1){                            \
            if (threadIdx.x < _w)                                        \
                _s[threadIdx.x] = fmaxf(_s[threadIdx.x], _s[threadIdx.x+_w]); \
            __syncthreads();                                             \
        }                                                                \
        if (threadIdx.x == 0) atomic_max_pos((dst), _s[0]); }

// ---------------- generic small kernels ----------------
__global__ void k_neginf(unsigned int* a, int n){
    int i = blockIdx.x*blockDim.x + threadIdx.x;
    if (i < n) a[i] = 0xFF800000u;
}

// m1 max + in-degree count (level 1)
__global__ void k_m1(const float* __restrict__ pos, const int* __restrict__ ei,
                     int E, float* m1, int* idg1){
    float loc = 0.f;
    for (int e = blockIdx.x*blockDim.x + threadIdx.x; e < E; e += gridDim.x*blockDim.x){
        int r = ei[e], c = ei[E + e];
        float dx = pos[2*c]   - pos[2*r];
        float dy = pos[2*c+1] - pos[2*r+1];
        loc = fmaxf(loc, fmaxf(fabsf(dx), fabsf(dy)));
        atomicAdd(&idg1[r], 1);
    }
    BLOCK_MAX_AND_ATOMIC(loc, m1);
}

// single-block exclusive scan: n = ipt*1024, ipt = n>>10
__global__ __launch_bounds__(1024) void k_scan(const int* __restrict__ in, int n,
                                               int* off, int* cur){
    __shared__ int s[1024];
    int t = threadIdx.x;
    int ipt = n >> 10;
    int base = t * ipt;
    int loc = 0;
    for (int i = 0; i < ipt; i++) loc += in[base + i];
    s[t] = loc; __syncthreads();
    for (int d = 1; d < 1024; d <<= 1){
        int v = (t >= d) ? s[t - d] : 0;
        __syncthreads();
        s[t] += v;
        __syncthreads();
    }
    int run = s[t] - loc;                 // exclusive prefix of this chunk
    for (int i = 0; i < ipt; i++){
        off[base + i] = run; cur[base + i] = run;
        run += in[base + i];
    }
    if (t == 1023) off[n] = run;
}

__global__ void k_fill1(const int* __restrict__ ei, int E, int* cur1, int* adj1){
    int e = blockIdx.x*blockDim.x + threadIdx.x;
    if (e >= E) return;
    int r = ei[e];
    int p = atomicAdd(&cur1[r], 1);
    adj1[p] = ei[E + e];
}

// ---------------- conv1: CSR gather + W1 finish + pool1-node, fused ----------------
__global__ __launch_bounds__(128) void k_conv1(
        const int* __restrict__ off1, const int* __restrict__ adj1,
        const float* __restrict__ pos, const float* m1,
        const float* __restrict__ x, const float* __restrict__ W1,
        const float* __restrict__ root1, const float* __restrict__ b1,
        int* cl1, float* cnt1, float* ps1, float* xm1){
    __shared__ float sacc[128*25];
    __shared__ float sW[25*32];
    int t = threadIdx.x;
    for (int i = t; i < 800; i += 128) sW[i] = W1[i];
    for (int i = 0; i < 25; i++) sacc[t*25 + i] = 0.f;
    int n = blockIdx.x*128 + t;
    float rx = pos[2*n], ry = pos[2*n+1];
    float mm = *m1;
    int s0 = off1[n], s1 = off1[n+1];
    for (int p = s0; p < s1; ++p){
        int c = adj1[p];
        float dx = pos[2*c] - rx, dy = pos[2*c+1] - ry;
        Crn cr = mk_corners(dx, dy, mm);
        float xin = x[c];
        int b = t*25 + cr.ix*5 + cr.iy;
        sacc[b]   += (1.f-cr.fx)*(1.f-cr.fy)*xin;
        sacc[b+1] += (1.f-cr.fx)*cr.fy*xin;
        sacc[b+5] += cr.fx*(1.f-cr.fy)*xin;
        sacc[b+6] += cr.fx*cr.fy*xin;
    }
    __syncthreads();   // sW ready (sacc region is thread-private)
    float inv = 1.f / fmaxf((float)(s1 - s0), 1.f);
    float xr = x[n];
    int cx = min(max((int)floorf(rx*0.25f), 0), 7);
    int cy = min(max((int)floorf(ry*0.25f), 0), 7);
    int cl = (n >> 8)*64 + cx*8 + cy;
    cl1[n] = cl;
    atomicAdd(&cnt1[cl], 1.f);
    atomicAdd(&ps1[2*cl],   rx);
    atomicAdd(&ps1[2*cl+1], ry);
    for (int o = 0; o < 32; o++){
        float s = 0.f;
        #pragma unroll
        for (int k = 0; k < 25; k++) s += sacc[t*25 + k] * sW[k*32 + o];
        float out = eluf(s*inv + xr*root1[o] + b1[o]);
        atomic_max_f32(&xm1[cl*32 + o], out);
    }
}

__global__ void k_pool1_fin(const float* __restrict__ cnt1, const float* __restrict__ ps1,
                            const float* __restrict__ xm1, float* xp1, float* pos1,
                            float* nv1){
    int gid = blockIdx.x*blockDim.x + threadIdx.x;
    if (gid >= NC1*32) return;
    int c = gid >> 5, o = gid & 31;
    float cnt = cnt1[c];
    xp1[gid] = (cnt > 0.f) ? xm1[gid] : 0.f;
    if (o == 0){
        float inv = 1.f / fmaxf(cnt, 1.f);
        pos1[2*c]   = ps1[2*c]   * inv;
        pos1[2*c+1] = ps1[2*c+1] * inv;
        nv1[c] = (cnt > 0.f) ? 1.f : 0.f;
    }
}

// remap level1->2: dedup bitmap, validity byte, indeg2, m2
__global__ void k_remap1(const int* __restrict__ ei, int E, const int* __restrict__ cl1,
                         const float* __restrict__ pos1, unsigned char* ev2,
                         unsigned int* bm1, int* idg2, float* m2){
    int e = blockIdx.x*blockDim.x + threadIdx.x;
    float loc = 0.f;
    if (e < E){
        int r2 = cl1[ei[e]], c2 = cl1[ei[E + e]];
        float dx = pos1[2*c2]   - pos1[2*r2];
        float dy = pos1[2*c2+1] - pos1[2*r2+1];
        loc = fmaxf(fabsf(dx), fabsf(dy));
        unsigned char valid = 0;
        if (r2 != c2){
            int g   = r2 >> 6;
            int bit = (g << 12) | ((r2 & 63) << 6) | (c2 & 63);
            unsigned int old = atomicOr(&bm1[bit >> 5], 1u << (bit & 31));
            if (!((old >> (bit & 31)) & 1u)){ valid = 1; atomicAdd(&idg2[r2], 1); }
        }
        ev2[e] = valid;
    }
    BLOCK_MAX_AND_ATOMIC(loc, m2);
}

__global__ void k_fill2(const int* __restrict__ ei, int E,
                        const unsigned char* __restrict__ ev2,
                        const int* __restrict__ cl1, int* cur2, int* adj2, int* rr2){
    int e = blockIdx.x*blockDim.x + threadIdx.x;
    if (e >= E || !ev2[e]) return;
    int r2 = cl1[ei[e]], c2 = cl1[ei[E + e]];
    int p = atomicAdd(&cur2[r2], 1);
    adj2[p] = c2; rr2[p] = r2;
}

// ---------------- conv2: gather (LDS, no atomics) + GEMM + pool2-node, fused ----------
__global__ __launch_bounds__(256) void k_conv2(
        const int* __restrict__ off2, const int* __restrict__ adj2,
        const float* __restrict__ pos1, const float* m2,
        const float* __restrict__ xp1, const float* __restrict__ W2,
        const float* __restrict__ root2, const float* __restrict__ b2,
        const float* __restrict__ nv1,
        int* cl2, float* cnt2, float* ps2, float* xm2){
    __shared__ float acc[8*800];
    for (int i = threadIdx.x; i < 8*800; i += 256) acc[i] = 0.f;
    __syncthreads();
    int grp = threadIdx.x >> 5, lane = threadIdx.x & 31;
    {   // gather: group grp owns cluster r = bid*8+grp -> exclusive LDS region
        int r = blockIdx.x*8 + grp;
        int s0 = off2[r], s1 = off2[r+1];
        float rx = pos1[2*r], ry = pos1[2*r+1];
        float mm = *m2;
        float* am = &acc[grp*800];
        for (int p = s0; p < s1; ++p){
            int c = adj2[p];
            float dx = pos1[2*c] - rx, dy = pos1[2*c+1] - ry;
            Crn cr = mk_corners(dx, dy, mm);
            float xin = xp1[c*32 + lane];
            int b = (cr.ix*5 + cr.iy)*32 + lane;
            am[b]       += (1.f-cr.fx)*(1.f-cr.fy)*xin;
            am[b+32]    += (1.f-cr.fx)*cr.fy*xin;
            am[b+5*32]  += cr.fx*(1.f-cr.fy)*xin;
            am[b+6*32]  += cr.fx*cr.fy*xin;
        }
    }
    __syncthreads();
    // GEMM finish: thread = (o, mg); handles clusters mg and mg+4
    int o = threadIdx.x & 63, mg = threadIdx.x >> 6;   // mg in 0..3
    const float* a0 = &acc[mg*800];
    const float* a1 = &acc[(mg+4)*800];
    float sA = 0.f, sB = 0.f;
    for (int kk = 0; kk < 800; kk += 4){
        float4 va = *(const float4*)&a0[kk];
        float4 vb = *(const float4*)&a1[kk];
        float w0 = W2[(kk+0)*64 + o], w1 = W2[(kk+1)*64 + o];
        float w2 = W2[(kk+2)*64 + o], w3 = W2[(kk+3)*64 + o];
        sA += va.x*w0 + va.y*w1 + va.z*w2 + va.w*w3;
        sB += vb.x*w0 + vb.y*w1 + vb.z*w2 + vb.w*w3;
    }
    #pragma unroll
    for (int h = 0; h < 2; ++h){
        int m  = mg + h*4;
        int rr = blockIdx.x*8 + m;
        float s = h ? sB : sA;
        float dg = fmaxf((float)(off2[rr+1] - off2[rr]), 1.f);
        float rt = 0.f;
        #pragma unroll
        for (int i = 0; i < 32; i++) rt += xp1[rr*32 + i]*root2[i*64 + o];
        float val = eluf(s/dg + rt + b2[o]);
        // fused pool2-node
        float px = pos1[2*rr], py = pos1[2*rr+1];
        int cx = min(max((int)floorf(px*0.125f), 0), 3);
        int cy = min(max((int)floorf(py*0.125f), 0), 3);
        int cl = (rr >> 6)*16 + cx*4 + cy;
        if (o == 0) cl2[rr] = cl;
        if (nv1[rr] > 0.f){
            if (o == 0){
                atomicAdd(&cnt2[cl], 1.f);
                atomicAdd(&ps2[2*cl],   px);
                atomicAdd(&ps2[2*cl+1], py);
            }
            atomic_max_f32(&xm2[cl*64 + o], val);
        }
    }
}

__global__ void k_pool2_fin(const float* __restrict__ cnt2, const float* __restrict__ ps2,
                            const float* __restrict__ xm2, float* xp2, float* pos2,
                            float* nv2){
    int gid = blockIdx.x*blockDim.x + threadIdx.x;
    if (gid >= NC2*64) return;
    int c = gid >> 6, o = gid & 63;
    float cnt = cnt2[c];
    xp2[gid] = (cnt > 0.f) ? xm2[gid] : 0.f;
    if (o == 0){
        float inv = 1.f / fmaxf(cnt, 1.f);
        pos2[2*c]   = ps2[2*c]   * inv;
        pos2[2*c+1] = ps2[2*c+1] * inv;
        nv2[c] = (cnt > 0.f) ? 1.f : 0.f;
    }
}

// remap level2->3 over the COMPACT valid-edge list
__global__ void k_remap2(const int* __restrict__ rr2, const int* __restrict__ adj2,
                         const int* __restrict__ off2, const int* __restrict__ cl2,
                         const float* __restrict__ pos2, unsigned char* ev3,
                         unsigned int* bm2, int* idg3, float* m3){
    int p = blockIdx.x*blockDim.x + threadIdx.x;
    int nval = off2[NC1];
    float loc = 0.f;
    if (p < nval){
        int r3 = cl2[rr2[p]], c3 = cl2[adj2[p]];
        float dx = pos2[2*c3]   - pos2[2*r3];
        float dy = pos2[2*c3+1] - pos2[2*r3+1];
        loc = fmaxf(fabsf(dx), fabsf(dy));
        unsigned char valid = 0;
        if (r3 != c3){
            int g   = r3 >> 4;
            int bit = (g << 8) | ((r3 & 15) << 4) | (c3 & 15);
            unsigned int old = atomicOr(&bm2[bit >> 5], 1u << (bit & 31));
            if (!((old >> (bit & 31)) & 1u)){ valid = 1; atomicAdd(&idg3[r3], 1); }
        }
        ev3[p] = valid;
    }
    BLOCK_MAX_AND_ATOMIC(loc, m3);
}

__global__ void k_fill3(const int* __restrict__ rr2, const int* __restrict__ adj2,
                        const int* __restrict__ off2,
                        const unsigned char* __restrict__ ev3,
                        const int* __restrict__ cl2, int* cur3, int* adj3){
    int p = blockIdx.x*blockDim.x + threadIdx.x;
    int nval = off2[NC1];
    if (p >= nval || !ev3[p]) return;
    int r3 = cl2[rr2[p]], c3 = cl2[adj2[p]];
    int q = atomicAdd(&cur3[r3], 1);
    adj3[q] = c3;
}

// ---------------- conv3: gather (LDS, no atomics) + GEMM ----------------
__global__ __launch_bounds__(256) void k_conv3(
        const int* __restrict__ off3, const int* __restrict__ adj3,
        const float* __restrict__ pos2, const float* m3,
        const float* __restrict__ xp2, const float* __restrict__ W3,
        const float* __restrict__ root3, const float* __restrict__ b3,
        float* h3){
    __shared__ float acc[4*1600];
    for (int i = threadIdx.x; i < 4*1600; i += 256) acc[i] = 0.f;
    __syncthreads();
    int grp = threadIdx.x >> 6, lane = threadIdx.x & 63;
    {
        int r = blockIdx.x*4 + grp;
        int s0 = off3[r], s1 = off3[r+1];
        float rx = pos2[2*r], ry = pos2[2*r+1];
        float mm = *m3;
        float* am = &acc[grp*1600];
        for (int p = s0; p < s1; ++p){
            int c = adj3[p];
            float dx = pos2[2*c] - rx, dy = pos2[2*c+1] - ry;
            Crn cr = mk_corners(dx, dy, mm);
            float xin = xp2[c*64 + lane];
            int b = (cr.ix*5 + cr.iy)*64 + lane;
            am[b]       += (1.f-cr.fx)*(1.f-cr.fy)*xin;
            am[b+64]    += (1.f-cr.fx)*cr.fy*xin;
            am[b+5*64]  += cr.fx*(1.f-cr.fy)*xin;
            am[b+6*64]  += cr.fx*cr.fy*xin;
        }
    }
    __syncthreads();
    int o = threadIdx.x & 127, mg = threadIdx.x >> 7;   // mg in 0..1
    const float* a0 = &acc[mg*1600];
    const float* a1 = &acc[(mg+2)*1600];
    float sA = 0.f, sB = 0.f;
    for (int kk = 0; kk < 1600; kk += 4){
        float4 va = *(const float4*)&a0[kk];
        float4 vb = *(const float4*)&a1[kk];
        float w0 = W3[(kk+0)*128 + o], w1 = W3[(kk+1)*128 + o];
        float w2 = W3[(kk+2)*128 + o], w3 = W3[(kk+3)*128 + o];
        sA += va.x*w0 + va.y*w1 + va.z*w2 + va.w*w3;
        sB += vb.x*w0 + vb.y*w1 + vb.z*w2 + vb.w*w3;
    }
    #pragma unroll
    for (int h = 0; h < 2; ++h){
        int m  = mg + h*2;
        int rr = blockIdx.x*4 + m;
        float s = h ? sB : sA;
        float dg = fmaxf((float)(off3[rr+1] - off3[rr]), 1.f);
        float rt = 0.f;
        #pragma unroll
        for (int i = 0; i < 64; i++) rt += xp2[rr*64 + i]*root3[i*128 + o];
        h3[rr*128 + o] = eluf(s/dg + rt + b3[o]);
    }
}

__global__ void k_readout(const float* __restrict__ h3, const float* __restrict__ nv2,
                          const float* __restrict__ fcw, const float* __restrict__ fcb,
                          float* out){
    int g = blockIdx.x, t = threadIdx.x;     // 128 threads
    __shared__ float gf[128];
    __shared__ float lg[10];
    __shared__ float lse;
    float s = 0.f, cnt = 0.f;
    for (int j = 0; j < 16; j++){
        int c = g*16 + j;
        float nv = nv2[c];
        s += h3[c*128 + t] * nv;
        cnt += nv;
    }
    gf[t] = s / fmaxf(cnt, 1.f);
    __syncthreads();
    if (t < 10){
        float l = fcb[t];
        for (int f = 0; f < 128; f++) l += gf[f]*fcw[f*10 + t];
        lg[t] = l;
    }
    __syncthreads();
    if (t == 0){
        float mx = -INFINITY;
        for (int o = 0; o < 10; o++) mx = fmaxf(mx, lg[o]);
        float ss = 0.f;
        for (int o = 0; o < 10; o++) ss += expf(lg[o] - mx);
        lse = mx + logf(ss);
    }
    __syncthreads();
    if (t < 10) out[g*10 + t] = lg[t] - lse;
}

// ---------------- launch ----------------
static inline int GS(long long n){ return (int)((n + 255) / 256); }

extern "C" void kernel_launch(void* const* d_in, const int* in_sizes, int n_in,
                              void* d_out, int out_size, void* d_ws, size_t ws_size,
                              hipStream_t stream){
    const float* x     = (const float*)d_in[0];
    const float* posi  = (const float*)d_in[1];
    const int*   ei    = (const int*)  d_in[2];
    const float* W1    = (const float*)d_in[4];
    const float* root1 = (const float*)d_in[5];
    const float* b1    = (const float*)d_in[6];
    const float* W2    = (const float*)d_in[7];
    const float* root2 = (const float*)d_in[8];
    const float* b2    = (const float*)d_in[9];
    const float* W3    = (const float*)d_in[10];
    const float* root3 = (const float*)d_in[11];
    const float* b3    = (const float*)d_in[12];
    const float* fcw   = (const float*)d_in[13];
    const float* fcb   = (const float*)d_in[14];
    float* out = (float*)d_out;
    const int E = in_sizes[2] / 2;   // 1048576

    char* ws = (char*)d_ws;
    float*         m1   = (float*)(ws + O_SCAL);
    float*         m2   = m1 + 1;
    float*         m3   = m1 + 2;
    float*         cnt1 = (float*)(ws + O_CNT1);
    float*         ps1  = (float*)(ws + O_PS1);
    float*         cnt2 = (float*)(ws + O_CNT2);
    float*         ps2  = (float*)(ws + O_PS2);
    int*           idg1 = (int*)  (ws + O_IDG1);
    int*           idg2 = (int*)  (ws + O_IDG2);
    int*           idg3 = (int*)  (ws + O_IDG3);
    unsigned int*  bm1  = (unsigned int*)(ws + O_BM1);
    unsigned int*  bm2  = (unsigned int*)(ws + O_BM2);
    float*         xm1  = (float*)(ws + O_XM1);
    float*         xm2  = (float*)(ws + O_XM2);
    int*           cl1  = (int*)  (ws + O_CL1);
    float*         xp1  = (float*)(ws + O_XP1);
    float*         pos1 = (float*)(ws + O_POS1);
    float*         nv1  = (float*)(ws + O_NV1);
    int*           cl2  = (int*)  (ws + O_CL2);
    float*         xp2  = (float*)(ws + O_XP2);
    float*         pos2 = (float*)(ws + O_POS2);
    float*         nv2  = (float*)(ws + O_NV2);
    int*           off1 = (int*)  (ws + O_OFF1);
    int*           cur1 = (int*)  (ws + O_CUR1);
    int*           adj1 = (int*)  (ws + O_ADJ1);
    unsigned char* ev2  = (unsigned char*)(ws + O_EV2);
    int*           off2 = (int*)  (ws + O_OFF2);
    int*           cur2 = (int*)  (ws + O_CUR2);
    int*           adj2 = (int*)  (ws + O_ADJ2);
    int*           rr2  = (int*)  (ws + O_RR2);
    unsigned char* ev3  = (unsigned char*)(ws + O_EV3);
    int*           off3 = (int*)  (ws + O_OFF3);
    int*           cur3 = (int*)  (ws + O_CUR3);
    int*           adj3 = (int*)  (ws + O_ADJ3);
    float*         h3   = (float*)(ws + O_H3);

    hipMemsetAsync(ws, 0, Z_END, stream);
    k_neginf<<<GS(NEG_N), 256, 0, stream>>>((unsigned int*)xm1, (int)NEG_N);

    // ---- layer 1 ----
    k_m1<<<1024, 256, 0, stream>>>(posi, ei, E, m1, idg1);
    k_scan<<<1, 1024, 0, stream>>>(idg1, NN, off1, cur1);
    k_fill1<<<GS(E), 256, 0, stream>>>(ei, E, cur1, adj1);
    k_conv1<<<NN/128, 128, 0, stream>>>(off1, adj1, posi, m1, x, W1, root1, b1,
                                        cl1, cnt1, ps1, xm1);
    k_pool1_fin<<<GS((long long)NC1*32), 256, 0, stream>>>(cnt1, ps1, xm1, xp1, pos1, nv1);

    // ---- layer 2 ----
    k_remap1<<<GS(E), 256, 0, stream>>>(ei, E, cl1, pos1, ev2, bm1, idg2, m2);
    k_scan<<<1, 1024, 0, stream>>>(idg2, NC1, off2, cur2);
    k_fill2<<<GS(E), 256, 0, stream>>>(ei, E, ev2, cl1, cur2, adj2, rr2);
    k_conv2<<<NC1/8, 256, 0, stream>>>(off2, adj2, pos1, m2, xp1, W2, root2, b2,
                                       nv1, cl2, cnt2, ps2, xm2);
    k_pool2_fin<<<GS((long long)NC2*64), 256, 0, stream>>>(cnt2, ps2, xm2, xp2, pos2, nv2);

    // ---- layer 3 ----
    k_remap2<<<GS(E), 256, 0, stream>>>(rr2, adj2, off2, cl2, pos2, ev3, bm2, idg3, m3);
    k_scan<<<1, 1024, 0, stream>>>(idg3, NC2, off3, cur3);
    k_fill3<<<GS(E), 256, 0, stream>>>(rr2, adj2, off2, ev3, cl2, cur3, adj3);
    k_conv3<<<NC2/4, 256, 0, stream>>>(off3, adj3, pos2, m3, xp2, W3, root3, b3, h3);

    // ---- readout ----
    k_readout<<<256, 128, 0, stream>>>(h3, nv2, fcw, fcb, out);
}

// Round 3
// 344.199 us; speedup vs baseline: 3.2556x; 3.0773x over previous
//
#include <hip/hip_runtime.h>
#include <math.h>

// ---------------- problem constants ----------------
constexpr int NN  = 65536;     // nodes (256 graphs x 256 nodes)
constexpr int EE  = 1048576;   // edges (N * 16)
constexpr int NG  = 256;       // graphs
constexpr int NC1 = 16384;     // clusters after pool1 (256 x 64)
constexpr int NC2 = 4096;      // clusters after pool2 (256 x 16)
constexpr int EPB = EE / 256;  // edges per bucketing block = 4096

// ---------------- workspace layout (bytes) ----------------
// Z region (memset 0 each launch)
constexpr size_t O_SCAL  = 0;                                  // m1,m2,m3
constexpr size_t O_GTOT  = 256;                                // 256 ints
constexpr size_t O_CNT2  = O_GTOT + 1024;                      // NC2 f32
constexpr size_t O_PS2   = O_CNT2 + (size_t)NC2*4;             // NC2*2 f32
constexpr size_t Z_END   = O_PS2  + (size_t)NC2*8;
// neg-inf region (kernel-filled)
constexpr size_t O_XM2   = Z_END;                              // NC2*64 f32
// fully-written-before-read region
constexpr size_t O_GOFF  = O_XM2  + (size_t)NC2*64*4;          // 257 ints (pad)
constexpr size_t O_BB    = O_GOFF + 1280;                      // 256*256 ints
constexpr size_t O_BE    = O_BB   + (size_t)256*256*4;         // EE ushort
constexpr size_t O_XP1   = O_BE   + (size_t)EE*2;              // NC1*32 f32
constexpr size_t O_POS1  = O_XP1  + (size_t)NC1*32*4;          // NC1*2 f32
constexpr size_t O_NV1   = O_POS1 + (size_t)NC1*8;             // NC1 f32
constexpr size_t O_ADJ2  = O_NV1  + (size_t)NC1*4;             // NG*4096 ints
constexpr size_t O_OFF2S = O_ADJ2 + (size_t)NG*4096*4;         // NC1 ints
constexpr size_t O_DEG2I = O_OFF2S+ (size_t)NC1*4;             // NC1 ints
constexpr size_t O_CL2   = O_DEG2I+ (size_t)NC1*4;             // NC1 ints
constexpr size_t O_XP2   = O_CL2  + (size_t)NC1*4;             // NC2*64 f32
constexpr size_t O_POS2  = O_XP2  + (size_t)NC2*64*4;          // NC2*2 f32
constexpr size_t O_NV2   = O_POS2 + (size_t)NC2*8;             // NC2 f32
constexpr size_t O_ADJ3  = O_NV2  + (size_t)NC2*4;             // NG*256 ints
constexpr size_t O_OFF3S = O_ADJ3 + (size_t)NG*256*4;          // NC2 ints
constexpr size_t O_DEG3I = O_OFF3S+ (size_t)NC2*4;             // NC2 ints
constexpr size_t O_H3    = O_DEG3I+ (size_t)NC2*4;             // NC2*128 f32

// ---------------- device helpers ----------------
__device__ __forceinline__ float eluf(float x){ return x > 0.f ? x : expm1f(x); }

__device__ __forceinline__ void atomic_max_pos(float* a, float v){
    atomicMax((unsigned int*)a, __float_as_uint(v));
}
// arbitrary-sign float atomic max (works for global or LDS); init = -inf bits
__device__ __forceinline__ void atomic_max_f32(float* a, float v){
    unsigned int b = __float_as_uint(v);
    if (b & 0x80000000u) atomicMin((unsigned int*)a, b);
    else                 atomicMax((int*)a, (int)b);
}

struct Crn { int ix, iy; float fx, fy; };
__device__ __forceinline__ Crn mk_corners(float dx, float dy, float m){
    float inv = 1.0f / (2.0f*m + 1e-12f);
    float vx = (dx*inv + 0.5f) * 4.0f;   // (K1-1)=4
    float vy = (dy*inv + 0.5f) * 4.0f;
    Crn c;
    c.ix = min(max((int)floorf(vx), 0), 3);
    c.iy = min(max((int)floorf(vy), 0), 3);
    c.fx = vx - (float)c.ix;
    c.fy = vy - (float)c.iy;
    return c;
}

#define BLOCK_MAX_AND_ATOMIC(val, dst)                                   \
    {   __shared__ float _s[256];                                        \
        _s[threadIdx.x] = (val); __syncthreads();                        \
        for (int _w = 128; _w > 0; _w >>= 1){                            \
            if (threadIdx.x < _w)                                        \
                _s[threadIdx.x] = fmaxf(_s[threadIdx.x], _s[threadIdx.x+_w]); \
            __syncthreads();                                             \
        }                                                                \
        if (threadIdx.x == 0) atomic_max_pos((dst), _s[0]); }

// ---------------- small kernels ----------------
__global__ void k_neginf(unsigned int* a, int n){
    int i = blockIdx.x*blockDim.x + threadIdx.x;
    if (i < n) a[i] = 0xFF800000u;
}

// pass1: m1 global max + per-graph histogram + per-block bin bases
__global__ __launch_bounds__(256) void k_pass1(const int* __restrict__ ei,
                                               const float* __restrict__ pos,
                                               float* m1, int* gtot, int* bb){
    __shared__ int h[256];
    h[threadIdx.x] = 0; __syncthreads();
    int base = blockIdx.x * EPB;
    float loc = 0.f;
    for (int i = threadIdx.x; i < EPB; i += 256){
        int e = base + i;
        int r = ei[e], c = ei[EE + e];
        float dx = pos[2*c]   - pos[2*r];
        float dy = pos[2*c+1] - pos[2*r+1];
        loc = fmaxf(loc, fmaxf(fabsf(dx), fabsf(dy)));
        atomicAdd(&h[r >> 8], 1);
    }
    __syncthreads();
    bb[blockIdx.x*256 + threadIdx.x] = atomicAdd(&gtot[threadIdx.x], h[threadIdx.x]);
    BLOCK_MAX_AND_ATOMIC(loc, m1);
}

__global__ void k_gscan(const int* __restrict__ gtot, int* goff){
    __shared__ int s[256];
    int t = threadIdx.x;
    int v0 = gtot[t];
    s[t] = v0; __syncthreads();
    for (int d = 1; d < 256; d <<= 1){
        int u = (t >= d) ? s[t-d] : 0;
        __syncthreads();
        s[t] += u;
        __syncthreads();
    }
    goff[t] = s[t] - v0;
    if (t == 255) goff[256] = s[t];
}

// pass2: scatter edges into per-graph buckets, packed (rl | cl<<8)
__global__ __launch_bounds__(256) void k_pass2(const int* __restrict__ ei,
                                               const int* __restrict__ goff,
                                               const int* __restrict__ bb,
                                               unsigned short* __restrict__ be){
    __shared__ int cur[256];
    cur[threadIdx.x] = 0; __syncthreads();
    int base = blockIdx.x * EPB;
    for (int i = threadIdx.x; i < EPB; i += 256){
        int e = base + i;
        int r = ei[e], c = ei[EE + e];
        int g = r >> 8;
        int l = atomicAdd(&cur[g], 1);
        be[goff[g] + bb[blockIdx.x*256 + g] + l] =
            (unsigned short)((r & 255) | ((c & 255) << 8));
    }
}

// ---------------- graph1: conv1 + pool1 + lvl2 dedup/CSR + m2, all in LDS ----------
__global__ __launch_bounds__(256) void k_graph1(
        const unsigned short* __restrict__ be, const int* __restrict__ goff,
        const float* __restrict__ pos, const float* __restrict__ x,
        const float* __restrict__ m1p, const float* __restrict__ W1,
        const float* __restrict__ root1, const float* __restrict__ b1,
        float* __restrict__ xp1, float* __restrict__ pos1g, float* __restrict__ nv1,
        int* __restrict__ adj2, int* __restrict__ off2s, int* __restrict__ deg2i,
        float* m2p){
    __shared__ float acc[256*25];
    __shared__ float posx[256], posy[256], xL[256];
    __shared__ int   cl1L[256], degL[256];
    __shared__ float sW[800];
    __shared__ unsigned int bitL[128];
    __shared__ float xmL[64*32];
    __shared__ int   cntL[64];
    __shared__ float psx[64], psy[64];
    __shared__ float p1x[64], p1y[64];
    __shared__ int   rpre[64];

    int t = threadIdx.x, g = blockIdx.x;
    for (int i = t; i < 800; i += 256) sW[i] = W1[i];
    for (int i = t; i < 6400; i += 256) acc[i] = 0.f;
    posx[t] = pos[2*(g*256 + t)];
    posy[t] = pos[2*(g*256 + t) + 1];
    xL[t]   = x[g*256 + t];
    degL[t] = 0;
    if (t < 128) bitL[t] = 0u;
    if (t < 64){ cntL[t] = 0; psx[t] = 0.f; psy[t] = 0.f; }
    for (int i = t; i < 2048; i += 256) xmL[i] = -INFINITY;
    {   // cluster id from own position (no cross-thread dep)
        int cx = min(max((int)floorf(posx[t]*0.25f), 0), 7);
        int cy = min(max((int)floorf(posy[t]*0.25f), 0), 7);
        cl1L[t] = cx*8 + cy;
    }
    __syncthreads();

    // edge pass: conv1 accumulate + deg + lvl2 bitmap (all LDS atomics)
    float mm = *m1p;
    int e1 = goff[g+1];
    for (int p = goff[g] + t; p < e1; p += 256){
        unsigned int b = be[p];
        int rl = b & 255, cl = (b >> 8) & 255;
        float dx = posx[cl] - posx[rl], dy = posy[cl] - posy[rl];
        Crn cr = mk_corners(dx, dy, mm);
        float xin = xL[cl];
        int ab = rl*25 + cr.ix*5 + cr.iy;
        atomicAdd(&acc[ab],   (1.f-cr.fx)*(1.f-cr.fy)*xin);
        atomicAdd(&acc[ab+1], (1.f-cr.fx)*cr.fy*xin);
        atomicAdd(&acc[ab+5], cr.fx*(1.f-cr.fy)*xin);
        atomicAdd(&acc[ab+6], cr.fx*cr.fy*xin);
        atomicAdd(&degL[rl], 1);
        int r2 = cl1L[rl], c2 = cl1L[cl];
        if (r2 != c2){
            int bit = r2*64 + c2;
            atomicOr(&bitL[bit >> 5], 1u << (bit & 31));
        }
    }
    __syncthreads();

    // node finish: W1 GEMM + elu + pool1 accumulate (LDS)
    {
        float inv = 1.f / fmaxf((float)degL[t], 1.f);
        float xr  = xL[t];
        int   cl  = cl1L[t];
        atomicAdd(&cntL[cl], 1);
        atomicAdd(&psx[cl], posx[t]);
        atomicAdd(&psy[cl], posy[t]);
        for (int o = 0; o < 32; o++){
            float s = 0.f;
            #pragma unroll
            for (int k = 0; k < 25; k++) s += acc[t*25 + k]*sW[k*32 + o];
            float out = eluf(s*inv + xr*root1[o] + b1[o]);
            atomic_max_f32(&xmL[cl*32 + o], out);
        }
    }
    __syncthreads();

    if (t < 64){
        float cnt = (float)cntL[t];
        float inv = 1.f / fmaxf(cnt, 1.f);
        p1x[t] = psx[t]*inv; p1y[t] = psy[t]*inv;
        pos1g[2*(g*64 + t)]     = p1x[t];
        pos1g[2*(g*64 + t) + 1] = p1y[t];
        nv1[g*64 + t] = (cnt > 0.f) ? 1.f : 0.f;
    }
    __syncthreads();
    for (int i = t; i < 2048; i += 256){
        int c = i >> 5;
        xp1[g*2048 + i] = (cntL[c] > 0) ? xmL[i] : 0.f;
    }

    // CSR2 emit + m2
    if (t < 64) rpre[t] = __popc(bitL[2*t]) + __popc(bitL[2*t+1]);
    __syncthreads();
    for (int d = 1; d < 64; d <<= 1){
        int v = 0;
        if (t < 64 && t >= d) v = rpre[t-d];
        __syncthreads();
        if (t < 64) rpre[t] += v;
        __syncthreads();
    }
    float m2loc = 0.f;
    if (t < 64){
        unsigned int w0 = bitL[2*t], w1 = bitL[2*t+1];
        int dg = __popc(w0) + __popc(w1);
        int baseo = rpre[t] - dg;
        off2s[g*64 + t] = g*4096 + baseo;
        deg2i[g*64 + t] = dg;
        int j = g*4096 + baseo;
        float rx = p1x[t], ry = p1y[t];
        while (w0){
            int b = __ffs(w0) - 1; w0 &= w0 - 1;
            adj2[j++] = g*64 + b;
            m2loc = fmaxf(m2loc, fmaxf(fabsf(p1x[b]-rx), fabsf(p1y[b]-ry)));
        }
        while (w1){
            int b = __ffs(w1) - 1; w1 &= w1 - 1;
            int c = 32 + b;
            adj2[j++] = g*64 + c;
            m2loc = fmaxf(m2loc, fmaxf(fabsf(p1x[c]-rx), fabsf(p1y[c]-ry)));
        }
    }
    BLOCK_MAX_AND_ATOMIC(m2loc, m2p);
}

// ---------------- conv2: LDS gather + GEMM + pool2-node ----------------
__global__ __launch_bounds__(256) void k_conv2(
        const int* __restrict__ off2s, const int* __restrict__ deg2i,
        const int* __restrict__ adj2, const float* __restrict__ pos1g,
        const float* __restrict__ m2p, const float* __restrict__ xp1,
        const float* __restrict__ W2, const float* __restrict__ root2,
        const float* __restrict__ b2, const float* __restrict__ nv1,
        int* __restrict__ cl2, float* cnt2, float* ps2, float* xm2){
    __shared__ float am[8*800];
    __shared__ float xpL[64*32];
    __shared__ float p1x[64], p1y[64];
    int t = threadIdx.x;
    int g = blockIdx.x >> 3, sub = blockIdx.x & 7;
    for (int i = t; i < 6400; i += 256) am[i] = 0.f;
    for (int i = t; i < 2048; i += 256) xpL[i] = xp1[g*2048 + i];
    if (t < 64){ p1x[t] = pos1g[2*(g*64+t)]; p1y[t] = pos1g[2*(g*64+t)+1]; }
    __syncthreads();
    int grp = t >> 5, lane = t & 31;
    {
        int rl = sub*8 + grp;
        int r  = g*64 + rl;
        int s0 = off2s[r], n = deg2i[r];
        float rx = p1x[rl], ry = p1y[rl];
        float mm = *m2p;
        float* a = &am[grp*800];
        for (int j = 0; j < n; ++j){
            int cLoc = adj2[s0 + j] & 63;
            float dx = p1x[cLoc] - rx, dy = p1y[cLoc] - ry;
            Crn cr = mk_corners(dx, dy, mm);
            float xin = xpL[cLoc*32 + lane];
            int b = (cr.ix*5 + cr.iy)*32 + lane;
            a[b]     += (1.f-cr.fx)*(1.f-cr.fy)*xin;
            a[b+32]  += (1.f-cr.fx)*cr.fy*xin;
            a[b+160] += cr.fx*(1.f-cr.fy)*xin;
            a[b+192] += cr.fx*cr.fy*xin;
        }
    }
    __syncthreads();
    int o = t & 63, mg = t >> 6;
    const float* a0 = &am[mg*800];
    const float* a1 = &am[(mg+4)*800];
    float sA = 0.f, sB = 0.f;
    for (int kk = 0; kk < 800; kk += 4){
        float4 va = *(const float4*)&a0[kk];
        float4 vb = *(const float4*)&a1[kk];
        float w0 = W2[kk*64+o], w1 = W2[(kk+1)*64+o];
        float w2 = W2[(kk+2)*64+o], w3 = W2[(kk+3)*64+o];
        sA += va.x*w0 + va.y*w1 + va.z*w2 + va.w*w3;
        sB += vb.x*w0 + vb.y*w1 + vb.z*w2 + vb.w*w3;
    }
    #pragma unroll
    for (int h = 0; h < 2; ++h){
        int m  = mg + h*4;
        int rl = sub*8 + m;
        int rr = g*64 + rl;
        float s  = h ? sB : sA;
        float dg = fmaxf((float)deg2i[rr], 1.f);
        float rt = 0.f;
        #pragma unroll
        for (int i = 0; i < 32; i++) rt += xpL[rl*32 + i]*root2[i*64 + o];
        float val = eluf(s/dg + rt + b2[o]);
        float px = p1x[rl], py = p1y[rl];
        int cx = min(max((int)floorf(px*0.125f), 0), 3);
        int cy = min(max((int)floorf(py*0.125f), 0), 3);
        int cl = g*16 + cx*4 + cy;
        if (o == 0) cl2[rr] = cl;
        if (nv1[rr] > 0.f){
            if (o == 0){
                atomicAdd(&cnt2[cl], 1.f);
                atomicAdd(&ps2[2*cl],   px);
                atomicAdd(&ps2[2*cl+1], py);
            }
            atomic_max_f32(&xm2[cl*64 + o], val);
        }
    }
}

// ---------------- lvl3: pool2-finish + lvl3 dedup/CSR + m3, per graph ----------------
__global__ __launch_bounds__(256) void k_lvl3(
        const int* __restrict__ off2s, const int* __restrict__ deg2i,
        const int* __restrict__ adj2, const int* __restrict__ cl2,
        const float* __restrict__ cnt2, const float* __restrict__ ps2,
        const float* __restrict__ xm2,
        float* __restrict__ xp2, float* __restrict__ pos2g, float* __restrict__ nv2,
        int* __restrict__ adj3, int* __restrict__ off3s, int* __restrict__ deg3i,
        float* m3p){
    __shared__ int cl2L[64];
    __shared__ unsigned int bit3[8];
    __shared__ float p2x[16], p2y[16];
    __shared__ int rpre[16];
    int t = threadIdx.x, g = blockIdx.x;
    if (t < 64) cl2L[t] = cl2[g*64 + t] & 15;
    if (t < 8)  bit3[t] = 0u;
    if (t < 16){
        float cnt = cnt2[g*16 + t];
        float inv = 1.f / fmaxf(cnt, 1.f);
        p2x[t] = ps2[2*(g*16+t)]*inv;
        p2y[t] = ps2[2*(g*16+t)+1]*inv;
        pos2g[2*(g*16+t)]   = p2x[t];
        pos2g[2*(g*16+t)+1] = p2y[t];
        nv2[g*16 + t] = (cnt > 0.f) ? 1.f : 0.f;
    }
    for (int i = t; i < 1024; i += 256){
        int c = i >> 6;
        xp2[g*1024 + i] = (cnt2[g*16 + c] > 0.f) ? xm2[g*1024 + i] : 0.f;
    }
    __syncthreads();
    if (t < 64){
        int s0 = off2s[g*64 + t], n = deg2i[g*64 + t];
        int r3 = cl2L[t];
        for (int j = 0; j < n; ++j){
            int c3 = cl2L[adj2[s0 + j] & 63];
            if (r3 != c3){
                int bit = r3*16 + c3;
                atomicOr(&bit3[bit >> 5], 1u << (bit & 31));
            }
        }
    }
    __syncthreads();
    if (t < 16)
        rpre[t] = __popc((bit3[t >> 1] >> ((t & 1)*16)) & 0xFFFFu);
    __syncthreads();
    for (int d = 1; d < 16; d <<= 1){
        int v = 0;
        if (t < 16 && t >= d) v = rpre[t-d];
        __syncthreads();
        if (t < 16) rpre[t] += v;
        __syncthreads();
    }
    float m3loc = 0.f;
    if (t < 16){
        unsigned int w = (bit3[t >> 1] >> ((t & 1)*16)) & 0xFFFFu;
        int dg = __popc(w);
        int baseo = rpre[t] - dg;
        off3s[g*16 + t] = g*256 + baseo;
        deg3i[g*16 + t] = dg;
        int j = g*256 + baseo;
        float rx = p2x[t], ry = p2y[t];
        while (w){
            int b = __ffs(w) - 1; w &= w - 1;
            adj3[j++] = g*16 + b;
            m3loc = fmaxf(m3loc, fmaxf(fabsf(p2x[b]-rx), fabsf(p2y[b]-ry)));
        }
    }
    BLOCK_MAX_AND_ATOMIC(m3loc, m3p);
}

// ---------------- conv3: LDS gather + GEMM ----------------
__global__ __launch_bounds__(256) void k_conv3(
        const int* __restrict__ off3s, const int* __restrict__ deg3i,
        const int* __restrict__ adj3, const float* __restrict__ pos2g,
        const float* __restrict__ m3p, const float* __restrict__ xp2,
        const float* __restrict__ W3, const float* __restrict__ root3,
        const float* __restrict__ b3, float* __restrict__ h3){
    __shared__ float am[4*1600];
    __shared__ float xpL[16*64];
    __shared__ float p2x[16], p2y[16];
    int t = threadIdx.x;
    int g = blockIdx.x >> 2, sub = blockIdx.x & 3;
    for (int i = t; i < 6400; i += 256) am[i] = 0.f;
    for (int i = t; i < 1024; i += 256) xpL[i] = xp2[g*1024 + i];
    if (t < 16){ p2x[t] = pos2g[2*(g*16+t)]; p2y[t] = pos2g[2*(g*16+t)+1]; }
    __syncthreads();
    int grp = t >> 6, lane = t & 63;
    {
        int rl = sub*4 + grp;
        int r  = g*16 + rl;
        int s0 = off3s[r], n = deg3i[r];
        float rx = p2x[rl], ry = p2y[rl];
        float mm = *m3p;
        float* a = &am[grp*1600];
        for (int j = 0; j < n; ++j){
            int cLoc = adj3[s0 + j] & 15;
            float dx = p2x[cLoc] - rx, dy = p2y[cLoc] - ry;
            Crn cr = mk_corners(dx, dy, mm);
            float xin = xpL[cLoc*64 + lane];
            int b = (cr.ix*5 + cr.iy)*64 + lane;
            a[b]     += (1.f-cr.fx)*(1.f-cr.fy)*xin;
            a[b+64]  += (1.f-cr.fx)*cr.fy*xin;
            a[b+320] += cr.fx*(1.f-cr.fy)*xin;
            a[b+384] += cr.fx*cr.fy*xin;
        }
    }
    __syncthreads();
    int o = t & 127, mg = t >> 7;
    const float* a0 = &am[mg*1600];
    const float* a1 = &am[(mg+2)*1600];
    float sA = 0.f, sB = 0.f;
    for (int kk = 0; kk < 1600; kk += 4){
        float4 va = *(const float4*)&a0[kk];
        float4 vb = *(const float4*)&a1[kk];
        float w0 = W3[kk*128+o], w1 = W3[(kk+1)*128+o];
        float w2 = W3[(kk+2)*128+o], w3 = W3[(kk+3)*128+o];
        sA += va.x*w0 + va.y*w1 + va.z*w2 + va.w*w3;
        sB += vb.x*w0 + vb.y*w1 + vb.z*w2 + vb.w*w3;
    }
    #pragma unroll
    for (int h = 0; h < 2; ++h){
        int m  = mg + h*2;
        int rl = sub*4 + m;
        int rr = g*16 + rl;
        float s  = h ? sB : sA;
        float dg = fmaxf((float)deg3i[rr], 1.f);
        float rt = 0.f;
        #pragma unroll
        for (int i = 0; i < 64; i++) rt += xpL[rl*64 + i]*root3[i*128 + o];
        h3[rr*128 + o] = eluf(s/dg + rt + b3[o]);
    }
}

__global__ void k_readout(const float* __restrict__ h3, const float* __restrict__ nv2,
                          const float* __restrict__ fcw, const float* __restrict__ fcb,
                          float* out){
    int g = blockIdx.x, t = threadIdx.x;     // 128 threads
    __shared__ float gf[128];
    __shared__ float lg[10];
    __shared__ float lse;
    float s = 0.f, cnt = 0.f;
    for (int j = 0; j < 16; j++){
        int c = g*16 + j;
        float nv = nv2[c];
        s += h3[c*128 + t] * nv;
        cnt += nv;
    }
    gf[t] = s / fmaxf(cnt, 1.f);
    __syncthreads();
    if (t < 10){
        float l = fcb[t];
        for (int f = 0; f < 128; f++) l += gf[f]*fcw[f*10 + t];
        lg[t] = l;
    }
    __syncthreads();
    if (t == 0){
        float mx = -INFINITY;
        for (int o = 0; o < 10; o++) mx = fmaxf(mx, lg[o]);
        float ss = 0.f;
        for (int o = 0; o < 10; o++) ss += expf(lg[o] - mx);
        lse = mx + logf(ss);
    }
    __syncthreads();
    if (t < 10) out[g*10 + t] = lg[t] - lse;
}

// ---------------- launch ----------------
extern "C" void kernel_launch(void* const* d_in, const int* in_sizes, int n_in,
                              void* d_out, int out_size, void* d_ws, size_t ws_size,
                              hipStream_t stream){
    const float* x     = (const float*)d_in[0];
    const float* posi  = (const float*)d_in[1];
    const int*   ei    = (const int*)  d_in[2];
    const float* W1    = (const float*)d_in[4];
    const float* root1 = (const float*)d_in[5];
    const float* b1    = (const float*)d_in[6];
    const float* W2    = (const float*)d_in[7];
    const float* root2 = (const float*)d_in[8];
    const float* b2    = (const float*)d_in[9];
    const float* W3    = (const float*)d_in[10];
    const float* root3 = (const float*)d_in[11];
    const float* b3    = (const float*)d_in[12];
    const float* fcw   = (const float*)d_in[13];
    const float* fcb   = (const float*)d_in[14];
    float* out = (float*)d_out;

    char* ws = (char*)d_ws;
    float*          m1    = (float*)(ws + O_SCAL);
    float*          m2    = m1 + 1;
    float*          m3    = m1 + 2;
    int*            gtot  = (int*)  (ws + O_GTOT);
    float*          cnt2  = (float*)(ws + O_CNT2);
    float*          ps2   = (float*)(ws + O_PS2);
    float*          xm2   = (float*)(ws + O_XM2);
    int*            goff  = (int*)  (ws + O_GOFF);
    int*            bb    = (int*)  (ws + O_BB);
    unsigned short* be    = (unsigned short*)(ws + O_BE);
    float*          xp1   = (float*)(ws + O_XP1);
    float*          pos1g = (float*)(ws + O_POS1);
    float*          nv1   = (float*)(ws + O_NV1);
    int*            adj2  = (int*)  (ws + O_ADJ2);
    int*            off2s = (int*)  (ws + O_OFF2S);
    int*            deg2i = (int*)  (ws + O_DEG2I);
    int*            cl2   = (int*)  (ws + O_CL2);
    float*          xp2   = (float*)(ws + O_XP2);
    float*          pos2g = (float*)(ws + O_POS2);
    float*          nv2   = (float*)(ws + O_NV2);
    int*            adj3  = (int*)  (ws + O_ADJ3);
    int*            off3s = (int*)  (ws + O_OFF3S);
    int*            deg3i = (int*)  (ws + O_DEG3I);
    float*          h3    = (float*)(ws + O_H3);

    hipMemsetAsync(ws, 0, Z_END, stream);
    k_neginf<<<(NC2*64 + 255)/256, 256, 0, stream>>>((unsigned int*)xm2, NC2*64);

    k_pass1<<<256, 256, 0, stream>>>(ei, posi, m1, gtot, bb);
    k_gscan<<<1, 256, 0, stream>>>(gtot, goff);
    k_pass2<<<256, 256, 0, stream>>>(ei, goff, bb, be);

    k_graph1<<<NG, 256, 0, stream>>>(be, goff, posi, x, m1, W1, root1, b1,
                                     xp1, pos1g, nv1, adj2, off2s, deg2i, m2);

    k_conv2<<<NC1/8, 256, 0, stream>>>(off2s, deg2i, adj2, pos1g, m2, xp1,
                                       W2, root2, b2, nv1, cl2, cnt2, ps2, xm2);

    k_lvl3<<<NG, 256, 0, stream>>>(off2s, deg2i, adj2, cl2, cnt2, ps2, xm2,
                                   xp2, pos2g, nv2, adj3, off3s, deg3i, m3);

    k_conv3<<<NC2/4, 256, 0, stream>>>(off3s, deg3i, adj3, pos2g, m3, xp2,
                                       W3, root3, b3, h3);

    k_readout<<<256, 128, 0, stream>>>(h3, nv2, fcw, fcb, out);
}

// Round 5
// 300.633 us; speedup vs baseline: 3.7273x; 1.1449x over previous
//
#include <hip/hip_runtime.h>
#include <math.h>

// ---------------- problem constants ----------------
constexpr int NN  = 65536;     // nodes (256 graphs x 256 nodes)
constexpr int EE  = 1048576;   // edges (N * 16)
constexpr int NG  = 256;       // graphs
constexpr int NC1 = 16384;     // clusters after pool1 (256 x 64)
constexpr int NC2 = 4096;      // clusters after pool2 (256 x 16)
constexpr int EPB = EE / 256;  // edges per bucketing block = 4096

// ---------------- workspace layout (bytes) ----------------
// Z region (memset 0 each launch)
constexpr size_t O_SCAL  = 0;                                  // m1,m2,m3
constexpr size_t O_GTOT  = 256;                                // 256 ints
constexpr size_t O_CNT2  = O_GTOT + 1024;                      // NC2 f32
constexpr size_t O_PS2   = O_CNT2 + (size_t)NC2*4;             // NC2*2 f32
constexpr size_t Z_END   = O_PS2  + (size_t)NC2*8;             // 50432
// xm2: memset 0xFF (acts as identity for both atomic-max paths)
constexpr size_t O_XM2   = Z_END;                              // NC2*64 f32
// fully-written-before-read region
constexpr size_t O_GOFF  = O_XM2  + (size_t)NC2*64*4;          // 257 ints (pad)
constexpr size_t O_BB    = O_GOFF + 1280;                      // 256*256 ints
constexpr size_t O_BE    = O_BB   + (size_t)256*256*4;         // EE ushort
constexpr size_t O_XP1   = O_BE   + (size_t)EE*2;              // NC1*32 f32
constexpr size_t O_POS1  = O_XP1  + (size_t)NC1*32*4;          // NC1*2 f32
constexpr size_t O_NV1   = O_POS1 + (size_t)NC1*8;             // NC1 f32
constexpr size_t O_ADJ2  = O_NV1  + (size_t)NC1*4;             // NG*4096 uchar
constexpr size_t O_OFF2S = O_ADJ2 + (size_t)NG*4096;           // NC1 ints
constexpr size_t O_DEG2I = O_OFF2S+ (size_t)NC1*4;             // NC1 ints
constexpr size_t O_CL2   = O_DEG2I+ (size_t)NC1*4;             // NC1 ints
constexpr size_t O_XP2   = O_CL2  + (size_t)NC1*4;             // NC2*64 f32
constexpr size_t O_POS2  = O_XP2  + (size_t)NC2*64*4;          // NC2*2 f32
constexpr size_t O_NV2   = O_POS2 + (size_t)NC2*8;             // NC2 f32
constexpr size_t O_ADJ3  = O_NV2  + (size_t)NC2*4;             // NG*256 uchar
constexpr size_t O_OFF3S = O_ADJ3 + (size_t)NG*256;            // NC2 ints
constexpr size_t O_DEG3I = O_OFF3S+ (size_t)NC2*4;             // NC2 ints
constexpr size_t O_H3    = O_DEG3I+ (size_t)NC2*4;             // NC2*128 f32
constexpr size_t O_W2Q   = O_H3   + (size_t)NC2*128*4;         // 51200 f16
constexpr size_t O_W3Q   = O_W2Q  + 102400;                    // 204800 f16
constexpr size_t O_R2T   = O_W3Q  + 409600;                    // 2048 f32
constexpr size_t O_R3T   = O_R2T  + 8192;                      // 8192 f32

// ---------------- device helpers ----------------
typedef __fp16   pk16x2 __attribute__((ext_vector_type(2)));   // cvt_pkrtz return
typedef _Float16 h16x2  __attribute__((ext_vector_type(2)));   // fdot2 operand

__device__ __forceinline__ float eluf(float x){ return x > 0.f ? x : expm1f(x); }

__device__ __forceinline__ void atomic_max_pos(float* a, float v){
    atomicMax((unsigned int*)a, __float_as_uint(v));
}
// arbitrary-sign float atomic max; target init = 0xFFFFFFFF or -inf bits
__device__ __forceinline__ void atomic_max_f32(float* a, float v){
    unsigned int b = __float_as_uint(v);
    if (b & 0x80000000u) atomicMin((unsigned int*)a, b);
    else                 atomicMax((int*)a, (int)b);
}

__device__ __forceinline__ unsigned int pack2(float a, float b){
    pk16x2 h = __builtin_amdgcn_cvt_pkrtz(a, b);
    return __builtin_bit_cast(unsigned int, h);
}
__device__ __forceinline__ unsigned short f2h(float v){
    pk16x2 h = __builtin_amdgcn_cvt_pkrtz(v, v);
    return (unsigned short)(__builtin_bit_cast(unsigned int, h) & 0xFFFFu);
}
__device__ __forceinline__ float dot2u(unsigned int a, unsigned int b, float c){
#if __has_builtin(__builtin_amdgcn_fdot2)
    return __builtin_amdgcn_fdot2(__builtin_bit_cast(h16x2, a),
                                  __builtin_bit_cast(h16x2, b), c, false);
#else
    h16x2 ha = __builtin_bit_cast(h16x2, a), hb = __builtin_bit_cast(h16x2, b);
    return c + (float)ha[0]*(float)hb[0] + (float)ha[1]*(float)hb[1];
#endif
}

struct Crn { int ix, iy; float fx, fy; };
__device__ __forceinline__ Crn mk_corners(float dx, float dy, float m){
    float inv = 1.0f / (2.0f*m + 1e-12f);
    float vx = (dx*inv + 0.5f) * 4.0f;   // (K1-1)=4
    float vy = (dy*inv + 0.5f) * 4.0f;
    Crn c;
    c.ix = min(max((int)floorf(vx), 0), 3);
    c.iy = min(max((int)floorf(vy), 0), 3);
    c.fx = vx - (float)c.ix;
    c.fy = vy - (float)c.iy;
    return c;
}

#define BLOCK_MAX_AND_ATOMIC(val, dst)                                   \
    {   __shared__ float _s[256];                                        \
        _s[threadIdx.x] = (val); __syncthreads();                        \
        for (int _w = 128; _w > 0; _w >>= 1){                            \
            if (threadIdx.x < _w)                                        \
                _s[threadIdx.x] = fmaxf(_s[threadIdx.x], _s[threadIdx.x+_w]); \
            __syncthreads();                                             \
        }                                                                \
        if (threadIdx.x == 0) atomic_max_pos((dst), _s[0]); }

// ---------------- prep: weight transpose/pack to f16 octets ----------------
// w2q[((k>>3)*64 + o)*8 + (k&7)]  = f16(W2[k*64+o])    (k<800, o<64)
// w3q[((k>>3)*128 + o)*8 + (k&7)] = f16(W3[k*128+o])   (k<1600, o<128)
__global__ __launch_bounds__(256) void k_prep(
        const float* __restrict__ W2, const float* __restrict__ W3,
        const float* __restrict__ root2, const float* __restrict__ root3,
        unsigned short* __restrict__ w2q, unsigned short* __restrict__ w3q,
        float* __restrict__ r2t, float* __restrict__ r3t){
    int idx = blockIdx.x*256 + threadIdx.x;
    if (idx < 51200){
        int k = idx >> 6, o = idx & 63;
        w2q[(size_t)((k>>3)*64 + o)*8 + (k&7)] = f2h(W2[idx]);
    }
    int i3 = idx - 51200;
    if (i3 >= 0 && i3 < 204800){
        int k = i3 >> 7, o = i3 & 127;
        w3q[(size_t)((k>>3)*128 + o)*8 + (k&7)] = f2h(W3[i3]);
    }
    int ir2 = idx - 256000;
    if (ir2 >= 0 && ir2 < 2048){
        int i = ir2 >> 6, o = ir2 & 63;
        r2t[o*32 + i] = root2[ir2];
    }
    int ir3 = idx - 258048;
    if (ir3 >= 0 && ir3 < 8192){
        int i = ir3 >> 7, o = ir3 & 127;
        r3t[o*64 + i] = root3[ir3];
    }
}

// ---------------- bucketing ----------------
__global__ __launch_bounds__(256) void k_pass1(const int* __restrict__ ei,
                                               const float* __restrict__ pos,
                                               float* m1, int* gtot, int* bb){
    __shared__ int h[256];
    h[threadIdx.x] = 0; __syncthreads();
    int base = blockIdx.x * EPB;
    float loc = 0.f;
    for (int i = threadIdx.x; i < EPB; i += 256){
        int e = base + i;
        int r = ei[e], c = ei[EE + e];
        float dx = pos[2*c]   - pos[2*r];
        float dy = pos[2*c+1] - pos[2*r+1];
        loc = fmaxf(loc, fmaxf(fabsf(dx), fabsf(dy)));
        atomicAdd(&h[r >> 8], 1);
    }
    __syncthreads();
    bb[blockIdx.x*256 + threadIdx.x] = atomicAdd(&gtot[threadIdx.x], h[threadIdx.x]);
    BLOCK_MAX_AND_ATOMIC(loc, m1);
}

__global__ void k_gscan(const int* __restrict__ gtot, int* goff){
    __shared__ int s[256];
    int t = threadIdx.x;
    int v0 = gtot[t];
    s[t] = v0; __syncthreads();
    for (int d = 1; d < 256; d <<= 1){
        int u = (t >= d) ? s[t-d] : 0;
        __syncthreads();
        s[t] += u;
        __syncthreads();
    }
    goff[t] = s[t] - v0;
    if (t == 255) goff[256] = s[t];
}

__global__ __launch_bounds__(256) void k_pass2(const int* __restrict__ ei,
                                               const int* __restrict__ goff,
                                               const int* __restrict__ bb,
                                               unsigned short* __restrict__ be){
    __shared__ int cur[256];
    cur[threadIdx.x] = 0; __syncthreads();
    int base = blockIdx.x * EPB;
    for (int i = threadIdx.x; i < EPB; i += 256){
        int e = base + i;
        int r = ei[e], c = ei[EE + e];
        int g = r >> 8;
        int l = atomicAdd(&cur[g], 1);
        be[goff[g] + bb[blockIdx.x*256 + g] + l] =
            (unsigned short)((r & 255) | ((c & 255) << 8));
    }
}

// ---------------- graph1: conv1 + pool1 + lvl2 dedup/CSR + m2, all in LDS ----------
__global__ __launch_bounds__(256) void k_graph1(
        const unsigned short* __restrict__ be, const int* __restrict__ goff,
        const float* __restrict__ pos, const float* __restrict__ x,
        const float* __restrict__ m1p, const float* __restrict__ W1,
        const float* __restrict__ root1, const float* __restrict__ b1,
        float* __restrict__ xp1, float* __restrict__ pos1g, float* __restrict__ nv1,
        unsigned char* __restrict__ adj2b, int* __restrict__ off2s,
        int* __restrict__ deg2i, float* m2p){
    __shared__ float acc[256*25];
    __shared__ float posx[256], posy[256], xL[256];
    __shared__ int   cl1L[256], degL[256];
    __shared__ float sW[800];
    __shared__ unsigned int bitL[128];
    __shared__ float xmL[64*32];
    __shared__ int   cntL[64];
    __shared__ float psx[64], psy[64];
    __shared__ float p1x[64], p1y[64];
    __shared__ int   rpre[64];

    int t = threadIdx.x, g = blockIdx.x;
    for (int i = t; i < 800; i += 256) sW[i] = W1[i];
    for (int i = t; i < 6400; i += 256) acc[i] = 0.f;
    posx[t] = pos[2*(g*256 + t)];
    posy[t] = pos[2*(g*256 + t) + 1];
    xL[t]   = x[g*256 + t];
    degL[t] = 0;
    if (t < 128) bitL[t] = 0u;
    if (t < 64){ cntL[t] = 0; psx[t] = 0.f; psy[t] = 0.f; }
    for (int i = t; i < 2048; i += 256) xmL[i] = -INFINITY;
    {
        int cx = min(max((int)floorf(posx[t]*0.25f), 0), 7);
        int cy = min(max((int)floorf(posy[t]*0.25f), 0), 7);
        cl1L[t] = cx*8 + cy;
    }
    __syncthreads();

    float mm = *m1p;
    int e1 = goff[g+1];
    for (int p = goff[g] + t; p < e1; p += 256){
        unsigned int b = be[p];
        int rl = b & 255, cl = (b >> 8) & 255;
        float dx = posx[cl] - posx[rl], dy = posy[cl] - posy[rl];
        Crn cr = mk_corners(dx, dy, mm);
        float xin = xL[cl];
        int ab = rl*25 + cr.ix*5 + cr.iy;
        atomicAdd(&acc[ab],   (1.f-cr.fx)*(1.f-cr.fy)*xin);
        atomicAdd(&acc[ab+1], (1.f-cr.fx)*cr.fy*xin);
        atomicAdd(&acc[ab+5], cr.fx*(1.f-cr.fy)*xin);
        atomicAdd(&acc[ab+6], cr.fx*cr.fy*xin);
        atomicAdd(&degL[rl], 1);
        int r2 = cl1L[rl], c2 = cl1L[cl];
        if (r2 != c2){
            int bit = r2*64 + c2;
            atomicOr(&bitL[bit >> 5], 1u << (bit & 31));
        }
    }
    __syncthreads();

    {
        float inv = 1.f / fmaxf((float)degL[t], 1.f);
        float xr  = xL[t];
        int   cl  = cl1L[t];
        atomicAdd(&cntL[cl], 1);
        atomicAdd(&psx[cl], posx[t]);
        atomicAdd(&psy[cl], posy[t]);
        for (int o = 0; o < 32; o++){
            float s = 0.f;
            #pragma unroll
            for (int k = 0; k < 25; k++) s += acc[t*25 + k]*sW[k*32 + o];
            float out = eluf(s*inv + xr*root1[o] + b1[o]);
            atomic_max_f32(&xmL[cl*32 + o], out);
        }
    }
    __syncthreads();

    if (t < 64){
        float cnt = (float)cntL[t];
        float inv = 1.f / fmaxf(cnt, 1.f);
        p1x[t] = psx[t]*inv; p1y[t] = psy[t]*inv;
        pos1g[2*(g*64 + t)]     = p1x[t];
        pos1g[2*(g*64 + t) + 1] = p1y[t];
        nv1[g*64 + t] = (cnt > 0.f) ? 1.f : 0.f;
    }
    __syncthreads();
    for (int i = t; i < 2048; i += 256){
        int c = i >> 5;
        xp1[g*2048 + i] = (cntL[c] > 0) ? xmL[i] : 0.f;
    }

    if (t < 64) rpre[t] = __popc(bitL[2*t]) + __popc(bitL[2*t+1]);
    __syncthreads();
    for (int d = 1; d < 64; d <<= 1){
        int v = 0;
        if (t < 64 && t >= d) v = rpre[t-d];
        __syncthreads();
        if (t < 64) rpre[t] += v;
        __syncthreads();
    }
    float m2loc = 0.f;
    if (t < 64){
        unsigned int w0 = bitL[2*t], w1 = bitL[2*t+1];
        int dg = __popc(w0) + __popc(w1);
        int baseo = rpre[t] - dg;
        off2s[g*64 + t] = g*4096 + baseo;
        deg2i[g*64 + t] = dg;
        int j = g*4096 + baseo;
        float rx = p1x[t], ry = p1y[t];
        while (w0){
            int b = __ffs(w0) - 1; w0 &= w0 - 1;
            adj2b[j++] = (unsigned char)b;
            m2loc = fmaxf(m2loc, fmaxf(fabsf(p1x[b]-rx), fabsf(p1y[b]-ry)));
        }
        while (w1){
            int b = __ffs(w1) - 1; w1 &= w1 - 1;
            int c = 32 + b;
            adj2b[j++] = (unsigned char)c;
            m2loc = fmaxf(m2loc, fmaxf(fabsf(p1x[c]-rx), fabsf(p1y[c]-ry)));
        }
    }
    BLOCK_MAX_AND_ATOMIC(m2loc, m2p);
}

// ---------------- conv2: LDS gather + f16 dot2 GEMM + pool2-node ----------------
// 512 threads, 16 clusters/block, 1024 blocks
__global__ __launch_bounds__(512) void k_conv2(
        const int* __restrict__ off2s, const int* __restrict__ deg2i,
        const unsigned char* __restrict__ adj2b, const float* __restrict__ pos1g,
        const float* __restrict__ m2p, const float* __restrict__ xp1,
        const unsigned short* __restrict__ w2q, const float* __restrict__ r2t,
        const float* __restrict__ b2, const float* __restrict__ nv1,
        int* __restrict__ cl2, float* cnt2, float* ps2, float* xm2){
    __shared__ __align__(16) float am[16*800];   // 51.2 KB; f16-packed in place later
    __shared__ __align__(16) float xpL[64*32];   // 8 KB
    __shared__ float p1x[64], p1y[64];
    int t = threadIdx.x;
    int g = blockIdx.x >> 2, sub = blockIdx.x & 3;
    for (int i = t; i < 12800; i += 512) am[i] = 0.f;
    for (int i = t; i < 2048; i += 512) xpL[i] = xp1[g*2048 + i];
    if (t < 64){ p1x[t] = pos1g[2*(g*64+t)]; p1y[t] = pos1g[2*(g*64+t)+1]; }
    __syncthreads();
    int grp = t >> 5, lane = t & 31;      // 16 groups x 32 lanes
    {
        int rl = sub*16 + grp;
        int r  = g*64 + rl;
        int s0 = off2s[r], n = deg2i[r];
        float rx = p1x[rl], ry = p1y[rl];
        float mm = *m2p;
        float* a = &am[grp*800];
        for (int j = 0; j < n; ++j){
            int cLoc = adj2b[s0 + j];
            float dx = p1x[cLoc] - rx, dy = p1y[cLoc] - ry;
            Crn cr = mk_corners(dx, dy, mm);
            float xin = xpL[cLoc*32 + lane];
            int b = (cr.ix*5 + cr.iy)*32 + lane;
            a[b]     += (1.f-cr.fx)*(1.f-cr.fy)*xin;
            a[b+32]  += (1.f-cr.fx)*cr.fy*xin;
            a[b+160] += cr.fx*(1.f-cr.fy)*xin;
            a[b+192] += cr.fx*cr.fy*xin;
        }
    }
    __syncthreads();
    // in-place f32 -> packed f16: 16 rows x 400 u32 = 6400
    unsigned int* amu = (unsigned int*)am;
    {
        unsigned int tmpv[13];
        #pragma unroll
        for (int j = 0; j < 13; j++){
            int i = t + j*512;
            if (i < 6400){
                int row = i/400, kp = i - row*400;
                tmpv[j] = pack2(am[row*800 + 2*kp], am[row*800 + 2*kp + 1]);
            }
        }
        __syncthreads();
        #pragma unroll
        for (int j = 0; j < 13; j++){
            int i = t + j*512;
            if (i < 6400) amu[i] = tmpv[j];
        }
        __syncthreads();
    }
    // GEMM: o = t&63, mg = t>>6 (0..7) -> rows mg, mg+8
    int o = t & 63, mg = t >> 6;
    const unsigned int* a0 = amu + mg*400;
    const unsigned int* a1 = amu + (mg+8)*400;
    const uint4* wq = (const uint4*)w2q;
    float sA0=0.f, sA1=0.f, sB0=0.f, sB1=0.f;
    for (int kp8 = 0; kp8 < 100; kp8++){
        uint4 wv = wq[kp8*64 + o];
        uint4 av = *(const uint4*)(a0 + kp8*4);
        uint4 bv = *(const uint4*)(a1 + kp8*4);
        sA0 = dot2u(av.x, wv.x, sA0); sA1 = dot2u(av.y, wv.y, sA1);
        sA0 = dot2u(av.z, wv.z, sA0); sA1 = dot2u(av.w, wv.w, sA1);
        sB0 = dot2u(bv.x, wv.x, sB0); sB1 = dot2u(bv.y, wv.y, sB1);
        sB0 = dot2u(bv.z, wv.z, sB0); sB1 = dot2u(bv.w, wv.w, sB1);
    }
    float sAB[2] = {sA0 + sA1, sB0 + sB1};
    #pragma unroll
    for (int h = 0; h < 2; ++h){
        int rl = sub*16 + mg + h*8;
        int rr = g*64 + rl;
        float s  = sAB[h];
        float dg = fmaxf((float)deg2i[rr], 1.f);
        float rt = 0.f;
        #pragma unroll
        for (int i = 0; i < 32; i += 4){
            float4 rv = *(const float4*)&r2t[o*32 + i];
            float4 xv = *(const float4*)&xpL[rl*32 + i];
            rt += rv.x*xv.x + rv.y*xv.y + rv.z*xv.z + rv.w*xv.w;
        }
        float val = eluf(s/dg + rt + b2[o]);
        float px = p1x[rl], py = p1y[rl];
        int cx = min(max((int)floorf(px*0.125f), 0), 3);
        int cy = min(max((int)floorf(py*0.125f), 0), 3);
        int cl = g*16 + cx*4 + cy;
        if (o == 0) cl2[rr] = cl;
        if (nv1[rr] > 0.f){
            if (o == 0){
                atomicAdd(&cnt2[cl], 1.f);
                atomicAdd(&ps2[2*cl],   px);
                atomicAdd(&ps2[2*cl+1], py);
            }
            atomic_max_f32(&xm2[cl*64 + o], val);
        }
    }
}

// ---------------- lvl3: pool2-finish + lvl3 dedup/CSR + m3, per graph ----------------
__global__ __launch_bounds__(256) void k_lvl3(
        const int* __restrict__ off2s, const int* __restrict__ deg2i,
        const unsigned char* __restrict__ adj2b, const int* __restrict__ cl2,
        const float* __restrict__ cnt2, const float* __restrict__ ps2,
        const float* __restrict__ xm2,
        float* __restrict__ xp2, float* __restrict__ pos2g, float* __restrict__ nv2,
        unsigned char* __restrict__ adj3b, int* __restrict__ off3s,
        int* __restrict__ deg3i, float* m3p){
    __shared__ int cl2L[64];
    __shared__ unsigned int bit3[8];
    __shared__ float p2x[16], p2y[16];
    __shared__ int rpre[16];
    int t = threadIdx.x, g = blockIdx.x;
    if (t < 64) cl2L[t] = cl2[g*64 + t] & 15;
    if (t < 8)  bit3[t] = 0u;
    if (t < 16){
        float cnt = cnt2[g*16 + t];
        float inv = 1.f / fmaxf(cnt, 1.f);
        p2x[t] = ps2[2*(g*16+t)]*inv;
        p2y[t] = ps2[2*(g*16+t)+1]*inv;
        pos2g[2*(g*16+t)]   = p2x[t];
        pos2g[2*(g*16+t)+1] = p2y[t];
        nv2[g*16 + t] = (cnt > 0.f) ? 1.f : 0.f;
    }
    for (int i = t; i < 1024; i += 256){
        int c = i >> 6;
        xp2[g*1024 + i] = (cnt2[g*16 + c] > 0.f) ? xm2[g*1024 + i] : 0.f;
    }
    __syncthreads();
    if (t < 64){
        int s0 = off2s[g*64 + t], n = deg2i[g*64 + t];
        int r3 = cl2L[t];
        for (int j = 0; j < n; ++j){
            int c3 = cl2L[adj2b[s0 + j]];
            if (r3 != c3){
                int bit = r3*16 + c3;
                atomicOr(&bit3[bit >> 5], 1u << (bit & 31));
            }
        }
    }
    __syncthreads();
    if (t < 16)
        rpre[t] = __popc((bit3[t >> 1] >> ((t & 1)*16)) & 0xFFFFu);
    __syncthreads();
    for (int d = 1; d < 16; d <<= 1){
        int v = 0;
        if (t < 16 && t >= d) v = rpre[t-d];
        __syncthreads();
        if (t < 16) rpre[t] += v;
        __syncthreads();
    }
    float m3loc = 0.f;
    if (t < 16){
        unsigned int w = (bit3[t >> 1] >> ((t & 1)*16)) & 0xFFFFu;
        int dg = __popc(w);
        int baseo = rpre[t] - dg;
        off3s[g*16 + t] = g*256 + baseo;
        deg3i[g*16 + t] = dg;
        int j = g*256 + baseo;
        float rx = p2x[t], ry = p2y[t];
        while (w){
            int b = __ffs(w) - 1; w &= w - 1;
            adj3b[j++] = (unsigned char)b;
            m3loc = fmaxf(m3loc, fmaxf(fabsf(p2x[b]-rx), fabsf(p2y[b]-ry)));
        }
    }
    BLOCK_MAX_AND_ATOMIC(m3loc, m3p);
}

// ---------------- conv3: LDS gather + f16 dot2 GEMM ----------------
// 512 threads, 8 clusters/block, 512 blocks
__global__ __launch_bounds__(512) void k_conv3(
        const int* __restrict__ off3s, const int* __restrict__ deg3i,
        const unsigned char* __restrict__ adj3b, const float* __restrict__ pos2g,
        const float* __restrict__ m3p, const float* __restrict__ xp2,
        const unsigned short* __restrict__ w3q, const float* __restrict__ r3t,
        const float* __restrict__ b3, float* __restrict__ h3){
    __shared__ __align__(16) float am[8*1600];   // 51.2 KB
    __shared__ __align__(16) float xpL[16*64];   // 4 KB
    __shared__ float p2x[16], p2y[16];
    int t = threadIdx.x;
    int g = blockIdx.x >> 1, sub = blockIdx.x & 1;
    for (int i = t; i < 12800; i += 512) am[i] = 0.f;
    for (int i = t; i < 1024; i += 512) xpL[i] = xp2[g*1024 + i];
    if (t < 16){ p2x[t] = pos2g[2*(g*16+t)]; p2y[t] = pos2g[2*(g*16+t)+1]; }
    __syncthreads();
    int grp = t >> 6, lane = t & 63;      // 8 groups x 64 lanes
    {
        int rl = sub*8 + grp;
        int r  = g*16 + rl;
        int s0 = off3s[r], n = deg3i[r];
        float rx = p2x[rl], ry = p2y[rl];
        float mm = *m3p;
        float* a = &am[grp*1600];
        for (int j = 0; j < n; ++j){
            int cLoc = adj3b[s0 + j];
            float dx = p2x[cLoc] - rx, dy = p2y[cLoc] - ry;
            Crn cr = mk_corners(dx, dy, mm);
            float xin = xpL[cLoc*64 + lane];
            int b = (cr.ix*5 + cr.iy)*64 + lane;
            a[b]     += (1.f-cr.fx)*(1.f-cr.fy)*xin;
            a[b+64]  += (1.f-cr.fx)*cr.fy*xin;
            a[b+320] += cr.fx*(1.f-cr.fy)*xin;
            a[b+384] += cr.fx*cr.fy*xin;
        }
    }
    __syncthreads();
    // in-place f32 -> packed f16: 8 rows x 800 u32 = 6400
    unsigned int* amu = (unsigned int*)am;
    {
        unsigned int tmpv[13];
        #pragma unroll
        for (int j = 0; j < 13; j++){
            int i = t + j*512;
            if (i < 6400){
                int row = i/800, kp = i - row*800;
                tmpv[j] = pack2(am[row*1600 + 2*kp], am[row*1600 + 2*kp + 1]);
            }
        }
        __syncthreads();
        #pragma unroll
        for (int j = 0; j < 13; j++){
            int i = t + j*512;
            if (i < 6400) amu[i] = tmpv[j];
        }
        __syncthreads();
    }
    // GEMM: o = t&127, mg = t>>7 (0..3) -> rows mg, mg+4
    int o = t & 127, mg = t >> 7;
    const unsigned int* a0 = amu + mg*800;
    const unsigned int* a1 = amu + (mg+4)*800;
    const uint4* wq = (const uint4*)w3q;
    float sA0=0.f, sA1=0.f, sB0=0.f, sB1=0.f;
    for (int kp8 = 0; kp8 < 200; kp8++){
        uint4 wv = wq[kp8*128 + o];
        uint4 av = *(const uint4*)(a0 + kp8*4);
        uint4 bv = *(const uint4*)(a1 + kp8*4);
        sA0 = dot2u(av.x, wv.x, sA0); sA1 = dot2u(av.y, wv.y, sA1);
        sA0 = dot2u(av.z, wv.z, sA0); sA1 = dot2u(av.w, wv.w, sA1);
        sB0 = dot2u(bv.x, wv.x, sB0); sB1 = dot2u(bv.y, wv.y, sB1);
        sB0 = dot2u(bv.z, wv.z, sB0); sB1 = dot2u(bv.w, wv.w, sB1);
    }
    float sAB[2] = {sA0 + sA1, sB0 + sB1};
    #pragma unroll
    for (int h = 0; h < 2; ++h){
        int rl = sub*8 + mg + h*4;
        int rr = g*16 + rl;
        float s  = sAB[h];
        float dg = fmaxf((float)deg3i[rr], 1.f);
        float rt = 0.f;
        #pragma unroll
        for (int i = 0; i < 64; i += 4){
            float4 rv = *(const float4*)&r3t[o*64 + i];
            float4 xv = *(const float4*)&xpL[rl*64 + i];
            rt += rv.x*xv.x + rv.y*xv.y + rv.z*xv.z + rv.w*xv.w;
        }
        h3[rr*128 + o] = eluf(s/dg + rt + b3[o]);
    }
}

__global__ void k_readout(const float* __restrict__ h3, const float* __restrict__ nv2,
                          const float* __restrict__ fcw, const float* __restrict__ fcb,
                          float* out){
    int g = blockIdx.x, t = threadIdx.x;     // 128 threads
    __shared__ float gf[128];
    __shared__ float lg[10];
    __shared__ float lse;
    float s = 0.f, cnt = 0.f;
    for (int j = 0; j < 16; j++){
        int c = g*16 + j;
        float nv = nv2[c];
        s += h3[c*128 + t] * nv;
        cnt += nv;
    }
    gf[t] = s / fmaxf(cnt, 1.f);
    __syncthreads();
    if (t < 10){
        float l = fcb[t];
        for (int f = 0; f < 128; f++) l += gf[f]*fcw[f*10 + t];
        lg[t] = l;
    }
    __syncthreads();
    if (t == 0){
        float mx = -INFINITY;
        for (int o = 0; o < 10; o++) mx = fmaxf(mx, lg[o]);
        float ss = 0.f;
        for (int o = 0; o < 10; o++) ss += expf(lg[o] - mx);
        lse = mx + logf(ss);
    }
    __syncthreads();
    if (t < 10) out[g*10 + t] = lg[t] - lse;
}

// ---------------- launch ----------------
extern "C" void kernel_launch(void* const* d_in, const int* in_sizes, int n_in,
                              void* d_out, int out_size, void* d_ws, size_t ws_size,
                              hipStream_t stream){
    const float* x     = (const float*)d_in[0];
    const float* posi  = (const float*)d_in[1];
    const int*   ei    = (const int*)  d_in[2];
    const float* W1    = (const float*)d_in[4];
    const float* root1 = (const float*)d_in[5];
    const float* b1    = (const float*)d_in[6];
    const float* W2    = (const float*)d_in[7];
    const float* root2 = (const float*)d_in[8];
    const float* b2    = (const float*)d_in[9];
    const float* W3    = (const float*)d_in[10];
    const float* root3 = (const float*)d_in[11];
    const float* b3    = (const float*)d_in[12];
    const float* fcw   = (const float*)d_in[13];
    const float* fcb   = (const float*)d_in[14];
    float* out = (float*)d_out;

    char* ws = (char*)d_ws;
    float*          m1    = (float*)(ws + O_SCAL);
    float*          m2    = m1 + 1;
    float*          m3    = m1 + 2;
    int*            gtot  = (int*)  (ws + O_GTOT);
    float*          cnt2  = (float*)(ws + O_CNT2);
    float*          ps2   = (float*)(ws + O_PS2);
    float*          xm2   = (float*)(ws + O_XM2);
    int*            goff  = (int*)  (ws + O_GOFF);
    int*            bb    = (int*)  (ws + O_BB);
    unsigned short* be    = (unsigned short*)(ws + O_BE);
    float*          xp1   = (float*)(ws + O_XP1);
    float*          pos1g = (float*)(ws + O_POS1);
    float*          nv1   = (float*)(ws + O_NV1);
    unsigned char*  adj2b = (unsigned char*)(ws + O_ADJ2);
    int*            off2s = (int*)  (ws + O_OFF2S);
    int*            deg2i = (int*)  (ws + O_DEG2I);
    int*            cl2   = (int*)  (ws + O_CL2);
    float*          xp2   = (float*)(ws + O_XP2);
    float*          pos2g = (float*)(ws + O_POS2);
    float*          nv2   = (float*)(ws + O_NV2);
    unsigned char*  adj3b = (unsigned char*)(ws + O_ADJ3);
    int*            off3s = (int*)  (ws + O_OFF3S);
    int*            deg3i = (int*)  (ws + O_DEG3I);
    float*          h3    = (float*)(ws + O_H3);
    unsigned short* w2q   = (unsigned short*)(ws + O_W2Q);
    unsigned short* w3q   = (unsigned short*)(ws + O_W3Q);
    float*          r2t   = (float*)(ws + O_R2T);
    float*          r3t   = (float*)(ws + O_R3T);

    hipMemsetAsync(ws, 0, Z_END, stream);
    hipMemsetAsync(xm2, 0xFF, (size_t)NC2*64*4, stream);   // identity for atomic max

    k_prep<<<1040, 256, 0, stream>>>(W2, W3, root2, root3, w2q, w3q, r2t, r3t);
    k_pass1<<<256, 256, 0, stream>>>(ei, posi, m1, gtot, bb);
    k_gscan<<<1, 256, 0, stream>>>(gtot, goff);
    k_pass2<<<256, 256, 0, stream>>>(ei, goff, bb, be);

    k_graph1<<<NG, 256, 0, stream>>>(be, goff, posi, x, m1, W1, root1, b1,
                                     xp1, pos1g, nv1, adj2b, off2s, deg2i, m2);

    k_conv2<<<NC1/16, 512, 0, stream>>>(off2s, deg2i, adj2b, pos1g, m2, xp1,
                                        w2q, r2t, b2, nv1, cl2, cnt2, ps2, xm2);

    k_lvl3<<<NG, 256, 0, stream>>>(off2s, deg2i, adj2b, cl2, cnt2, ps2, xm2,
                                   xp2, pos2g, nv2, adj3b, off3s, deg3i, m3);

    k_conv3<<<NC2/8, 512, 0, stream>>>(off3s, deg3i, adj3b, pos2g, m3, xp2,
                                       w3q, r3t, b3, h3);

    k_readout<<<256, 128, 0, stream>>>(h3, nv2, fcw, fcb, out);
}

// Round 6
// 290.230 us; speedup vs baseline: 3.8609x; 1.0358x over previous
//
#include <hip/hip_runtime.h>
#include <math.h>

// ---------------- problem constants ----------------
constexpr int NN  = 65536;     // nodes (256 graphs x 256 nodes)
constexpr int EE  = 1048576;   // edges (N * 16)
constexpr int NG  = 256;       // graphs
constexpr int NC1 = 16384;     // clusters after pool1 (256 x 64)
constexpr int NC2 = 4096;      // clusters after pool2 (256 x 16)
constexpr int EPB = EE / 256;  // edges per bucketing block = 4096

// ---------------- workspace layout (bytes) ----------------
// Z region (memset 0 each launch)
constexpr size_t O_SCAL  = 0;                                  // m1,m2,m3
constexpr size_t O_GTOT  = 256;                                // 256 ints
constexpr size_t O_CNT2  = O_GTOT + 1024;                      // NC2 f32
constexpr size_t O_PS2   = O_CNT2 + (size_t)NC2*4;             // NC2*2 f32
constexpr size_t Z_END   = O_PS2  + (size_t)NC2*8;             // 50432
// xm2: memset 0xFF (identity for both atomic-max paths)
constexpr size_t O_XM2   = Z_END;                              // NC2*64 f32
// fully-written-before-read region
constexpr size_t O_GOFF  = O_XM2  + (size_t)NC2*64*4;          // 257 ints (pad)
constexpr size_t O_BB    = O_GOFF + 1280;                      // 256*256 ints
constexpr size_t O_BE    = O_BB   + (size_t)256*256*4;         // EE ushort
constexpr size_t O_XP1   = O_BE   + (size_t)EE*2;              // NC1*32 f32
constexpr size_t O_POS1  = O_XP1  + (size_t)NC1*32*4;          // NC1*2 f32
constexpr size_t O_NV1   = O_POS1 + (size_t)NC1*8;             // NC1 f32
constexpr size_t O_ADJ2  = O_NV1  + (size_t)NC1*4;             // NG*4096 uchar
constexpr size_t O_OFF2S = O_ADJ2 + (size_t)NG*4096;           // NC1 ints
constexpr size_t O_DEG2I = O_OFF2S+ (size_t)NC1*4;             // NC1 ints
constexpr size_t O_CL2   = O_DEG2I+ (size_t)NC1*4;             // NC1 ints
constexpr size_t O_XP2   = O_CL2  + (size_t)NC1*4;             // NC2*64 f32
constexpr size_t O_POS2  = O_XP2  + (size_t)NC2*64*4;          // NC2*2 f32
constexpr size_t O_NV2   = O_POS2 + (size_t)NC2*8;             // NC2 f32
constexpr size_t O_ADJ3  = O_NV2  + (size_t)NC2*4;             // NG*256 uchar
constexpr size_t O_OFF3S = O_ADJ3 + (size_t)NG*256;            // NC2 ints
constexpr size_t O_DEG3I = O_OFF3S+ (size_t)NC2*4;             // NC2 ints
constexpr size_t O_H3    = O_DEG3I+ (size_t)NC2*4;             // NC2*128 f32
constexpr size_t O_W2Q   = O_H3   + (size_t)NC2*128*4;         // 51200 f16
constexpr size_t O_W3Q   = O_W2Q  + 102400;                    // 204800 f16
constexpr size_t O_R2T   = O_W3Q  + 409600;                    // 2048 f32
constexpr size_t O_R3T   = O_R2T  + 8192;                      // 8192 f32

// ---------------- device helpers ----------------
typedef __fp16   pk16x2 __attribute__((ext_vector_type(2)));   // cvt_pkrtz return
typedef _Float16 h16x2  __attribute__((ext_vector_type(2)));   // fdot2 operand

__device__ __forceinline__ float eluf(float x){ return x > 0.f ? x : expm1f(x); }

__device__ __forceinline__ void atomic_max_pos(float* a, float v){
    atomicMax((unsigned int*)a, __float_as_uint(v));
}
// arbitrary-sign float atomic max; target init = 0xFFFFFFFF or -inf bits
__device__ __forceinline__ void atomic_max_f32(float* a, float v){
    unsigned int b = __float_as_uint(v);
    if (b & 0x80000000u) atomicMin((unsigned int*)a, b);
    else                 atomicMax((int*)a, (int)b);
}

__device__ __forceinline__ unsigned int pack2(float a, float b){
    pk16x2 h = __builtin_amdgcn_cvt_pkrtz(a, b);
    return __builtin_bit_cast(unsigned int, h);
}
__device__ __forceinline__ unsigned short f2h(float v){
    pk16x2 h = __builtin_amdgcn_cvt_pkrtz(v, v);
    return (unsigned short)(__builtin_bit_cast(unsigned int, h) & 0xFFFFu);
}
__device__ __forceinline__ float dot2u(unsigned int a, unsigned int b, float c){
#if __has_builtin(__builtin_amdgcn_fdot2)
    return __builtin_amdgcn_fdot2(__builtin_bit_cast(h16x2, a),
                                  __builtin_bit_cast(h16x2, b), c, false);
#else
    h16x2 ha = __builtin_bit_cast(h16x2, a), hb = __builtin_bit_cast(h16x2, b);
    return c + (float)ha[0]*(float)hb[0] + (float)ha[1]*(float)hb[1];
#endif
}

struct Crn { int ix, iy; float fx, fy; };
__device__ __forceinline__ Crn mk_corners(float dx, float dy, float m){
    float inv = 1.0f / (2.0f*m + 1e-12f);
    float vx = (dx*inv + 0.5f) * 4.0f;   // (K1-1)=4
    float vy = (dy*inv + 0.5f) * 4.0f;
    Crn c;
    c.ix = min(max((int)floorf(vx), 0), 3);
    c.iy = min(max((int)floorf(vy), 0), 3);
    c.fx = vx - (float)c.ix;
    c.fy = vy - (float)c.iy;
    return c;
}

#define BLOCK_MAX_AND_ATOMIC(val, dst)                                   \
    {   __shared__ float _s[256];                                        \
        _s[threadIdx.x] = (val); __syncthreads();                        \
        for (int _w = 128; _w > 0; _w >>= 1){                            \
            if (threadIdx.x < _w)                                        \
                _s[threadIdx.x] = fmaxf(_s[threadIdx.x], _s[threadIdx.x+_w]); \
            __syncthreads();                                             \
        }                                                                \
        if (threadIdx.x == 0) atomic_max_pos((dst), _s[0]); }

// ---------------- pass1 (+fused weight prep in extra blocks) ----------------
// blocks [0,256): m1 max + per-graph histogram + per-block bin bases
// blocks [256,1296): weight transpose/pack (w2q/w3q/r2t/r3t)
__global__ __launch_bounds__(256) void k_pass1(
        const int* __restrict__ ei, const float* __restrict__ pos,
        float* m1, int* gtot, int* bb,
        const float* __restrict__ W2, const float* __restrict__ W3,
        const float* __restrict__ root2, const float* __restrict__ root3,
        unsigned short* __restrict__ w2q, unsigned short* __restrict__ w3q,
        float* __restrict__ r2t, float* __restrict__ r3t){
    __shared__ int h[256];
    if (blockIdx.x >= 256){
        int idx = (blockIdx.x - 256)*256 + threadIdx.x;
        if (idx < 51200){
            int k = idx >> 6, o = idx & 63;
            w2q[(size_t)((k>>3)*64 + o)*8 + (k&7)] = f2h(W2[idx]);
        }
        int i3 = idx - 51200;
        if (i3 >= 0 && i3 < 204800){
            int k = i3 >> 7, o = i3 & 127;
            w3q[(size_t)((k>>3)*128 + o)*8 + (k&7)] = f2h(W3[i3]);
        }
        int ir2 = idx - 256000;
        if (ir2 >= 0 && ir2 < 2048){
            int i = ir2 >> 6, o = ir2 & 63;
            r2t[o*32 + i] = root2[ir2];
        }
        int ir3 = idx - 258048;
        if (ir3 >= 0 && ir3 < 8192){
            int i = ir3 >> 7, o = ir3 & 127;
            r3t[o*64 + i] = root3[ir3];
        }
        return;
    }
    h[threadIdx.x] = 0; __syncthreads();
    int base = blockIdx.x * EPB;
    float loc = 0.f;
    for (int i = threadIdx.x; i < EPB; i += 256){
        int e = base + i;
        int r = ei[e], c = ei[EE + e];
        float dx = pos[2*c]   - pos[2*r];
        float dy = pos[2*c+1] - pos[2*r+1];
        loc = fmaxf(loc, fmaxf(fabsf(dx), fabsf(dy)));
        atomicAdd(&h[r >> 8], 1);
    }
    __syncthreads();
    bb[blockIdx.x*256 + threadIdx.x] = atomicAdd(&gtot[threadIdx.x], h[threadIdx.x]);
    BLOCK_MAX_AND_ATOMIC(loc, m1);
}

__global__ void k_gscan(const int* __restrict__ gtot, int* goff){
    __shared__ int s[256];
    int t = threadIdx.x;
    int v0 = gtot[t];
    s[t] = v0; __syncthreads();
    for (int d = 1; d < 256; d <<= 1){
        int u = (t >= d) ? s[t-d] : 0;
        __syncthreads();
        s[t] += u;
        __syncthreads();
    }
    goff[t] = s[t] - v0;
    if (t == 255) goff[256] = s[t];
}

__global__ __launch_bounds__(256) void k_pass2(const int* __restrict__ ei,
                                               const int* __restrict__ goff,
                                               const int* __restrict__ bb,
                                               unsigned short* __restrict__ be){
    __shared__ int cur[256];
    cur[threadIdx.x] = 0; __syncthreads();
    int base = blockIdx.x * EPB;
    for (int i = threadIdx.x; i < EPB; i += 256){
        int e = base + i;
        int r = ei[e], c = ei[EE + e];
        int g = r >> 8;
        int l = atomicAdd(&cur[g], 1);
        be[goff[g] + bb[blockIdx.x*256 + g] + l] =
            (unsigned short)((r & 255) | ((c & 255) << 8));
    }
}

// ---------------- graph1: conv1 + pool1 + lvl2 dedup/CSR + m2 (1024 thr) --------
__global__ __launch_bounds__(1024) void k_graph1(
        const unsigned short* __restrict__ be, const int* __restrict__ goff,
        const float* __restrict__ pos, const float* __restrict__ x,
        const float* __restrict__ m1p, const float* __restrict__ W1,
        const float* __restrict__ root1, const float* __restrict__ b1,
        float* __restrict__ xp1, float* __restrict__ pos1g, float* __restrict__ nv1,
        unsigned char* __restrict__ adj2b, int* __restrict__ off2s,
        int* __restrict__ deg2i, float* m2p){
    __shared__ float acc[256*25];
    __shared__ float posx[256], posy[256], xL[256];
    __shared__ int   cl1L[256], degL[256];
    __shared__ float sW[800];
    __shared__ unsigned int bitL[128];
    __shared__ float xmL[64*32];
    __shared__ int   cntL[64];
    __shared__ float psx[64], psy[64];
    __shared__ float p1x[64], p1y[64];
    __shared__ int   rpre[64];
    __shared__ float mred[64];

    int t = threadIdx.x, g = blockIdx.x;
    if (t < 800) sW[t] = W1[t];
    for (int i = t; i < 6400; i += 1024) acc[i] = 0.f;
    if (t < 256){
        float px = pos[2*(g*256 + t)], py = pos[2*(g*256 + t) + 1];
        posx[t] = px; posy[t] = py;
        xL[t]   = x[g*256 + t];
        degL[t] = 0;
        int cx = min(max((int)floorf(px*0.25f), 0), 7);
        int cy = min(max((int)floorf(py*0.25f), 0), 7);
        cl1L[t] = cx*8 + cy;
    }
    if (t < 128) bitL[t] = 0u;
    if (t < 64){ cntL[t] = 0; psx[t] = 0.f; psy[t] = 0.f; }
    for (int i = t; i < 2048; i += 1024) xmL[i] = -INFINITY;
    __syncthreads();

    // edge pass: conv1 accumulate + deg + lvl2 bitmap (LDS atomics, no-return)
    float mm = *m1p;
    int e1 = goff[g+1];
    for (int p = goff[g] + t; p < e1; p += 1024){
        unsigned int b = be[p];
        int rl = b & 255, cl = (b >> 8) & 255;
        float dx = posx[cl] - posx[rl], dy = posy[cl] - posy[rl];
        Crn cr = mk_corners(dx, dy, mm);
        float xin = xL[cl];
        int ab = rl*25 + cr.ix*5 + cr.iy;
        atomicAdd(&acc[ab],   (1.f-cr.fx)*(1.f-cr.fy)*xin);
        atomicAdd(&acc[ab+1], (1.f-cr.fx)*cr.fy*xin);
        atomicAdd(&acc[ab+5], cr.fx*(1.f-cr.fy)*xin);
        atomicAdd(&acc[ab+6], cr.fx*cr.fy*xin);
        atomicAdd(&degL[rl], 1);
        int r2 = cl1L[rl], c2 = cl1L[cl];
        if (r2 != c2){
            int bit = r2*64 + c2;
            atomicOr(&bitL[bit >> 5], 1u << (bit & 31));
        }
    }
    __syncthreads();

    // node finish: 4 threads per node, 8 outputs each
    {
        int n = t >> 2, q = t & 3;
        float accR[25];
        #pragma unroll
        for (int k = 0; k < 25; k++) accR[k] = acc[n*25 + k];
        float inv = 1.f / fmaxf((float)degL[n], 1.f);
        float xr  = xL[n];
        int   cl  = cl1L[n];
        if (q == 0){
            atomicAdd(&cntL[cl], 1);
            atomicAdd(&psx[cl], posx[n]);
            atomicAdd(&psy[cl], posy[n]);
        }
        #pragma unroll
        for (int oo = 0; oo < 8; oo++){
            int o = q*8 + oo;
            float s = 0.f;
            #pragma unroll
            for (int k = 0; k < 25; k++) s += accR[k]*sW[k*32 + o];
            float out = eluf(s*inv + xr*root1[o] + b1[o]);
            atomic_max_f32(&xmL[cl*32 + o], out);
        }
    }
    __syncthreads();

    if (t < 64){
        float cnt = (float)cntL[t];
        float inv = 1.f / fmaxf(cnt, 1.f);
        p1x[t] = psx[t]*inv; p1y[t] = psy[t]*inv;
        pos1g[2*(g*64 + t)]     = p1x[t];
        pos1g[2*(g*64 + t) + 1] = p1y[t];
        nv1[g*64 + t] = (cnt > 0.f) ? 1.f : 0.f;
    }
    __syncthreads();
    for (int i = t; i < 2048; i += 1024){
        int c = i >> 5;
        xp1[g*2048 + i] = (cntL[c] > 0) ? xmL[i] : 0.f;
    }

    // CSR2 emit + m2
    if (t < 64) rpre[t] = __popc(bitL[2*t]) + __popc(bitL[2*t+1]);
    __syncthreads();
    for (int d = 1; d < 64; d <<= 1){
        int v = 0;
        if (t < 64 && t >= d) v = rpre[t-d];
        __syncthreads();
        if (t < 64) rpre[t] += v;
        __syncthreads();
    }
    float m2loc = 0.f;
    if (t < 64){
        unsigned int w0 = bitL[2*t], w1 = bitL[2*t+1];
        int dg = __popc(w0) + __popc(w1);
        int baseo = rpre[t] - dg;
        off2s[g*64 + t] = g*4096 + baseo;
        deg2i[g*64 + t] = dg;
        int j = g*4096 + baseo;
        float rx = p1x[t], ry = p1y[t];
        while (w0){
            int b = __ffs(w0) - 1; w0 &= w0 - 1;
            adj2b[j++] = (unsigned char)b;
            m2loc = fmaxf(m2loc, fmaxf(fabsf(p1x[b]-rx), fabsf(p1y[b]-ry)));
        }
        while (w1){
            int b = __ffs(w1) - 1; w1 &= w1 - 1;
            int c = 32 + b;
            adj2b[j++] = (unsigned char)c;
            m2loc = fmaxf(m2loc, fmaxf(fabsf(p1x[c]-rx), fabsf(p1y[c]-ry)));
        }
        mred[t] = m2loc;
    }
    __syncthreads();
    if (t == 0){
        float v = mred[0];
        for (int i = 1; i < 64; i++) v = fmaxf(v, mred[i]);
        atomic_max_pos(m2p, v);
    }
}

// ---------------- conv2: register gather + f16 dot2 GEMM + pool2-node ------------
// 512 threads, 16 clusters/block, 1024 blocks. LDS ~34 KB.
__global__ __launch_bounds__(512) void k_conv2(
        const int* __restrict__ off2s, const int* __restrict__ deg2i,
        const unsigned char* __restrict__ adj2b, const float* __restrict__ pos1g,
        const float* __restrict__ m2p, const float* __restrict__ xp1,
        const unsigned short* __restrict__ w2q, const float* __restrict__ r2t,
        const float* __restrict__ b2, const float* __restrict__ nv1,
        int* __restrict__ cl2, float* cnt2, float* ps2, float* xm2){
    __shared__ __align__(16) unsigned int amu[16*400];   // f16-packed acc, 25.6 KB
    __shared__ __align__(16) float xpL[64*32];           // 8 KB
    __shared__ float p1x[64], p1y[64];
    int t = threadIdx.x;
    int g = blockIdx.x >> 2, sub = blockIdx.x & 3;
    for (int i = t; i < 2048; i += 512) xpL[i] = xp1[g*2048 + i];
    if (t < 64){ p1x[t] = pos1g[2*(g*64+t)]; p1y[t] = pos1g[2*(g*64+t)+1]; }
    __syncthreads();
    int grp = t >> 5, lane = t & 31;      // 16 groups x 32 lanes
    {
        int rl = sub*16 + grp;
        int r  = g*64 + rl;
        int s0 = off2s[r], n = deg2i[r];
        float rx = p1x[rl], ry = p1y[rl];
        float mm = *m2p;
        float inv = 1.0f / (2.0f*mm + 1e-12f);
        float acc[25];
        #pragma unroll
        for (int k = 0; k < 25; k++) acc[k] = 0.f;
        for (int j = 0; j < n; ++j){
            int cLoc = adj2b[s0 + j];
            float vx = ((p1x[cLoc] - rx)*inv + 0.5f)*4.0f;
            float vy = ((p1y[cLoc] - ry)*inv + 0.5f)*4.0f;
            float xin = xpL[cLoc*32 + lane];
            float wxx[5], wy[5];
            #pragma unroll
            for (int k = 0; k < 5; k++){
                wxx[k] = fmaxf(0.f, 1.f - fabsf(vx - (float)k)) * xin;
                wy[k]  = fmaxf(0.f, 1.f - fabsf(vy - (float)k));
            }
            #pragma unroll
            for (int kx = 0; kx < 5; kx++)
                #pragma unroll
                for (int ky = 0; ky < 5; ky++)
                    acc[kx*5+ky] = fmaf(wxx[kx], wy[ky], acc[kx*5+ky]);
        }
        // pack pairs via lane exchange; even lane writes u32 (k, j=lane>>1)
        unsigned int* dst = &amu[grp*400];
        #pragma unroll
        for (int k = 0; k < 25; k++){
            float other = __shfl_xor(acc[k], 1, 64);
            if (!(lane & 1)) dst[k*16 + (lane >> 1)] = pack2(acc[k], other);
        }
    }
    __syncthreads();
    // GEMM: o = t&63, mg = t>>6 (0..7) -> rows mg, mg+8
    int o = t & 63, mg = t >> 6;
    const unsigned int* a0 = amu + mg*400;
    const unsigned int* a1 = amu + (mg+8)*400;
    const uint4* wq = (const uint4*)w2q;
    float sA0=0.f, sA1=0.f, sB0=0.f, sB1=0.f;
    for (int kp8 = 0; kp8 < 100; kp8++){
        uint4 wv = wq[kp8*64 + o];
        uint4 av = *(const uint4*)(a0 + kp8*4);
        uint4 bv = *(const uint4*)(a1 + kp8*4);
        sA0 = dot2u(av.x, wv.x, sA0); sA1 = dot2u(av.y, wv.y, sA1);
        sA0 = dot2u(av.z, wv.z, sA0); sA1 = dot2u(av.w, wv.w, sA1);
        sB0 = dot2u(bv.x, wv.x, sB0); sB1 = dot2u(bv.y, wv.y, sB1);
        sB0 = dot2u(bv.z, wv.z, sB0); sB1 = dot2u(bv.w, wv.w, sB1);
    }
    float sAB[2] = {sA0 + sA1, sB0 + sB1};
    #pragma unroll
    for (int h = 0; h < 2; ++h){
        int rl = sub*16 + mg + h*8;
        int rr = g*64 + rl;
        float s  = sAB[h];
        float dg = fmaxf((float)deg2i[rr], 1.f);
        float rt = 0.f;
        #pragma unroll
        for (int i = 0; i < 32; i += 4){
            float4 rv = *(const float4*)&r2t[o*32 + i];
            float4 xv = *(const float4*)&xpL[rl*32 + i];
            rt += rv.x*xv.x + rv.y*xv.y + rv.z*xv.z + rv.w*xv.w;
        }
        float val = eluf(s/dg + rt + b2[o]);
        float px = p1x[rl], py = p1y[rl];
        int cx = min(max((int)floorf(px*0.125f), 0), 3);
        int cy = min(max((int)floorf(py*0.125f), 0), 3);
        int cl = g*16 + cx*4 + cy;
        if (o == 0) cl2[rr] = cl;
        if (nv1[rr] > 0.f){
            if (o == 0){
                atomicAdd(&cnt2[cl], 1.f);
                atomicAdd(&ps2[2*cl],   px);
                atomicAdd(&ps2[2*cl+1], py);
            }
            atomic_max_f32(&xm2[cl*64 + o], val);
        }
    }
}

// ---------------- lvl3: pool2-finish + lvl3 dedup/CSR + m3, per graph ----------------
__global__ __launch_bounds__(256) void k_lvl3(
        const int* __restrict__ off2s, const int* __restrict__ deg2i,
        const unsigned char* __restrict__ adj2b, const int* __restrict__ cl2,
        const float* __restrict__ cnt2, const float* __restrict__ ps2,
        const float* __restrict__ xm2,
        float* __restrict__ xp2, float* __restrict__ pos2g, float* __restrict__ nv2,
        unsigned char* __restrict__ adj3b, int* __restrict__ off3s,
        int* __restrict__ deg3i, float* m3p){
    __shared__ int cl2L[64];
    __shared__ unsigned int bit3[8];
    __shared__ float p2x[16], p2y[16];
    __shared__ int rpre[16];
    int t = threadIdx.x, g = blockIdx.x;
    if (t < 64) cl2L[t] = cl2[g*64 + t] & 15;
    if (t < 8)  bit3[t] = 0u;
    if (t < 16){
        float cnt = cnt2[g*16 + t];
        float inv = 1.f / fmaxf(cnt, 1.f);
        p2x[t] = ps2[2*(g*16+t)]*inv;
        p2y[t] = ps2[2*(g*16+t)+1]*inv;
        pos2g[2*(g*16+t)]   = p2x[t];
        pos2g[2*(g*16+t)+1] = p2y[t];
        nv2[g*16 + t] = (cnt > 0.f) ? 1.f : 0.f;
    }
    for (int i = t; i < 1024; i += 256){
        int c = i >> 6;
        xp2[g*1024 + i] = (cnt2[g*16 + c] > 0.f) ? xm2[g*1024 + i] : 0.f;
    }
    __syncthreads();
    if (t < 64){
        int s0 = off2s[g*64 + t], n = deg2i[g*64 + t];
        int r3 = cl2L[t];
        for (int j = 0; j < n; ++j){
            int c3 = cl2L[adj2b[s0 + j]];
            if (r3 != c3){
                int bit = r3*16 + c3;
                atomicOr(&bit3[bit >> 5], 1u << (bit & 31));
            }
        }
    }
    __syncthreads();
    if (t < 16)
        rpre[t] = __popc((bit3[t >> 1] >> ((t & 1)*16)) & 0xFFFFu);
    __syncthreads();
    for (int d = 1; d < 16; d <<= 1){
        int v = 0;
        if (t < 16 && t >= d) v = rpre[t-d];
        __syncthreads();
        if (t < 16) rpre[t] += v;
        __syncthreads();
    }
    float m3loc = 0.f;
    if (t < 16){
        unsigned int w = (bit3[t >> 1] >> ((t & 1)*16)) & 0xFFFFu;
        int dg = __popc(w);
        int baseo = rpre[t] - dg;
        off3s[g*16 + t] = g*256 + baseo;
        deg3i[g*16 + t] = dg;
        int j = g*256 + baseo;
        float rx = p2x[t], ry = p2y[t];
        while (w){
            int b = __ffs(w) - 1; w &= w - 1;
            adj3b[j++] = (unsigned char)b;
            m3loc = fmaxf(m3loc, fmaxf(fabsf(p2x[b]-rx), fabsf(p2y[b]-ry)));
        }
    }
    BLOCK_MAX_AND_ATOMIC(m3loc, m3p);
}

// ---------------- conv3: register gather + f16 dot2 GEMM ----------------
// 512 threads, 8 clusters/block, 512 blocks. LDS ~30 KB.
__global__ __launch_bounds__(512) void k_conv3(
        const int* __restrict__ off3s, const int* __restrict__ deg3i,
        const unsigned char* __restrict__ adj3b, const float* __restrict__ pos2g,
        const float* __restrict__ m3p, const float* __restrict__ xp2,
        const unsigned short* __restrict__ w3q, const float* __restrict__ r3t,
        const float* __restrict__ b3, float* __restrict__ h3){
    __shared__ __align__(16) unsigned int amu[8*800];    // f16-packed acc, 25.6 KB
    __shared__ __align__(16) float xpL[16*64];           // 4 KB
    __shared__ float p2x[16], p2y[16];
    int t = threadIdx.x;
    int g = blockIdx.x >> 1, sub = blockIdx.x & 1;
    for (int i = t; i < 1024; i += 512) xpL[i] = xp2[g*1024 + i];
    if (t < 16){ p2x[t] = pos2g[2*(g*16+t)]; p2y[t] = pos2g[2*(g*16+t)+1]; }
    __syncthreads();
    int grp = t >> 6, lane = t & 63;      // 8 groups x 64 lanes
    {
        int rl = sub*8 + grp;
        int r  = g*16 + rl;
        int s0 = off3s[r], n = deg3i[r];
        float rx = p2x[rl], ry = p2y[rl];
        float mm = *m3p;
        float inv = 1.0f / (2.0f*mm + 1e-12f);
        float acc[25];
        #pragma unroll
        for (int k = 0; k < 25; k++) acc[k] = 0.f;
        for (int j = 0; j < n; ++j){
            int cLoc = adj3b[s0 + j];
            float vx = ((p2x[cLoc] - rx)*inv + 0.5f)*4.0f;
            float vy = ((p2y[cLoc] - ry)*inv + 0.5f)*4.0f;
            float xin = xpL[cLoc*64 + lane];
            float wxx[5], wy[5];
            #pragma unroll
            for (int k = 0; k < 5; k++){
                wxx[k] = fmaxf(0.f, 1.f - fabsf(vx - (float)k)) * xin;
                wy[k]  = fmaxf(0.f, 1.f - fabsf(vy - (float)k));
            }
            #pragma unroll
            for (int kx = 0; kx < 5; kx++)
                #pragma unroll
                for (int ky = 0; ky < 5; ky++)
                    acc[kx*5+ky] = fmaf(wxx[kx], wy[ky], acc[kx*5+ky]);
        }
        unsigned int* dst = &amu[grp*800];
        #pragma unroll
        for (int k = 0; k < 25; k++){
            float other = __shfl_xor(acc[k], 1, 64);
            if (!(lane & 1)) dst[k*32 + (lane >> 1)] = pack2(acc[k], other);
        }
    }
    __syncthreads();
    // GEMM: o = t&127, mg = t>>7 (0..3) -> rows mg, mg+4
    int o = t & 127, mg = t >> 7;
    const unsigned int* a0 = amu + mg*800;
    const unsigned int* a1 = amu + (mg+4)*800;
    const uint4* wq = (const uint4*)w3q;
    float sA0=0.f, sA1=0.f, sB0=0.f, sB1=0.f;
    for (int kp8 = 0; kp8 < 200; kp8++){
        uint4 wv = wq[kp8*128 + o];
        uint4 av = *(const uint4*)(a0 + kp8*4);
        uint4 bv = *(const uint4*)(a1 + kp8*4);
        sA0 = dot2u(av.x, wv.x, sA0); sA1 = dot2u(av.y, wv.y, sA1);
        sA0 = dot2u(av.z, wv.z, sA0); sA1 = dot2u(av.w, wv.w, sA1);
        sB0 = dot2u(bv.x, wv.x, sB0); sB1 = dot2u(bv.y, wv.y, sB1);
        sB0 = dot2u(bv.z, wv.z, sB0); sB1 = dot2u(bv.w, wv.w, sB1);
    }
    float sAB[2] = {sA0 + sA1, sB0 + sB1};
    #pragma unroll
    for (int h = 0; h < 2; ++h){
        int rl = sub*8 + mg + h*4;
        int rr = g*16 + rl;
        float s  = sAB[h];
        float dg = fmaxf((float)deg3i[rr], 1.f);
        float rt = 0.f;
        #pragma unroll
        for (int i = 0; i < 64; i += 4){
            float4 rv = *(const float4*)&r3t[o*64 + i];
            float4 xv = *(const float4*)&xpL[rl*64 + i];
            rt += rv.x*xv.x + rv.y*xv.y + rv.z*xv.z + rv.w*xv.w;
        }
        h3[rr*128 + o] = eluf(s/dg + rt + b3[o]);
    }
}

__global__ void k_readout(const float* __restrict__ h3, const float* __restrict__ nv2,
                          const float* __restrict__ fcw, const float* __restrict__ fcb,
                          float* out){
    int g = blockIdx.x, t = threadIdx.x;     // 128 threads
    __shared__ float gf[128];
    __shared__ float lg[10];
    __shared__ float lse;
    float s = 0.f, cnt = 0.f;
    for (int j = 0; j < 16; j++){
        int c = g*16 + j;
        float nv = nv2[c];
        s += h3[c*128 + t] * nv;
        cnt += nv;
    }
    gf[t] = s / fmaxf(cnt, 1.f);
    __syncthreads();
    if (t < 10){
        float l = fcb[t];
        for (int f = 0; f < 128; f++) l += gf[f]*fcw[f*10 + t];
        lg[t] = l;
    }
    __syncthreads();
    if (t == 0){
        float mx = -INFINITY;
        for (int o = 0; o < 10; o++) mx = fmaxf(mx, lg[o]);
        float ss = 0.f;
        for (int o = 0; o < 10; o++) ss += expf(lg[o] - mx);
        lse = mx + logf(ss);
    }
    __syncthreads();
    if (t < 10) out[g*10 + t] = lg[t] - lse;
}

// ---------------- launch ----------------
extern "C" void kernel_launch(void* const* d_in, const int* in_sizes, int n_in,
                              void* d_out, int out_size, void* d_ws, size_t ws_size,
                              hipStream_t stream){
    const float* x     = (const float*)d_in[0];
    const float* posi  = (const float*)d_in[1];
    const int*   ei    = (const int*)  d_in[2];
    const float* W1    = (const float*)d_in[4];
    const float* root1 = (const float*)d_in[5];
    const float* b1    = (const float*)d_in[6];
    const float* W2    = (const float*)d_in[7];
    const float* root2 = (const float*)d_in[8];
    const float* b2    = (const float*)d_in[9];
    const float* W3    = (const float*)d_in[10];
    const float* root3 = (const float*)d_in[11];
    const float* b3    = (const float*)d_in[12];
    const float* fcw   = (const float*)d_in[13];
    const float* fcb   = (const float*)d_in[14];
    float* out = (float*)d_out;

    char* ws = (char*)d_ws;
    float*          m1    = (float*)(ws + O_SCAL);
    float*          m2    = m1 + 1;
    float*          m3    = m1 + 2;
    int*            gtot  = (int*)  (ws + O_GTOT);
    float*          cnt2  = (float*)(ws + O_CNT2);
    float*          ps2   = (float*)(ws + O_PS2);
    float*          xm2   = (float*)(ws + O_XM2);
    int*            goff  = (int*)  (ws + O_GOFF);
    int*            bb    = (int*)  (ws + O_BB);
    unsigned short* be    = (unsigned short*)(ws + O_BE);
    float*          xp1   = (float*)(ws + O_XP1);
    float*          pos1g = (float*)(ws + O_POS1);
    float*          nv1   = (float*)(ws + O_NV1);
    unsigned char*  adj2b = (unsigned char*)(ws + O_ADJ2);
    int*            off2s = (int*)  (ws + O_OFF2S);
    int*            deg2i = (int*)  (ws + O_DEG2I);
    int*            cl2   = (int*)  (ws + O_CL2);
    float*          xp2   = (float*)(ws + O_XP2);
    float*          pos2g = (float*)(ws + O_POS2);
    float*          nv2   = (float*)(ws + O_NV2);
    unsigned char*  adj3b = (unsigned char*)(ws + O_ADJ3);
    int*            off3s = (int*)  (ws + O_OFF3S);
    int*            deg3i = (int*)  (ws + O_DEG3I);
    float*          h3    = (float*)(ws + O_H3);
    unsigned short* w2q   = (unsigned short*)(ws + O_W2Q);
    unsigned short* w3q   = (unsigned short*)(ws + O_W3Q);
    float*          r2t   = (float*)(ws + O_R2T);
    float*          r3t   = (float*)(ws + O_R3T);

    hipMemsetAsync(ws, 0, Z_END, stream);
    hipMemsetAsync(xm2, 0xFF, (size_t)NC2*64*4, stream);   // identity for atomic max

    k_pass1<<<256 + 1040, 256, 0, stream>>>(ei, posi, m1, gtot, bb,
                                            W2, W3, root2, root3, w2q, w3q, r2t, r3t);
    k_gscan<<<1, 256, 0, stream>>>(gtot, goff);
    k_pass2<<<256, 256, 0, stream>>>(ei, goff, bb, be);

    k_graph1<<<NG, 1024, 0, stream>>>(be, goff, posi, x, m1, W1, root1, b1,
                                      xp1, pos1g, nv1, adj2b, off2s, deg2i, m2);

    k_conv2<<<NC1/16, 512, 0, stream>>>(off2s, deg2i, adj2b, pos1g, m2, xp1,
                                        w2q, r2t, b2, nv1, cl2, cnt2, ps2, xm2);

    k_lvl3<<<NG, 256, 0, stream>>>(off2s, deg2i, adj2b, cl2, cnt2, ps2, xm2,
                                   xp2, pos2g, nv2, adj3b, off3s, deg3i, m3);

    k_conv3<<<NC2/8, 512, 0, stream>>>(off3s, deg3i, adj3b, pos2g, m3, xp2,
                                       w3q, r3t, b3, h3);

    k_readout<<<256, 128, 0, stream>>>(h3, nv2, fcw, fcb, out);
}

// Round 7
// 274.560 us; speedup vs baseline: 4.0813x; 1.0571x over previous
//
#include <hip/hip_runtime.h>
#include <math.h>

// ---------------- problem constants ----------------
constexpr int NN  = 65536;     // nodes (256 graphs x 256 nodes)
constexpr int EE  = 1048576;   // edges (N * 16)
constexpr int NG  = 256;       // graphs
constexpr int NC1 = 16384;     // clusters after pool1 (256 x 64)
constexpr int NC2 = 4096;      // clusters after pool2 (256 x 16)
constexpr int EPB = EE / 256;  // edges per bucketing block = 4096

// ---------------- workspace layout (bytes) ----------------
// Z region (memset 0 each launch)
constexpr size_t O_SCAL  = 0;                                  // m1,m2,m3
constexpr size_t O_GTOT  = 256;                                // 256 ints
constexpr size_t O_CNT2  = O_GTOT + 1024;                      // NC2 f32
constexpr size_t O_PS2   = O_CNT2 + (size_t)NC2*4;             // NC2*2 f32
constexpr size_t Z_END   = O_PS2  + (size_t)NC2*8;
// xm2: memset 0xFF (identity for both atomic-max paths)
constexpr size_t O_XM2   = Z_END;                              // NC2*64 f32
// fully-written-before-read region
constexpr size_t O_GOFF  = O_XM2  + (size_t)NC2*64*4;          // 257 ints (pad)
constexpr size_t O_BB    = O_GOFF + 1280;                      // 256*256 ints
constexpr size_t O_BE    = O_BB   + (size_t)256*256*4;         // EE ushort
constexpr size_t O_XP1   = O_BE   + (size_t)EE*2;              // NC1*32 f32
constexpr size_t O_POS1  = O_XP1  + (size_t)NC1*32*4;          // NC1*2 f32
constexpr size_t O_NV1   = O_POS1 + (size_t)NC1*8;             // NC1 f32
constexpr size_t O_ADJ2  = O_NV1  + (size_t)NC1*4;             // NG*4096 uchar
constexpr size_t O_OFF2S = O_ADJ2 + (size_t)NG*4096;           // NC1 ints
constexpr size_t O_DEG2I = O_OFF2S+ (size_t)NC1*4;             // NC1 ints
constexpr size_t O_CL2   = O_DEG2I+ (size_t)NC1*4;             // NC1 ints
constexpr size_t O_XP2   = O_CL2  + (size_t)NC1*4;             // NC2*64 f32
constexpr size_t O_POS2  = O_XP2  + (size_t)NC2*64*4;          // NC2*2 f32
constexpr size_t O_NV2   = O_POS2 + (size_t)NC2*8;             // NC2 f32
constexpr size_t O_ADJ3  = O_NV2  + (size_t)NC2*4;             // NG*256 uchar
constexpr size_t O_OFF3S = O_ADJ3 + (size_t)NG*256;            // NC2 ints
constexpr size_t O_DEG3I = O_OFF3S+ (size_t)NC2*4;             // NC2 ints
constexpr size_t O_H3    = O_DEG3I+ (size_t)NC2*4;             // NC2*128 f32
// MFMA-fragment-packed weights (f16 pairs as u32)
constexpr size_t O_W2Q   = O_H3   + (size_t)NC2*128*4;         // 25600 u32
constexpr size_t O_W3Q   = O_W2Q  + 102400;                    // 102400 u32
constexpr size_t O_RT2   = O_W3Q  + 409600;                    // 1024 u32
constexpr size_t O_RT3   = O_RT2  + 4096;                      // 4096 u32

// ---------------- device helpers ----------------
typedef __fp16   pk16x2 __attribute__((ext_vector_type(2)));   // cvt_pkrtz return
typedef _Float16 f16x8  __attribute__((ext_vector_type(8)));   // MFMA A/B operand
typedef float    f32x4  __attribute__((ext_vector_type(4)));   // MFMA C/D

__device__ __forceinline__ float eluf(float x){ return x > 0.f ? x : expm1f(x); }

__device__ __forceinline__ void atomic_max_pos(float* a, float v){
    atomicMax((unsigned int*)a, __float_as_uint(v));
}
// arbitrary-sign float atomic max; target init = 0xFFFFFFFF or -inf bits
__device__ __forceinline__ void atomic_max_f32(float* a, float v){
    unsigned int b = __float_as_uint(v);
    if (b & 0x80000000u) atomicMin((unsigned int*)a, b);
    else                 atomicMax((int*)a, (int)b);
}

__device__ __forceinline__ unsigned int pack2(float a, float b){
    pk16x2 h = __builtin_amdgcn_cvt_pkrtz(a, b);
    return __builtin_bit_cast(unsigned int, h);
}
__device__ __forceinline__ f32x4 mfma16(uint4 a, uint4 b, f32x4 c){
    return __builtin_amdgcn_mfma_f32_16x16x32_f16(
        __builtin_bit_cast(f16x8, a), __builtin_bit_cast(f16x8, b), c, 0, 0, 0);
}

struct Crn { int ix, iy; float fx, fy; };
__device__ __forceinline__ Crn mk_corners(float dx, float dy, float m){
    float inv = 1.0f / (2.0f*m + 1e-12f);
    float vx = (dx*inv + 0.5f) * 4.0f;   // (K1-1)=4
    float vy = (dy*inv + 0.5f) * 4.0f;
    Crn c;
    c.ix = min(max((int)floorf(vx), 0), 3);
    c.iy = min(max((int)floorf(vy), 0), 3);
    c.fx = vx - (float)c.ix;
    c.fy = vy - (float)c.iy;
    return c;
}

#define BLOCK_MAX_AND_ATOMIC(val, dst)                                   \
    {   __shared__ float _s[256];                                        \
        _s[threadIdx.x] = (val); __syncthreads();                        \
        for (int _w = 128; _w > 0; _w >>= 1){                            \
            if (threadIdx.x < _w)                                        \
                _s[threadIdx.x] = fmaxf(_s[threadIdx.x], _s[threadIdx.x+_w]); \
            __syncthreads();                                             \
        }                                                                \
        if (threadIdx.x == 0) atomic_max_pos((dst), _s[0]); }

// ---------------- pass1 (+fused B-fragment weight prep in extra blocks) ----------
// blocks [0,256): m1 max + per-graph histogram + per-block bin bases
// blocks [256,776): pack W2/W3/root2/root3 into MFMA B-fragment layout:
//   u32 d = ((tile*NK + kc)*64 + lane)*4 + j holds f16 pair
//   (B[Kb][o], B[Kb+1][o]) with Kb = kc*32 + (lane>>4)*8 + 2j, o = tile*16+(lane&15)
__global__ __launch_bounds__(256) void k_pass1(
        const int* __restrict__ ei, const float* __restrict__ pos,
        float* m1, int* gtot, int* bb,
        const float* __restrict__ W2, const float* __restrict__ W3,
        const float* __restrict__ root2, const float* __restrict__ root3,
        unsigned int* __restrict__ w2q, unsigned int* __restrict__ w3q,
        unsigned int* __restrict__ rt2q, unsigned int* __restrict__ rt3q){
    __shared__ int h[256];
    if (blockIdx.x >= 256){
        int idx = (blockIdx.x - 256)*256 + threadIdx.x;
        if (idx < 25600){                                   // W2: 4 tiles x 25 kslots
            int tt = idx/6400, r = idx%6400, i = r/256, r2 = r%256;
            int l = r2>>2, j = r2&3;
            int o = tt*16 + (l&15);
            int Kb = i*32 + (l>>4)*8 + 2*j;
            w2q[idx] = pack2(W2[Kb*64 + o], W2[(Kb+1)*64 + o]);
        } else if (idx < 128000){                           // W3: 8 tiles x 50 chunks
            int d = idx - 25600;
            int tt = d/12800, r = d%12800, kc = r/256, r2 = r%256;
            int l = r2>>2, j = r2&3;
            int o = tt*16 + (l&15);
            int Kb = kc*32 + (l>>4)*8 + 2*j;
            w3q[d] = pack2(W3[Kb*128 + o], W3[(Kb+1)*128 + o]);
        } else if (idx < 129024){                           // root2: 4 tiles x 1 chunk
            int d = idx - 128000;
            int tt = d/256, r2 = d%256, l = r2>>2, j = r2&3;
            int o = tt*16 + (l&15);
            int k = (l>>4)*8 + 2*j;
            rt2q[d] = pack2(root2[k*64 + o], root2[(k+1)*64 + o]);
        } else if (idx < 133120){                           // root3: 8 tiles x 2 chunks
            int d = idx - 129024;
            int tt = d/512, kc = (d/256)&1, r2 = d%256, l = r2>>2, j = r2&3;
            int o = tt*16 + (l&15);
            int k = kc*32 + (l>>4)*8 + 2*j;
            rt3q[d] = pack2(root3[k*128 + o], root3[(k+1)*128 + o]);
        }
        return;
    }
    h[threadIdx.x] = 0; __syncthreads();
    int base = blockIdx.x * EPB;
    float loc = 0.f;
    for (int i = threadIdx.x; i < EPB; i += 256){
        int e = base + i;
        int r = ei[e], c = ei[EE + e];
        float dx = pos[2*c]   - pos[2*r];
        float dy = pos[2*c+1] - pos[2*r+1];
        loc = fmaxf(loc, fmaxf(fabsf(dx), fabsf(dy)));
        atomicAdd(&h[r >> 8], 1);
    }
    __syncthreads();
    bb[blockIdx.x*256 + threadIdx.x] = atomicAdd(&gtot[threadIdx.x], h[threadIdx.x]);
    BLOCK_MAX_AND_ATOMIC(loc, m1);
}

__global__ void k_gscan(const int* __restrict__ gtot, int* goff){
    __shared__ int s[256];
    int t = threadIdx.x;
    int v0 = gtot[t];
    s[t] = v0; __syncthreads();
    for (int d = 1; d < 256; d <<= 1){
        int u = (t >= d) ? s[t-d] : 0;
        __syncthreads();
        s[t] += u;
        __syncthreads();
    }
    goff[t] = s[t] - v0;
    if (t == 255) goff[256] = s[t];
}

__global__ __launch_bounds__(256) void k_pass2(const int* __restrict__ ei,
                                               const int* __restrict__ goff,
                                               const int* __restrict__ bb,
                                               unsigned short* __restrict__ be){
    __shared__ int cur[256];
    cur[threadIdx.x] = 0; __syncthreads();
    int base = blockIdx.x * EPB;
    for (int i = threadIdx.x; i < EPB; i += 256){
        int e = base + i;
        int r = ei[e], c = ei[EE + e];
        int g = r >> 8;
        int l = atomicAdd(&cur[g], 1);
        be[goff[g] + bb[blockIdx.x*256 + g] + l] =
            (unsigned short)((r & 255) | ((c & 255) << 8));
    }
}

// ---------------- graph1: conv1 + pool1 + lvl2 dedup/CSR + m2 (1024 thr) --------
__global__ __launch_bounds__(1024) void k_graph1(
        const unsigned short* __restrict__ be, const int* __restrict__ goff,
        const float* __restrict__ pos, const float* __restrict__ x,
        const float* __restrict__ m1p, const float* __restrict__ W1,
        const float* __restrict__ root1, const float* __restrict__ b1,
        float* __restrict__ xp1, float* __restrict__ pos1g, float* __restrict__ nv1,
        unsigned char* __restrict__ adj2b, int* __restrict__ off2s,
        int* __restrict__ deg2i, float* m2p){
    __shared__ float acc[256*25];
    __shared__ float posx[256], posy[256], xL[256];
    __shared__ int   cl1L[256], degL[256];
    __shared__ float sW[800];
    __shared__ unsigned int bitL[128];
    __shared__ float xmL[64*32];
    __shared__ int   cntL[64];
    __shared__ float psx[64], psy[64];
    __shared__ float p1x[64], p1y[64];
    __shared__ int   rpre[64];
    __shared__ float mred[64];

    int t = threadIdx.x, g = blockIdx.x;
    if (t < 800) sW[t] = W1[t];
    for (int i = t; i < 6400; i += 1024) acc[i] = 0.f;
    if (t < 256){
        float px = pos[2*(g*256 + t)], py = pos[2*(g*256 + t) + 1];
        posx[t] = px; posy[t] = py;
        xL[t]   = x[g*256 + t];
        degL[t] = 0;
        int cx = min(max((int)floorf(px*0.25f), 0), 7);
        int cy = min(max((int)floorf(py*0.25f), 0), 7);
        cl1L[t] = cx*8 + cy;
    }
    if (t < 128) bitL[t] = 0u;
    if (t < 64){ cntL[t] = 0; psx[t] = 0.f; psy[t] = 0.f; }
    for (int i = t; i < 2048; i += 1024) xmL[i] = -INFINITY;
    __syncthreads();

    float mm = *m1p;
    int e1 = goff[g+1];
    for (int p = goff[g] + t; p < e1; p += 1024){
        unsigned int b = be[p];
        int rl = b & 255, cl = (b >> 8) & 255;
        float dx = posx[cl] - posx[rl], dy = posy[cl] - posy[rl];
        Crn cr = mk_corners(dx, dy, mm);
        float xin = xL[cl];
        int ab = rl*25 + cr.ix*5 + cr.iy;
        atomicAdd(&acc[ab],   (1.f-cr.fx)*(1.f-cr.fy)*xin);
        atomicAdd(&acc[ab+1], (1.f-cr.fx)*cr.fy*xin);
        atomicAdd(&acc[ab+5], cr.fx*(1.f-cr.fy)*xin);
        atomicAdd(&acc[ab+6], cr.fx*cr.fy*xin);
        atomicAdd(&degL[rl], 1);
        int r2 = cl1L[rl], c2 = cl1L[cl];
        if (r2 != c2){
            int bit = r2*64 + c2;
            atomicOr(&bitL[bit >> 5], 1u << (bit & 31));
        }
    }
    __syncthreads();

    {
        int n = t >> 2, q = t & 3;
        float accR[25];
        #pragma unroll
        for (int k = 0; k < 25; k++) accR[k] = acc[n*25 + k];
        float inv = 1.f / fmaxf((float)degL[n], 1.f);
        float xr  = xL[n];
        int   cl  = cl1L[n];
        if (q == 0){
            atomicAdd(&cntL[cl], 1);
            atomicAdd(&psx[cl], posx[n]);
            atomicAdd(&psy[cl], posy[n]);
        }
        #pragma unroll
        for (int oo = 0; oo < 8; oo++){
            int o = q*8 + oo;
            float s = 0.f;
            #pragma unroll
            for (int k = 0; k < 25; k++) s += accR[k]*sW[k*32 + o];
            float out = eluf(s*inv + xr*root1[o] + b1[o]);
            atomic_max_f32(&xmL[cl*32 + o], out);
        }
    }
    __syncthreads();

    if (t < 64){
        float cnt = (float)cntL[t];
        float inv = 1.f / fmaxf(cnt, 1.f);
        p1x[t] = psx[t]*inv; p1y[t] = psy[t]*inv;
        pos1g[2*(g*64 + t)]     = p1x[t];
        pos1g[2*(g*64 + t) + 1] = p1y[t];
        nv1[g*64 + t] = (cnt > 0.f) ? 1.f : 0.f;
    }
    __syncthreads();
    for (int i = t; i < 2048; i += 1024){
        int c = i >> 5;
        xp1[g*2048 + i] = (cntL[c] > 0) ? xmL[i] : 0.f;
    }

    if (t < 64) rpre[t] = __popc(bitL[2*t]) + __popc(bitL[2*t+1]);
    __syncthreads();
    for (int d = 1; d < 64; d <<= 1){
        int v = 0;
        if (t < 64 && t >= d) v = rpre[t-d];
        __syncthreads();
        if (t < 64) rpre[t] += v;
        __syncthreads();
    }
    float m2loc = 0.f;
    if (t < 64){
        unsigned int w0 = bitL[2*t], w1 = bitL[2*t+1];
        int dg = __popc(w0) + __popc(w1);
        int baseo = rpre[t] - dg;
        off2s[g*64 + t] = g*4096 + baseo;
        deg2i[g*64 + t] = dg;
        int j = g*4096 + baseo;
        float rx = p1x[t], ry = p1y[t];
        while (w0){
            int b = __ffs(w0) - 1; w0 &= w0 - 1;
            adj2b[j++] = (unsigned char)b;
            m2loc = fmaxf(m2loc, fmaxf(fabsf(p1x[b]-rx), fabsf(p1y[b]-ry)));
        }
        while (w1){
            int b = __ffs(w1) - 1; w1 &= w1 - 1;
            int c = 32 + b;
            adj2b[j++] = (unsigned char)c;
            m2loc = fmaxf(m2loc, fmaxf(fabsf(p1x[c]-rx), fabsf(p1y[c]-ry)));
        }
        mred[t] = m2loc;
    }
    __syncthreads();
    if (t == 0){
        float v = mred[0];
        for (int i = 1; i < 64; i++) v = fmaxf(v, mred[i]);
        atomic_max_pos(m2p, v);
    }
}

// ---------------- conv2: shfl-gather + MFMA GEMM + pool2-node ----------------
// 512 threads = 8 waves, 16 clusters/block, 1024 blocks. LDS ~44 KB -> 3 blk/CU.
__global__ __launch_bounds__(512) void k_conv2(
        const int* __restrict__ off2s, const int* __restrict__ deg2i,
        const unsigned char* __restrict__ adj2b, const float* __restrict__ pos1g,
        const float* __restrict__ m2p, const float* __restrict__ xp1,
        const unsigned int* __restrict__ wq2, const unsigned int* __restrict__ rt2q,
        const float* __restrict__ b2, const float* __restrict__ nv1,
        int* __restrict__ cl2, float* cnt2, float* ps2, float* xm2){
    __shared__ unsigned int amu[16*404];   // packed f16 acc (deg-scaled), stride pad +4
    __shared__ float xpL[64*32];
    __shared__ unsigned int xq[16*20];     // packed f16 xp of own 16 clusters
    __shared__ float pc[8*256];            // per-wave partial C
    __shared__ float p1x[64], p1y[64];
    int t = threadIdx.x;
    int g = blockIdx.x >> 2, sub = blockIdx.x & 3;
    for (int i = t; i < 2048; i += 512) xpL[i] = xp1[g*2048 + i];
    if (t < 64){ p1x[t] = pos1g[2*(g*64+t)]; p1y[t] = pos1g[2*(g*64+t)+1]; }
    __syncthreads();
    if (t < 256){
        int m = t >> 4, jj = t & 15;
        int c = sub*16 + m;
        xq[m*20 + jj] = pack2(xpL[c*32 + 2*jj], xpL[c*32 + 2*jj + 1]);
    }
    int grp = t >> 5, lane = t & 31;       // 16 groups x 32 lanes (= feature)
    {
        int rl = sub*16 + grp;
        int r  = g*64 + rl;
        int s0 = off2s[r], nd = deg2i[r];
        float rx = p1x[rl], ry = p1y[rl];
        float invm = 1.0f / (2.0f*(*m2p) + 1e-12f);
        float acc[25];
        #pragma unroll
        for (int k = 0; k < 25; k++) acc[k] = 0.f;
        for (int base = 0; base < nd; base += 32){
            int e = base + lane;
            int myc = 0;
            float wxl[5], wyl[5];
            #pragma unroll
            for (int k = 0; k < 5; k++){ wxl[k] = 0.f; wyl[k] = 0.f; }
            if (e < nd){
                myc = adj2b[s0 + e];
                float vx = ((p1x[myc]-rx)*invm + 0.5f)*4.0f;
                float vy = ((p1y[myc]-ry)*invm + 0.5f)*4.0f;
                #pragma unroll
                for (int k = 0; k < 5; k++){
                    wxl[k] = fmaxf(0.f, 1.f - fabsf(vx - (float)k));
                    wyl[k] = fmaxf(0.f, 1.f - fabsf(vy - (float)k));
                }
            }
            int cnt = min(32, nd - base);
            for (int j = 0; j < cnt; ++j){
                int c = __shfl(myc, j, 32);
                float xin = xpL[c*32 + lane];
                float xv[5], yv[5];
                #pragma unroll
                for (int k = 0; k < 5; k++){
                    xv[k] = __shfl(wxl[k], j, 32) * xin;
                    yv[k] = __shfl(wyl[k], j, 32);
                }
                #pragma unroll
                for (int kx = 0; kx < 5; kx++)
                    #pragma unroll
                    for (int ky = 0; ky < 5; ky++)
                        acc[kx*5+ky] = fmaf(xv[kx], yv[ky], acc[kx*5+ky]);
            }
        }
        float invd = 1.f / fmaxf((float)nd, 1.f);       // fold 1/deg into A
        unsigned int* dst = &amu[grp*404];
        #pragma unroll
        for (int k = 0; k < 25; k++){
            float a = acc[k]*invd;
            float o2 = __shfl_xor(a, 1, 64);
            if (!(lane & 1)) dst[k*16 + (lane >> 1)] = pack2(a, o2);
        }
    }
    __syncthreads();
    // MFMA: wave w -> N-tile (w&3), K-half (w>>2); root in K-half 0
    {
        int w = t >> 6, l = t & 63;
        int tt = w & 3, kh = w >> 2;
        int m = l & 15, kb = l >> 4;
        f32x4 cacc = {0.f, 0.f, 0.f, 0.f};
        int ks0 = kh ? 12 : 0, ks1 = kh ? 25 : 12;
        for (int i = ks0; i < ks1; ++i){
            uint4 au = *(const uint4*)&amu[m*404 + i*16 + kb*4];
            uint4 bu = *(const uint4*)&wq2[((tt*25 + i)*64 + l)*4];
            cacc = mfma16(au, bu, cacc);
        }
        if (kh == 0){
            uint4 au = *(const uint4*)&xq[m*20 + kb*4];
            uint4 bu = *(const uint4*)&rt2q[(tt*64 + l)*4];
            cacc = mfma16(au, bu, cacc);
        }
        *(f32x4*)&pc[w*256 + l*4] = cacc;
    }
    __syncthreads();
    // epilogue: combine K-halves, bias, elu, pool2-node
    {
        int tt = t >> 7, q = t & 127;
        int l = q & 63, rh = q >> 6;
        #pragma unroll
        for (int u = 0; u < 2; ++u){
            int r_ = rh*2 + u;
            int m = (l >> 4)*4 + r_;
            int o = tt*16 + (l & 15);
            float val = pc[tt*256 + l*4 + r_] + pc[(tt+4)*256 + l*4 + r_];
            val = eluf(val + b2[o]);
            int rl = sub*16 + m;
            int rr = g*64 + rl;
            float px = p1x[rl], py = p1y[rl];
            int cx = min(max((int)floorf(px*0.125f), 0), 3);
            int cy = min(max((int)floorf(py*0.125f), 0), 3);
            int cl = g*16 + cx*4 + cy;
            float nv = nv1[rr];
            if (o == 0){
                cl2[rr] = cl;
                if (nv > 0.f){
                    atomicAdd(&cnt2[cl], 1.f);
                    atomicAdd(&ps2[2*cl],   px);
                    atomicAdd(&ps2[2*cl+1], py);
                }
            }
            if (nv > 0.f) atomic_max_f32(&xm2[cl*64 + o], val);
        }
    }
}

// ---------------- lvl3: pool2-finish + lvl3 dedup/CSR + m3, per graph ----------------
__global__ __launch_bounds__(256) void k_lvl3(
        const int* __restrict__ off2s, const int* __restrict__ deg2i,
        const unsigned char* __restrict__ adj2b, const int* __restrict__ cl2,
        const float* __restrict__ cnt2, const float* __restrict__ ps2,
        const float* __restrict__ xm2,
        float* __restrict__ xp2, float* __restrict__ pos2g, float* __restrict__ nv2,
        unsigned char* __restrict__ adj3b, int* __restrict__ off3s,
        int* __restrict__ deg3i, float* m3p){
    __shared__ int cl2L[64];
    __shared__ unsigned int bit3[8];
    __shared__ float p2x[16], p2y[16];
    __shared__ int rpre[16];
    int t = threadIdx.x, g = blockIdx.x;
    if (t < 64) cl2L[t] = cl2[g*64 + t] & 15;
    if (t < 8)  bit3[t] = 0u;
    if (t < 16){
        float cnt = cnt2[g*16 + t];
        float inv = 1.f / fmaxf(cnt, 1.f);
        p2x[t] = ps2[2*(g*16+t)]*inv;
        p2y[t] = ps2[2*(g*16+t)+1]*inv;
        pos2g[2*(g*16+t)]   = p2x[t];
        pos2g[2*(g*16+t)+1] = p2y[t];
        nv2[g*16 + t] = (cnt > 0.f) ? 1.f : 0.f;
    }
    for (int i = t; i < 1024; i += 256){
        int c = i >> 6;
        xp2[g*1024 + i] = (cnt2[g*16 + c] > 0.f) ? xm2[g*1024 + i] : 0.f;
    }
    __syncthreads();
    if (t < 64){
        int s0 = off2s[g*64 + t], n = deg2i[g*64 + t];
        int r3 = cl2L[t];
        for (int j = 0; j < n; ++j){
            int c3 = cl2L[adj2b[s0 + j]];
            if (r3 != c3){
                int bit = r3*16 + c3;
                atomicOr(&bit3[bit >> 5], 1u << (bit & 31));
            }
        }
    }
    __syncthreads();
    if (t < 16)
        rpre[t] = __popc((bit3[t >> 1] >> ((t & 1)*16)) & 0xFFFFu);
    __syncthreads();
    for (int d = 1; d < 16; d <<= 1){
        int v = 0;
        if (t < 16 && t >= d) v = rpre[t-d];
        __syncthreads();
        if (t < 16) rpre[t] += v;
        __syncthreads();
    }
    float m3loc = 0.f;
    if (t < 16){
        unsigned int w = (bit3[t >> 1] >> ((t & 1)*16)) & 0xFFFFu;
        int dg = __popc(w);
        int baseo = rpre[t] - dg;
        off3s[g*16 + t] = g*256 + baseo;
        deg3i[g*16 + t] = dg;
        int j = g*256 + baseo;
        float rx = p2x[t], ry = p2y[t];
        while (w){
            int b = __ffs(w) - 1; w &= w - 1;
            adj3b[j++] = (unsigned char)b;
            m3loc = fmaxf(m3loc, fmaxf(fabsf(p2x[b]-rx), fabsf(p2y[b]-ry)));
        }
    }
    BLOCK_MAX_AND_ATOMIC(m3loc, m3p);
}

// ---------------- conv3: shfl-gather + MFMA GEMM ----------------
// 512 threads = 8 waves, 1 graph (16 clusters)/block, 256 blocks.
__global__ __launch_bounds__(512) void k_conv3(
        const int* __restrict__ off3s, const int* __restrict__ deg3i,
        const unsigned char* __restrict__ adj3b, const float* __restrict__ pos2g,
        const float* __restrict__ m3p, const float* __restrict__ xp2,
        const unsigned int* __restrict__ wq3, const unsigned int* __restrict__ rt3q,
        const float* __restrict__ b3, float* __restrict__ h3){
    __shared__ unsigned int amu[16*804];   // packed f16 acc, stride pad +4
    __shared__ float xpL[16*64];
    __shared__ unsigned int xq[16*36];
    __shared__ float p2x[16], p2y[16];
    int t = threadIdx.x, g = blockIdx.x;
    for (int i = t; i < 1024; i += 512) xpL[i] = xp2[g*1024 + i];
    if (t < 16){ p2x[t] = pos2g[2*(g*16+t)]; p2y[t] = pos2g[2*(g*16+t)+1]; }
    __syncthreads();
    {
        int m = t >> 5, jj = t & 31;
        xq[m*36 + jj] = pack2(xpL[m*64 + 2*jj], xpL[m*64 + 2*jj + 1]);
    }
    int grp = t >> 6, lane = t & 63;       // 8 groups x 64 lanes; 2 clusters/group
    float invm = 1.0f / (2.0f*(*m3p) + 1e-12f);
    for (int cc = 0; cc < 2; ++cc){
        int rl = grp + cc*8;
        int r  = g*16 + rl;
        int s0 = off3s[r], nd = deg3i[r];
        float rx = p2x[rl], ry = p2y[rl];
        float acc[25];
        #pragma unroll
        for (int k = 0; k < 25; k++) acc[k] = 0.f;
        for (int base = 0; base < nd; base += 64){
            int e = base + lane;
            int myc = 0;
            float wxl[5], wyl[5];
            #pragma unroll
            for (int k = 0; k < 5; k++){ wxl[k] = 0.f; wyl[k] = 0.f; }
            if (e < nd){
                myc = adj3b[s0 + e];
                float vx = ((p2x[myc]-rx)*invm + 0.5f)*4.0f;
                float vy = ((p2y[myc]-ry)*invm + 0.5f)*4.0f;
                #pragma unroll
                for (int k = 0; k < 5; k++){
                    wxl[k] = fmaxf(0.f, 1.f - fabsf(vx - (float)k));
                    wyl[k] = fmaxf(0.f, 1.f - fabsf(vy - (float)k));
                }
            }
            int cnt = min(64, nd - base);
            for (int j = 0; j < cnt; ++j){
                int c = __shfl(myc, j, 64);
                float xin = xpL[c*64 + lane];
                float xv[5], yv[5];
                #pragma unroll
                for (int k = 0; k < 5; k++){
                    xv[k] = __shfl(wxl[k], j, 64) * xin;
                    yv[k] = __shfl(wyl[k], j, 64);
                }
                #pragma unroll
                for (int kx = 0; kx < 5; kx++)
                    #pragma unroll
                    for (int ky = 0; ky < 5; ky++)
                        acc[kx*5+ky] = fmaf(xv[kx], yv[ky], acc[kx*5+ky]);
            }
        }
        float invd = 1.f / fmaxf((float)nd, 1.f);
        unsigned int* dst = &amu[rl*804];
        #pragma unroll
        for (int k = 0; k < 25; k++){
            float a = acc[k]*invd;
            float o2 = __shfl_xor(a, 1, 64);
            if (!(lane & 1)) dst[k*32 + (lane >> 1)] = pack2(a, o2);
        }
    }
    __syncthreads();
    // MFMA: wave w = N-tile (8 tiles x 16 cols = 128 outputs), full K=1600 + root
    {
        int w = t >> 6, l = t & 63;
        int m = l & 15, kb = l >> 4;
        f32x4 cacc = {0.f, 0.f, 0.f, 0.f};
        for (int kc = 0; kc < 50; ++kc){
            uint4 au = *(const uint4*)&amu[m*804 + kc*16 + kb*4];
            uint4 bu = *(const uint4*)&wq3[((w*50 + kc)*64 + l)*4];
            cacc = mfma16(au, bu, cacc);
        }
        #pragma unroll
        for (int kc = 0; kc < 2; ++kc){
            uint4 au = *(const uint4*)&xq[m*36 + kc*16 + kb*4];
            uint4 bu = *(const uint4*)&rt3q[((w*2 + kc)*64 + l)*4];
            cacc = mfma16(au, bu, cacc);
        }
        int o = w*16 + (l & 15);
        float bb3 = b3[o];
        #pragma unroll
        for (int r_ = 0; r_ < 4; ++r_){
            int m2_ = (l >> 4)*4 + r_;
            h3[(g*16 + m2_)*128 + o] = eluf(cacc[r_] + bb3);
        }
    }
}

__global__ void k_readout(const float* __restrict__ h3, const float* __restrict__ nv2,
                          const float* __restrict__ fcw, const float* __restrict__ fcb,
                          float* out){
    int g = blockIdx.x, t = threadIdx.x;     // 128 threads
    __shared__ float gf[128];
    __shared__ float lg[10];
    __shared__ float lse;
    float s = 0.f, cnt = 0.f;
    for (int j = 0; j < 16; j++){
        int c = g*16 + j;
        float nv = nv2[c];
        s += h3[c*128 + t] * nv;
        cnt += nv;
    }
    gf[t] = s / fmaxf(cnt, 1.f);
    __syncthreads();
    if (t < 10){
        float l = fcb[t];
        for (int f = 0; f < 128; f++) l += gf[f]*fcw[f*10 + t];
        lg[t] = l;
    }
    __syncthreads();
    if (t == 0){
        float mx = -INFINITY;
        for (int o = 0; o < 10; o++) mx = fmaxf(mx, lg[o]);
        float ss = 0.f;
        for (int o = 0; o < 10; o++) ss += expf(lg[o] - mx);
        lse = mx + logf(ss);
    }
    __syncthreads();
    if (t < 10) out[g*10 + t] = lg[t] - lse;
}

// ---------------- launch ----------------
extern "C" void kernel_launch(void* const* d_in, const int* in_sizes, int n_in,
                              void* d_out, int out_size, void* d_ws, size_t ws_size,
                              hipStream_t stream){
    const float* x     = (const float*)d_in[0];
    const float* posi  = (const float*)d_in[1];
    const int*   ei    = (const int*)  d_in[2];
    const float* W1    = (const float*)d_in[4];
    const float* root1 = (const float*)d_in[5];
    const float* b1    = (const float*)d_in[6];
    const float* W2    = (const float*)d_in[7];
    const float* root2 = (const float*)d_in[8];
    const float* b2    = (const float*)d_in[9];
    const float* W3    = (const float*)d_in[10];
    const float* root3 = (const float*)d_in[11];
    const float* b3    = (const float*)d_in[12];
    const float* fcw   = (const float*)d_in[13];
    const float* fcb   = (const float*)d_in[14];
    float* out = (float*)d_out;

    char* ws = (char*)d_ws;
    float*          m1    = (float*)(ws + O_SCAL);
    float*          m2    = m1 + 1;
    float*          m3    = m1 + 2;
    int*            gtot  = (int*)  (ws + O_GTOT);
    float*          cnt2  = (float*)(ws + O_CNT2);
    float*          ps2   = (float*)(ws + O_PS2);
    float*          xm2   = (float*)(ws + O_XM2);
    int*            goff  = (int*)  (ws + O_GOFF);
    int*            bb    = (int*)  (ws + O_BB);
    unsigned short* be    = (unsigned short*)(ws + O_BE);
    float*          xp1   = (float*)(ws + O_XP1);
    float*          pos1g = (float*)(ws + O_POS1);
    float*          nv1   = (float*)(ws + O_NV1);
    unsigned char*  adj2b = (unsigned char*)(ws + O_ADJ2);
    int*            off2s = (int*)  (ws + O_OFF2S);
    int*            deg2i = (int*)  (ws + O_DEG2I);
    int*            cl2   = (int*)  (ws + O_CL2);
    float*          xp2   = (float*)(ws + O_XP2);
    float*          pos2g = (float*)(ws + O_POS2);
    float*          nv2   = (float*)(ws + O_NV2);
    unsigned char*  adj3b = (unsigned char*)(ws + O_ADJ3);
    int*            off3s = (int*)  (ws + O_OFF3S);
    int*            deg3i = (int*)  (ws + O_DEG3I);
    float*          h3    = (float*)(ws + O_H3);
    unsigned int*   w2q   = (unsigned int*)(ws + O_W2Q);
    unsigned int*   w3q   = (unsigned int*)(ws + O_W3Q);
    unsigned int*   rt2q  = (unsigned int*)(ws + O_RT2);
    unsigned int*   rt3q  = (unsigned int*)(ws + O_RT3);

    hipMemsetAsync(ws, 0, Z_END, stream);
    hipMemsetAsync(xm2, 0xFF, (size_t)NC2*64*4, stream);   // identity for atomic max

    k_pass1<<<256 + 520, 256, 0, stream>>>(ei, posi, m1, gtot, bb,
                                           W2, W3, root2, root3, w2q, w3q, rt2q, rt3q);
    k_gscan<<<1, 256, 0, stream>>>(gtot, goff);
    k_pass2<<<256, 256, 0, stream>>>(ei, goff, bb, be);

    k_graph1<<<NG, 1024, 0, stream>>>(be, goff, posi, x, m1, W1, root1, b1,
                                      xp1, pos1g, nv1, adj2b, off2s, deg2i, m2);

    k_conv2<<<NC1/16, 512, 0, stream>>>(off2s, deg2i, adj2b, pos1g, m2, xp1,
                                        w2q, rt2q, b2, nv1, cl2, cnt2, ps2, xm2);

    k_lvl3<<<NG, 256, 0, stream>>>(off2s, deg2i, adj2b, cl2, cnt2, ps2, xm2,
                                   xp2, pos2g, nv2, adj3b, off3s, deg3i, m3);

    k_conv3<<<NG, 512, 0, stream>>>(off3s, deg3i, adj3b, pos2g, m3, xp2,
                                    w3q, rt3q, b3, h3);

    k_readout<<<256, 128, 0, stream>>>(h3, nv2, fcw, fcb, out);
}

// Round 9
// 246.678 us; speedup vs baseline: 4.5426x; 1.1130x over previous
//
#include <hip/hip_runtime.h>
#include <math.h>

// ---------------- problem constants ----------------
constexpr int NN  = 65536;     // nodes (256 graphs x 256 nodes)
constexpr int EE  = 1048576;   // edges (N * 16)
constexpr int NG  = 256;       // graphs
constexpr int NC1 = 16384;     // clusters after pool1 (256 x 64)
constexpr int NC2 = 4096;      // clusters after pool2 (256 x 16)
constexpr int EPB = EE / 256;  // edges per bucketing block = 4096

// ---------------- workspace layout (bytes) ----------------
// Z region (memset 0 each launch)
constexpr size_t O_SCAL  = 0;                                  // m1,m2,m3
constexpr size_t O_GTOT  = 256;                                // 256 ints
constexpr size_t O_CNT2  = O_GTOT + 1024;                      // NC2 f32
constexpr size_t O_PS2   = O_CNT2 + (size_t)NC2*4;             // NC2*2 f32
constexpr size_t Z_END   = O_PS2  + (size_t)NC2*8;
// xm2: memset 0xFF (identity for both atomic-max paths)
constexpr size_t O_XM2   = Z_END;                              // NC2*64 f32
// fully-written-before-read region
constexpr size_t O_GOFF  = O_XM2  + (size_t)NC2*64*4;          // 257 ints (pad)
constexpr size_t O_BB    = O_GOFF + 1280;                      // 256*256 ints
constexpr size_t O_BE    = O_BB   + (size_t)256*256*4;         // EE ushort
constexpr size_t O_XP1   = O_BE   + (size_t)EE*2;              // NC1*32 f32
constexpr size_t O_POS1  = O_XP1  + (size_t)NC1*32*4;          // NC1*2 f32
constexpr size_t O_NV1   = O_POS1 + (size_t)NC1*8;             // NC1 f32
constexpr size_t O_ADJ2  = O_NV1  + (size_t)NC1*4;             // NG*4096 uchar
constexpr size_t O_OFF2S = O_ADJ2 + (size_t)NG*4096;           // NC1 ints
constexpr size_t O_DEG2I = O_OFF2S+ (size_t)NC1*4;             // NC1 ints
constexpr size_t O_CL2   = O_DEG2I+ (size_t)NC1*4;             // NC1 ints
constexpr size_t O_XP2   = O_CL2  + (size_t)NC1*4;             // NC2*64 f32
constexpr size_t O_POS2  = O_XP2  + (size_t)NC2*64*4;          // NC2*2 f32
constexpr size_t O_NV2   = O_POS2 + (size_t)NC2*8;             // NC2 f32
constexpr size_t O_ADJ3  = O_NV2  + (size_t)NC2*4;             // NG*256 uchar
constexpr size_t O_OFF3S = O_ADJ3 + (size_t)NG*256;            // NC2 ints
constexpr size_t O_DEG3I = O_OFF3S+ (size_t)NC2*4;             // NC2 ints
constexpr size_t O_H3    = O_DEG3I+ (size_t)NC2*4;             // NC2*128 f32
// MFMA-fragment-packed weights (f16 pairs as u32)
constexpr size_t O_W2Q   = O_H3   + (size_t)NC2*128*4;         // 25600 u32
constexpr size_t O_W3Q   = O_W2Q  + 102400;                    // 102400 u32
constexpr size_t O_RT2   = O_W3Q  + 409600;                    // 1024 u32
constexpr size_t O_RT3   = O_RT2  + 4096;                      // 4096 u32

// ---------------- device helpers ----------------
typedef __fp16   pk16x2 __attribute__((ext_vector_type(2)));   // cvt_pkrtz return
typedef _Float16 h16x2  __attribute__((ext_vector_type(2)));
typedef _Float16 f16x8  __attribute__((ext_vector_type(8)));   // MFMA A/B operand
typedef float    f32x4  __attribute__((ext_vector_type(4)));   // MFMA C/D

__device__ __forceinline__ float eluf(float x){ return x > 0.f ? x : expm1f(x); }

__device__ __forceinline__ void atomic_max_pos(float* a, float v){
    atomicMax((unsigned int*)a, __float_as_uint(v));
}
// arbitrary-sign float atomic max; target init = 0xFFFFFFFF or -inf bits
__device__ __forceinline__ void atomic_max_f32(float* a, float v){
    unsigned int b = __float_as_uint(v);
    if (b & 0x80000000u) atomicMin((unsigned int*)a, b);
    else                 atomicMax((int*)a, (int)b);
}

__device__ __forceinline__ unsigned int pack2(float a, float b){
    pk16x2 h = __builtin_amdgcn_cvt_pkrtz(a, b);
    return __builtin_bit_cast(unsigned int, h);
}
__device__ __forceinline__ float2 unpk(unsigned int u){
    h16x2 h = __builtin_bit_cast(h16x2, u);
    return make_float2((float)h[0], (float)h[1]);
}
__device__ __forceinline__ f32x4 mfma16(uint4 a, uint4 b, f32x4 c){
    return __builtin_amdgcn_mfma_f32_16x16x32_f16(
        __builtin_bit_cast(f16x8, a), __builtin_bit_cast(f16x8, b), c, 0, 0, 0);
}

struct Crn { int ix, iy; float fx, fy; };
__device__ __forceinline__ Crn mk_corners(float dx, float dy, float m){
    float inv = 1.0f / (2.0f*m + 1e-12f);
    float vx = (dx*inv + 0.5f) * 4.0f;   // (K1-1)=4
    float vy = (dy*inv + 0.5f) * 4.0f;
    Crn c;
    c.ix = min(max((int)floorf(vx), 0), 3);
    c.iy = min(max((int)floorf(vy), 0), 3);
    c.fx = vx - (float)c.ix;
    c.fy = vy - (float)c.iy;
    return c;
}

#define BLOCK_MAX_AND_ATOMIC(val, dst)                                   \
    {   __shared__ float _s[256];                                        \
        _s[threadIdx.x] = (val); __syncthreads();                        \
        for (int _w = 128; _w > 0; _w >>= 1){                            \
            if (threadIdx.x < _w)                                        \
                _s[threadIdx.x] = fmaxf(_s[threadIdx.x], _s[threadIdx.x+_w]); \
            __syncthreads();                                             \
        }                                                                \
        if (threadIdx.x == 0) atomic_max_pos((dst), _s[0]); }

// ---------------- pass1 (+fused B-fragment weight prep in extra blocks) ----------
__global__ __launch_bounds__(256) void k_pass1(
        const int* __restrict__ ei, const float* __restrict__ pos,
        float* m1, int* gtot, int* bb,
        const float* __restrict__ W2, const float* __restrict__ W3,
        const float* __restrict__ root2, const float* __restrict__ root3,
        unsigned int* __restrict__ w2q, unsigned int* __restrict__ w3q,
        unsigned int* __restrict__ rt2q, unsigned int* __restrict__ rt3q){
    __shared__ int h[256];
    if (blockIdx.x >= 256){
        int idx = (blockIdx.x - 256)*256 + threadIdx.x;
        if (idx < 25600){                                   // W2: 4 tiles x 25 kslots
            int tt = idx/6400, r = idx%6400, i = r/256, r2 = r%256;
            int l = r2>>2, j = r2&3;
            int o = tt*16 + (l&15);
            int Kb = i*32 + (l>>4)*8 + 2*j;
            w2q[idx] = pack2(W2[Kb*64 + o], W2[(Kb+1)*64 + o]);
        } else if (idx < 128000){                           // W3: 8 tiles x 50 chunks
            int d = idx - 25600;
            int tt = d/12800, r = d%12800, kc = r/256, r2 = r%256;
            int l = r2>>2, j = r2&3;
            int o = tt*16 + (l&15);
            int Kb = kc*32 + (l>>4)*8 + 2*j;
            w3q[d] = pack2(W3[Kb*128 + o], W3[(Kb+1)*128 + o]);
        } else if (idx < 129024){                           // root2: 4 tiles x 1 chunk
            int d = idx - 128000;
            int tt = d/256, r2 = d%256, l = r2>>2, j = r2&3;
            int o = tt*16 + (l&15);
            int k = (l>>4)*8 + 2*j;
            rt2q[d] = pack2(root2[k*64 + o], root2[(k+1)*64 + o]);
        } else if (idx < 133120){                           // root3: 8 tiles x 2 chunks
            int d = idx - 129024;
            int tt = d/512, kc = (d/256)&1, r2 = d%256, l = r2>>2, j = r2&3;
            int o = tt*16 + (l&15);
            int k = kc*32 + (l>>4)*8 + 2*j;
            rt3q[d] = pack2(root3[k*128 + o], root3[(k+1)*128 + o]);
        }
        return;
    }
    h[threadIdx.x] = 0; __syncthreads();
    int base = blockIdx.x * EPB;
    float loc = 0.f;
    for (int i = threadIdx.x; i < EPB; i += 256){
        int e = base + i;
        int r = ei[e], c = ei[EE + e];
        float dx = pos[2*c]   - pos[2*r];
        float dy = pos[2*c+1] - pos[2*r+1];
        loc = fmaxf(loc, fmaxf(fabsf(dx), fabsf(dy)));
        atomicAdd(&h[r >> 8], 1);
    }
    __syncthreads();
    bb[blockIdx.x*256 + threadIdx.x] = atomicAdd(&gtot[threadIdx.x], h[threadIdx.x]);
    BLOCK_MAX_AND_ATOMIC(loc, m1);
}

__global__ void k_gscan(const int* __restrict__ gtot, int* goff){
    __shared__ int s[256];
    int t = threadIdx.x;
    int v0 = gtot[t];
    s[t] = v0; __syncthreads();
    for (int d = 1; d < 256; d <<= 1){
        int u = (t >= d) ? s[t-d] : 0;
        __syncthreads();
        s[t] += u;
        __syncthreads();
    }
    goff[t] = s[t] - v0;
    if (t == 255) goff[256] = s[t];
}

__global__ __launch_bounds__(256) void k_pass2(const int* __restrict__ ei,
                                               const int* __restrict__ goff,
                                               const int* __restrict__ bb,
                                               unsigned short* __restrict__ be){
    __shared__ int cur[256];
    cur[threadIdx.x] = 0; __syncthreads();
    int base = blockIdx.x * EPB;
    for (int i = threadIdx.x; i < EPB; i += 256){
        int e = base + i;
        int r = ei[e], c = ei[EE + e];
        int g = r >> 8;
        int l = atomicAdd(&cur[g], 1);
        be[goff[g] + bb[blockIdx.x*256 + g] + l] =
            (unsigned short)((r & 255) | ((c & 255) << 8));
    }
}

// ---------------- graph1: conv1 + pool1 + lvl2 dedup/CSR + m2 (1024 thr) --------
__global__ __launch_bounds__(1024) void k_graph1(
        const unsigned short* __restrict__ be, const int* __restrict__ goff,
        const float* __restrict__ pos, const float* __restrict__ x,
        const float* __restrict__ m1p, const float* __restrict__ W1,
        const float* __restrict__ root1, const float* __restrict__ b1,
        float* __restrict__ xp1, float* __restrict__ pos1g, float* __restrict__ nv1,
        unsigned char* __restrict__ adj2b, int* __restrict__ off2s,
        int* __restrict__ deg2i, float* m2p){
    __shared__ float acc[256*25];
    __shared__ float posx[256], posy[256], xL[256];
    __shared__ int   cl1L[256], degL[256];
    __shared__ float sW[800];
    __shared__ unsigned int bitL[128];
    __shared__ float xmL[64*32];
    __shared__ int   cntL[64];
    __shared__ float psx[64], psy[64];
    __shared__ float p1x[64], p1y[64];
    __shared__ int   rpre[64];
    __shared__ float mred[64];

    int t = threadIdx.x, g = blockIdx.x;
    if (t < 800) sW[t] = W1[t];
    for (int i = t; i < 6400; i += 1024) acc[i] = 0.f;
    if (t < 256){
        float px = pos[2*(g*256 + t)], py = pos[2*(g*256 + t) + 1];
        posx[t] = px; posy[t] = py;
        xL[t]   = x[g*256 + t];
        degL[t] = 0;
        int cx = min(max((int)floorf(px*0.25f), 0), 7);
        int cy = min(max((int)floorf(py*0.25f), 0), 7);
        cl1L[t] = cx*8 + cy;
    }
    if (t < 128) bitL[t] = 0u;
    if (t < 64){ cntL[t] = 0; psx[t] = 0.f; psy[t] = 0.f; }
    for (int i = t; i < 2048; i += 1024) xmL[i] = -INFINITY;
    __syncthreads();

    float mm = *m1p;
    int e1 = goff[g+1];
    for (int p = goff[g] + t; p < e1; p += 1024){
        unsigned int b = be[p];
        int rl = b & 255, cl = (b >> 8) & 255;
        float dx = posx[cl] - posx[rl], dy = posy[cl] - posy[rl];
        Crn cr = mk_corners(dx, dy, mm);
        float xin = xL[cl];
        int ab = rl*25 + cr.ix*5 + cr.iy;
        atomicAdd(&acc[ab],   (1.f-cr.fx)*(1.f-cr.fy)*xin);
        atomicAdd(&acc[ab+1], (1.f-cr.fx)*cr.fy*xin);
        atomicAdd(&acc[ab+5], cr.fx*(1.f-cr.fy)*xin);
        atomicAdd(&acc[ab+6], cr.fx*cr.fy*xin);
        atomicAdd(&degL[rl], 1);
        int r2 = cl1L[rl], c2 = cl1L[cl];
        if (r2 != c2){
            int bit = r2*64 + c2;
            atomicOr(&bitL[bit >> 5], 1u << (bit & 31));
        }
    }
    __syncthreads();

    {
        int n = t >> 2, q = t & 3;
        float accR[25];
        #pragma unroll
        for (int k = 0; k < 25; k++) accR[k] = acc[n*25 + k];
        float inv = 1.f / fmaxf((float)degL[n], 1.f);
        float xr  = xL[n];
        int   cl  = cl1L[n];
        if (q == 0){
            atomicAdd(&cntL[cl], 1);
            atomicAdd(&psx[cl], posx[n]);
            atomicAdd(&psy[cl], posy[n]);
        }
        #pragma unroll
        for (int oo = 0; oo < 8; oo++){
            int o = q*8 + oo;
            float s = 0.f;
            #pragma unroll
            for (int k = 0; k < 25; k++) s += accR[k]*sW[k*32 + o];
            float out = eluf(s*inv + xr*root1[o] + b1[o]);
            atomic_max_f32(&xmL[cl*32 + o], out);
        }
    }
    __syncthreads();

    if (t < 64){
        float cnt = (float)cntL[t];
        float inv = 1.f / fmaxf(cnt, 1.f);
        p1x[t] = psx[t]*inv; p1y[t] = psy[t]*inv;
        pos1g[2*(g*64 + t)]     = p1x[t];
        pos1g[2*(g*64 + t) + 1] = p1y[t];
        nv1[g*64 + t] = (cnt > 0.f) ? 1.f : 0.f;
    }
    __syncthreads();
    for (int i = t; i < 2048; i += 1024){
        int c = i >> 5;
        xp1[g*2048 + i] = (cntL[c] > 0) ? xmL[i] : 0.f;
    }

    if (t < 64) rpre[t] = __popc(bitL[2*t]) + __popc(bitL[2*t+1]);
    __syncthreads();
    for (int d = 1; d < 64; d <<= 1){
        int v = 0;
        if (t < 64 && t >= d) v = rpre[t-d];
        __syncthreads();
        if (t < 64) rpre[t] += v;
        __syncthreads();
    }
    float m2loc = 0.f;
    if (t < 64){
        unsigned int w0 = bitL[2*t], w1 = bitL[2*t+1];
        int dg = __popc(w0) + __popc(w1);
        int baseo = rpre[t] - dg;
        off2s[g*64 + t] = g*4096 + baseo;
        deg2i[g*64 + t] = dg;
        int j = g*4096 + baseo;
        float rx = p1x[t], ry = p1y[t];
        while (w0){
            int b = __ffs(w0) - 1; w0 &= w0 - 1;
            adj2b[j++] = (unsigned char)b;
            m2loc = fmaxf(m2loc, fmaxf(fabsf(p1x[b]-rx), fabsf(p1y[b]-ry)));
        }
        while (w1){
            int b = __ffs(w1) - 1; w1 &= w1 - 1;
            int c = 32 + b;
            adj2b[j++] = (unsigned char)c;
            m2loc = fmaxf(m2loc, fmaxf(fabsf(p1x[c]-rx), fabsf(p1y[c]-ry)));
        }
        mred[t] = m2loc;
    }
    __syncthreads();
    if (t == 0){
        float v = mred[0];
        for (int i = 1; i < 64; i++) v = fmaxf(v, mred[i]);
        atomic_max_pos(m2p, v);
    }
}

// ---------------- conv2: phase-split gather + MFMA GEMM + pool2-node -------------
// 512 threads = 8 waves, 16 clusters/block, 1024 blocks. LDS ~48 KB -> 3 blk/CU.
__global__ __launch_bounds__(512) void k_conv2(
        const int* __restrict__ off2s, const int* __restrict__ deg2i,
        const unsigned char* __restrict__ adj2b, const float* __restrict__ pos1g,
        const float* __restrict__ m2p, const float* __restrict__ xp1,
        const unsigned int* __restrict__ wq2, const unsigned int* __restrict__ rt2q,
        const float* __restrict__ b2, const float* __restrict__ nv1,
        int* __restrict__ cl2, float* cnt2, float* ps2, float* xm2){
    __shared__ unsigned int amu[16*404];   // packed f16 acc (deg-scaled), stride pad +4
    __shared__ float xpL[64*32];
    __shared__ unsigned int xq[16*20];     // packed f16 xp of own 16 clusters
    __shared__ unsigned int wbuf[6][512];  // SoA per-edge packed weights + c
    __shared__ float p1x[64], p1y[64];
    int t = threadIdx.x;
    int g = blockIdx.x >> 2, sub = blockIdx.x & 3;
    for (int i = t; i < 2048; i += 512) xpL[i] = xp1[g*2048 + i];
    if (t < 64){ p1x[t] = pos1g[2*(g*64+t)]; p1y[t] = pos1g[2*(g*64+t)+1]; }
    __syncthreads();
    if (t < 256){
        int m = t >> 4, jj = t & 15;
        int c = sub*16 + m;
        xq[m*20 + jj] = pack2(xpL[c*32 + 2*jj], xpL[c*32 + 2*jj + 1]);
    }
    int grp = t >> 5, lane = t & 31;       // 16 groups x 32 lanes (= feature)
    int rl = sub*16 + grp;
    int r  = g*64 + rl;
    int s0 = off2s[r], nd = deg2i[r];
    float rx = p1x[rl], ry = p1y[rl];
    float invm = 1.0f / (2.0f*(*m2p) + 1e-12f);
    float acc[25];
    #pragma unroll
    for (int k = 0; k < 25; k++) acc[k] = 0.f;
    #pragma unroll
    for (int chunk = 0; chunk < 2; ++chunk){
        int base = chunk*32;
        {   // phase A: thread precomputes weights for edge base+lane of its cluster
            int e = base + lane;
            unsigned int u0=0,u1=0,u2=0,u3=0,u4=0,uc=0;
            if (e < nd){
                int cc = adj2b[s0 + e];
                float vx = ((p1x[cc]-rx)*invm + 0.5f)*4.0f;
                float vy = ((p1y[cc]-ry)*invm + 0.5f)*4.0f;
                float wx[5], wy[5];
                #pragma unroll
                for (int k = 0; k < 5; k++){
                    wx[k] = fmaxf(0.f, 1.f - fabsf(vx - (float)k));
                    wy[k] = fmaxf(0.f, 1.f - fabsf(vy - (float)k));
                }
                u0 = pack2(wx[0], wx[1]); u1 = pack2(wx[2], wx[3]);
                u2 = pack2(wx[4], wy[0]); u3 = pack2(wy[1], wy[2]);
                u4 = pack2(wy[3], wy[4]); uc = (unsigned int)cc;
            }
            wbuf[0][t]=u0; wbuf[1][t]=u1; wbuf[2][t]=u2;
            wbuf[3][t]=u3; wbuf[4][t]=u4; wbuf[5][t]=uc;
        }
        __syncthreads();
        int cnt = min(32, nd - base);
        for (int j = 0; j < cnt; ++j){
            int idx = grp*32 + j;
            float2 a0 = unpk(wbuf[0][idx]);
            float2 a1 = unpk(wbuf[1][idx]);
            float2 a2 = unpk(wbuf[2][idx]);
            float2 a3 = unpk(wbuf[3][idx]);
            float2 a4 = unpk(wbuf[4][idx]);
            int c = (int)wbuf[5][idx];
            float xin = xpL[c*32 + lane];
            float xv[5] = {a0.x*xin, a0.y*xin, a1.x*xin, a1.y*xin, a2.x*xin};
            float yv[5] = {a2.y, a3.x, a3.y, a4.x, a4.y};
            #pragma unroll
            for (int kx = 0; kx < 5; kx++)
                #pragma unroll
                for (int ky = 0; ky < 5; ky++)
                    acc[kx*5+ky] = fmaf(xv[kx], yv[ky], acc[kx*5+ky]);
        }
        __syncthreads();
    }
    {   // scale by 1/deg and pack pairs (features) into amu
        float invd = 1.f / fmaxf((float)nd, 1.f);
        unsigned int* dst = &amu[grp*404];
        #pragma unroll
        for (int k = 0; k < 25; k++){
            float a = acc[k]*invd;
            float o2 = __shfl_xor(a, 1, 64);
            if (!(lane & 1)) dst[k*16 + (lane >> 1)] = pack2(a, o2);
        }
    }
    __syncthreads();
    // MFMA: 4 waves, full K (25 slots + root); direct-register epilogue
    if (t < 256){
        int w = t >> 6, l = t & 63;
        int m = l & 15, kb = l >> 4;
        f32x4 cacc = {0.f, 0.f, 0.f, 0.f};
        for (int i = 0; i < 25; ++i){
            uint4 au = *(const uint4*)&amu[m*404 + i*16 + kb*4];
            uint4 bu = *(const uint4*)&wq2[((w*25 + i)*64 + l)*4];
            cacc = mfma16(au, bu, cacc);
        }
        {
            uint4 au = *(const uint4*)&xq[m*20 + kb*4];
            uint4 bu = *(const uint4*)&rt2q[(w*64 + l)*4];
            cacc = mfma16(au, bu, cacc);
        }
        int o = w*16 + (l & 15);
        float bb = b2[o];
        #pragma unroll
        for (int r_ = 0; r_ < 4; ++r_){
            int mrow = (l >> 4)*4 + r_;
            float val = eluf(cacc[r_] + bb);
            int rl2 = sub*16 + mrow;
            int rr = g*64 + rl2;
            float px = p1x[rl2], py = p1y[rl2];
            int cx = min(max((int)floorf(px*0.125f), 0), 3);
            int cy = min(max((int)floorf(py*0.125f), 0), 3);
            int cl = g*16 + cx*4 + cy;
            float nv = nv1[rr];
            if (o == 0){
                cl2[rr] = cl;
                if (nv > 0.f){
                    atomicAdd(&cnt2[cl], 1.f);
                    atomicAdd(&ps2[2*cl],   px);
                    atomicAdd(&ps2[2*cl+1], py);
                }
            }
            if (nv > 0.f) atomic_max_f32(&xm2[cl*64 + o], val);
        }
    }
}

// ---------------- lvl3: pool2-finish + lvl3 dedup/CSR + m3, per graph ----------------
__global__ __launch_bounds__(256) void k_lvl3(
        const int* __restrict__ off2s, const int* __restrict__ deg2i,
        const unsigned char* __restrict__ adj2b, const int* __restrict__ cl2,
        const float* __restrict__ cnt2, const float* __restrict__ ps2,
        const float* __restrict__ xm2,
        float* __restrict__ xp2, float* __restrict__ pos2g, float* __restrict__ nv2,
        unsigned char* __restrict__ adj3b, int* __restrict__ off3s,
        int* __restrict__ deg3i, float* m3p){
    __shared__ int cl2L[64];
    __shared__ unsigned int bit3[8];
    __shared__ float p2x[16], p2y[16];
    __shared__ int rpre[16];
    int t = threadIdx.x, g = blockIdx.x;
    if (t < 64) cl2L[t] = cl2[g*64 + t] & 15;
    if (t < 8)  bit3[t] = 0u;
    if (t < 16){
        float cnt = cnt2[g*16 + t];
        float inv = 1.f / fmaxf(cnt, 1.f);
        p2x[t] = ps2[2*(g*16+t)]*inv;
        p2y[t] = ps2[2*(g*16+t)+1]*inv;
        pos2g[2*(g*16+t)]   = p2x[t];
        pos2g[2*(g*16+t)+1] = p2y[t];
        nv2[g*16 + t] = (cnt > 0.f) ? 1.f : 0.f;
    }
    for (int i = t; i < 1024; i += 256){
        int c = i >> 6;
        xp2[g*1024 + i] = (cnt2[g*16 + c] > 0.f) ? xm2[g*1024 + i] : 0.f;
    }
    __syncthreads();
    if (t < 64){
        int s0 = off2s[g*64 + t], n = deg2i[g*64 + t];
        int r3 = cl2L[t];
        for (int j = 0; j < n; ++j){
            int c3 = cl2L[adj2b[s0 + j]];
            if (r3 != c3){
                int bit = r3*16 + c3;
                atomicOr(&bit3[bit >> 5], 1u << (bit & 31));
            }
        }
    }
    __syncthreads();
    if (t < 16)
        rpre[t] = __popc((bit3[t >> 1] >> ((t & 1)*16)) & 0xFFFFu);
    __syncthreads();
    for (int d = 1; d < 16; d <<= 1){
        int v = 0;
        if (t < 16 && t >= d) v = rpre[t-d];
        __syncthreads();
        if (t < 16) rpre[t] += v;
        __syncthreads();
    }
    float m3loc = 0.f;
    if (t < 16){
        unsigned int w = (bit3[t >> 1] >> ((t & 1)*16)) & 0xFFFFu;
        int dg = __popc(w);
        int baseo = rpre[t] - dg;
        off3s[g*16 + t] = g*256 + baseo;
        deg3i[g*16 + t] = dg;
        int j = g*256 + baseo;
        float rx = p2x[t], ry = p2y[t];
        while (w){
            int b = __ffs(w) - 1; w &= w - 1;
            adj3b[j++] = (unsigned char)b;
            m3loc = fmaxf(m3loc, fmaxf(fabsf(p2x[b]-rx), fabsf(p2y[b]-ry)));
        }
    }
    BLOCK_MAX_AND_ATOMIC(m3loc, m3p);
}

// ---------------- conv3: phase-split gather + MFMA GEMM ----------------
// 512 threads = 8 waves, 8 clusters/block (half graph), 512 blocks. LDS ~34 KB.
__global__ __launch_bounds__(512) void k_conv3(
        const int* __restrict__ off3s, const int* __restrict__ deg3i,
        const unsigned char* __restrict__ adj3b, const float* __restrict__ pos2g,
        const float* __restrict__ m3p, const float* __restrict__ xp2,
        const unsigned int* __restrict__ wq3, const unsigned int* __restrict__ rt3q,
        const float* __restrict__ b3, float* __restrict__ h3){
    __shared__ unsigned int amu[8*804];
    __shared__ float xpL[16*64];
    __shared__ unsigned int xq[8*36];
    __shared__ unsigned int wbuf[6][128];
    __shared__ float p2x[16], p2y[16];
    int t = threadIdx.x;
    int g = blockIdx.x >> 1, sub = blockIdx.x & 1;
    for (int i = t; i < 1024; i += 512) xpL[i] = xp2[g*1024 + i];
    if (t < 16){ p2x[t] = pos2g[2*(g*16+t)]; p2y[t] = pos2g[2*(g*16+t)+1]; }
    __syncthreads();
    if (t < 256){
        int m = t >> 5, jj = t & 31;
        int c = sub*8 + m;
        xq[m*36 + jj] = pack2(xpL[c*64 + 2*jj], xpL[c*64 + 2*jj + 1]);
    }
    int grp = t >> 6, lane = t & 63;       // 8 groups x 64 lanes (= feature)
    int rl = sub*8 + grp;
    int r  = g*16 + rl;
    int s0 = off3s[r], nd = deg3i[r];      // nd <= 15
    float rx = p2x[rl], ry = p2y[rl];
    float invm = 1.0f / (2.0f*(*m3p) + 1e-12f);
    if (lane < 16){   // phase A
        int e = lane;
        unsigned int u0=0,u1=0,u2=0,u3=0,u4=0,uc=0;
        if (e < nd){
            int cc = adj3b[s0 + e];
            float vx = ((p2x[cc]-rx)*invm + 0.5f)*4.0f;
            float vy = ((p2y[cc]-ry)*invm + 0.5f)*4.0f;
            float wx[5], wy[5];
            #pragma unroll
            for (int k = 0; k < 5; k++){
                wx[k] = fmaxf(0.f, 1.f - fabsf(vx - (float)k));
                wy[k] = fmaxf(0.f, 1.f - fabsf(vy - (float)k));
            }
            u0 = pack2(wx[0], wx[1]); u1 = pack2(wx[2], wx[3]);
            u2 = pack2(wx[4], wy[0]); u3 = pack2(wy[1], wy[2]);
            u4 = pack2(wy[3], wy[4]); uc = (unsigned int)cc;
        }
        int idx = grp*16 + e;
        wbuf[0][idx]=u0; wbuf[1][idx]=u1; wbuf[2][idx]=u2;
        wbuf[3][idx]=u3; wbuf[4][idx]=u4; wbuf[5][idx]=uc;
    }
    __syncthreads();
    float acc[25];
    #pragma unroll
    for (int k = 0; k < 25; k++) acc[k] = 0.f;
    for (int j = 0; j < nd; ++j){
        int idx = grp*16 + j;
        float2 a0 = unpk(wbuf[0][idx]);
        float2 a1 = unpk(wbuf[1][idx]);
        float2 a2 = unpk(wbuf[2][idx]);
        float2 a3 = unpk(wbuf[3][idx]);
        float2 a4 = unpk(wbuf[4][idx]);
        int c = (int)wbuf[5][idx];
        float xin = xpL[c*64 + lane];
        float xv[5] = {a0.x*xin, a0.y*xin, a1.x*xin, a1.y*xin, a2.x*xin};
        float yv[5] = {a2.y, a3.x, a3.y, a4.x, a4.y};
        #pragma unroll
        for (int kx = 0; kx < 5; kx++)
            #pragma unroll
            for (int ky = 0; ky < 5; ky++)
                acc[kx*5+ky] = fmaf(xv[kx], yv[ky], acc[kx*5+ky]);
    }
    {
        float invd = 1.f / fmaxf((float)nd, 1.f);
        unsigned int* dst = &amu[grp*804];
        #pragma unroll
        for (int k = 0; k < 25; k++){
            float a = acc[k]*invd;
            float o2 = __shfl_xor(a, 1, 64);
            if (!(lane & 1)) dst[k*32 + (lane >> 1)] = pack2(a, o2);
        }
    }
    __syncthreads();
    // MFMA: 8 waves = 8 N-tiles (128 outputs), full K; rows 8-15 zero via reg-select
    {
        int w = t >> 6, l = t & 63;
        int m = l & 15, kb = l >> 4;
        f32x4 cacc = {0.f, 0.f, 0.f, 0.f};
        for (int kc = 0; kc < 50; ++kc){
            uint4 au = {0u,0u,0u,0u};
            if (m < 8) au = *(const uint4*)&amu[m*804 + kc*16 + kb*4];
            uint4 bu = *(const uint4*)&wq3[((w*50 + kc)*64 + l)*4];
            cacc = mfma16(au, bu, cacc);
        }
        #pragma unroll
        for (int kc = 0; kc < 2; ++kc){
            uint4 au = {0u,0u,0u,0u};
            if (m < 8) au = *(const uint4*)&xq[m*36 + kc*16 + kb*4];
            uint4 bu = *(const uint4*)&rt3q[((w*2 + kc)*64 + l)*4];
            cacc = mfma16(au, bu, cacc);
        }
        int o = w*16 + (l & 15);
        float bb = b3[o];
        #pragma unroll
        for (int r_ = 0; r_ < 4; ++r_){
            int mrow = (l >> 4)*4 + r_;
            if (mrow < 8)
                h3[(g*16 + sub*8 + mrow)*128 + o] = eluf(cacc[r_] + bb);
        }
    }
}

__global__ void k_readout(const float* __restrict__ h3, const float* __restrict__ nv2,
                          const float* __restrict__ fcw, const float* __restrict__ fcb,
                          float* out){
    int g = blockIdx.x, t = threadIdx.x;     // 128 threads
    __shared__ float gf[128];
    __shared__ float lg[10];
    __shared__ float lse;
    float s = 0.f, cnt = 0.f;
    for (int j = 0; j < 16; j++){
        int c = g*16 + j;
        float nv = nv2[c];
        s += h3[c*128 + t] * nv;
        cnt += nv;
    }
    gf[t] = s / fmaxf(cnt, 1.f);
    __syncthreads();
    if (t < 10){
        float l = fcb[t];
        for (int f = 0; f < 128; f++) l += gf[f]*fcw[f*10 + t];
        lg[t] = l;
    }
    __syncthreads();
    if (t == 0){
        float mx = -INFINITY;
        for (int o = 0; o < 10; o++) mx = fmaxf(mx, lg[o]);
        float ss = 0.f;
        for (int o = 0; o < 10; o++) ss += expf(lg[o] - mx);
        lse = mx + logf(ss);
    }
    __syncthreads();
    if (t < 10) out[g*10 + t] = lg[t] - lse;
}

// ---------------- launch ----------------
extern "C" void kernel_launch(void* const* d_in, const int* in_sizes, int n_in,
                              void* d_out, int out_size, void* d_ws, size_t ws_size,
                              hipStream_t stream){
    const float* x     = (const float*)d_in[0];
    const float* posi  = (const float*)d_in[1];
    const int*   ei    = (const int*)  d_in[2];
    const float* W1    = (const float*)d_in[4];
    const float* root1 = (const float*)d_in[5];
    const float* b1    = (const float*)d_in[6];
    const float* W2    = (const float*)d_in[7];
    const float* root2 = (const float*)d_in[8];
    const float* b2    = (const float*)d_in[9];
    const float* W3    = (const float*)d_in[10];
    const float* root3 = (const float*)d_in[11];
    const float* b3    = (const float*)d_in[12];
    const float* fcw   = (const float*)d_in[13];
    const float* fcb   = (const float*)d_in[14];
    float* out = (float*)d_out;

    char* ws = (char*)d_ws;
    float*          m1    = (float*)(ws + O_SCAL);
    float*          m2    = m1 + 1;
    float*          m3    = m1 + 2;
    int*            gtot  = (int*)  (ws + O_GTOT);
    float*          cnt2  = (float*)(ws + O_CNT2);
    float*          ps2   = (float*)(ws + O_PS2);
    float*          xm2   = (float*)(ws + O_XM2);
    int*            goff  = (int*)  (ws + O_GOFF);
    int*            bb    = (int*)  (ws + O_BB);
    unsigned short* be    = (unsigned short*)(ws + O_BE);
    float*          xp1   = (float*)(ws + O_XP1);
    float*          pos1g = (float*)(ws + O_POS1);
    float*          nv1   = (float*)(ws + O_NV1);
    unsigned char*  adj2b = (unsigned char*)(ws + O_ADJ2);
    int*            off2s = (int*)  (ws + O_OFF2S);
    int*            deg2i = (int*)  (ws + O_DEG2I);
    int*            cl2   = (int*)  (ws + O_CL2);
    float*          xp2   = (float*)(ws + O_XP2);
    float*          pos2g = (float*)(ws + O_POS2);
    float*          nv2   = (float*)(ws + O_NV2);
    unsigned char*  adj3b = (unsigned char*)(ws + O_ADJ3);
    int*            off3s = (int*)  (ws + O_OFF3S);
    int*            deg3i = (int*)  (ws + O_DEG3I);
    float*          h3    = (float*)(ws + O_H3);
    unsigned int*   w2q   = (unsigned int*)(ws + O_W2Q);
    unsigned int*   w3q   = (unsigned int*)(ws + O_W3Q);
    unsigned int*   rt2q  = (unsigned int*)(ws + O_RT2);
    unsigned int*   rt3q  = (unsigned int*)(ws + O_RT3);

    hipMemsetAsync(ws, 0, Z_END, stream);
    hipMemsetAsync(xm2, 0xFF, (size_t)NC2*64*4, stream);   // identity for atomic max

    k_pass1<<<256 + 520, 256, 0, stream>>>(ei, posi, m1, gtot, bb,
                                           W2, W3, root2, root3, w2q, w3q, rt2q, rt3q);
    k_gscan<<<1, 256, 0, stream>>>(gtot, goff);
    k_pass2<<<256, 256, 0, stream>>>(ei, goff, bb, be);

    k_graph1<<<NG, 1024, 0, stream>>>(be, goff, posi, x, m1, W1, root1, b1,
                                      xp1, pos1g, nv1, adj2b, off2s, deg2i, m2);

    k_conv2<<<NC1/16, 512, 0, stream>>>(off2s, deg2i, adj2b, pos1g, m2, xp1,
                                        w2q, rt2q, b2, nv1, cl2, cnt2, ps2, xm2);

    k_lvl3<<<NG, 256, 0, stream>>>(off2s, deg2i, adj2b, cl2, cnt2, ps2, xm2,
                                   xp2, pos2g, nv2, adj3b, off3s, deg3i, m3);

    k_conv3<<<NG*2, 512, 0, stream>>>(off3s, deg3i, adj3b, pos2g, m3, xp2,
                                      w3q, rt3q, b3, h3);

    k_readout<<<256, 128, 0, stream>>>(h3, nv2, fcw, fcb, out);
}

// Round 11
// 246.650 us; speedup vs baseline: 4.5431x; 1.0001x over previous
//
#include <hip/hip_runtime.h>
#include <math.h>

// ---------------- problem constants ----------------
constexpr int NN  = 65536;     // nodes (256 graphs x 256 nodes)
constexpr int EE  = 1048576;   // edges (N * 16)
constexpr int NG  = 256;       // graphs
constexpr int NC1 = 16384;     // clusters after pool1 (256 x 64)
constexpr int NC2 = 4096;      // clusters after pool2 (256 x 16)
constexpr int EPB = EE / 256;  // edges per bucketing block = 4096

// ---------------- workspace layout (bytes) ----------------
// Z region (memset 0 each launch)
constexpr size_t O_SCAL  = 0;                                  // m1,m2,m3
constexpr size_t O_GTOT  = 256;                                // 256 ints
constexpr size_t O_CNT2  = O_GTOT + 1024;                      // NC2 f32
constexpr size_t O_PS2   = O_CNT2 + (size_t)NC2*4;             // NC2*2 f32
constexpr size_t Z_END   = O_PS2  + (size_t)NC2*8;
// xm2: memset 0xFF (identity for both atomic-max paths)
constexpr size_t O_XM2   = Z_END;                              // NC2*64 f32
// fully-written-before-read region
constexpr size_t O_GOFF  = O_XM2  + (size_t)NC2*64*4;          // 257 ints (pad)
constexpr size_t O_BB    = O_GOFF + 1280;                      // 256*256 ints
constexpr size_t O_BE    = O_BB   + (size_t)256*256*4;         // EE ushort
constexpr size_t O_XP1   = O_BE   + (size_t)EE*2;              // NC1*32 f32
constexpr size_t O_POS1  = O_XP1  + (size_t)NC1*32*4;          // NC1*2 f32
constexpr size_t O_NV1   = O_POS1 + (size_t)NC1*8;             // NC1 f32
constexpr size_t O_ADJ2  = O_NV1  + (size_t)NC1*4;             // NG*4096 uchar
constexpr size_t O_OFF2S = O_ADJ2 + (size_t)NG*4096;           // NC1 ints
constexpr size_t O_DEG2I = O_OFF2S+ (size_t)NC1*4;             // NC1 ints
constexpr size_t O_CL2   = O_DEG2I+ (size_t)NC1*4;             // NC1 ints
constexpr size_t O_XP2   = O_CL2  + (size_t)NC1*4;             // NC2*64 f32
constexpr size_t O_POS2  = O_XP2  + (size_t)NC2*64*4;          // NC2*2 f32
constexpr size_t O_NV2   = O_POS2 + (size_t)NC2*8;             // NC2 f32
constexpr size_t O_ADJ3  = O_NV2  + (size_t)NC2*4;             // NG*256 uchar
constexpr size_t O_OFF3S = O_ADJ3 + (size_t)NG*256;            // NC2 ints
constexpr size_t O_DEG3I = O_OFF3S+ (size_t)NC2*4;             // NC2 ints
constexpr size_t O_H3    = O_DEG3I+ (size_t)NC2*4;             // NC2*128 f32
// MFMA-fragment-packed weights (f16 pairs as u32)
constexpr size_t O_W2Q   = O_H3   + (size_t)NC2*128*4;         // 25600 u32
constexpr size_t O_W3Q   = O_W2Q  + 102400;                    // 102400 u32
constexpr size_t O_RT2   = O_W3Q  + 409600;                    // 1024 u32
constexpr size_t O_RT3   = O_RT2  + 4096;                      // 4096 u32

// ---------------- device helpers ----------------
typedef __fp16   pk16x2 __attribute__((ext_vector_type(2)));   // cvt_pkrtz return
typedef _Float16 h16x2  __attribute__((ext_vector_type(2)));
typedef _Float16 f16x8  __attribute__((ext_vector_type(8)));   // MFMA A/B operand
typedef float    f32x4  __attribute__((ext_vector_type(4)));   // MFMA C/D

__device__ __forceinline__ float eluf(float x){ return x > 0.f ? x : expm1f(x); }

__device__ __forceinline__ void atomic_max_pos(float* a, float v){
    atomicMax((unsigned int*)a, __float_as_uint(v));
}
// arbitrary-sign float atomic max; target init = 0xFFFFFFFF or -inf bits
__device__ __forceinline__ void atomic_max_f32(float* a, float v){
    unsigned int b = __float_as_uint(v);
    if (b & 0x80000000u) atomicMin((unsigned int*)a, b);
    else                 atomicMax((int*)a, (int)b);
}

__device__ __forceinline__ unsigned int pack2(float a, float b){
    pk16x2 h = __builtin_amdgcn_cvt_pkrtz(a, b);
    return __builtin_bit_cast(unsigned int, h);
}
__device__ __forceinline__ float2 unpk(unsigned int u){
    h16x2 h = __builtin_bit_cast(h16x2, u);
    return make_float2((float)h[0], (float)h[1]);
}
__device__ __forceinline__ f32x4 mfma16(uint4 a, uint4 b, f32x4 c){
    return __builtin_amdgcn_mfma_f32_16x16x32_f16(
        __builtin_bit_cast(f16x8, a), __builtin_bit_cast(f16x8, b), c, 0, 0, 0);
}

struct Crn { int ix, iy; float fx, fy; };
__device__ __forceinline__ Crn mk_corners(float dx, float dy, float m){
    float inv = 1.0f / (2.0f*m + 1e-12f);
    float vx = (dx*inv + 0.5f) * 4.0f;   // (K1-1)=4
    float vy = (dy*inv + 0.5f) * 4.0f;
    Crn c;
    c.ix = min(max((int)floorf(vx), 0), 3);
    c.iy = min(max((int)floorf(vy), 0), 3);
    c.fx = vx - (float)c.ix;
    c.fy = vy - (float)c.iy;
    return c;
}

#define BLOCK_MAX_AND_ATOMIC(val, dst)                                   \
    {   __shared__ float _s[256];                                        \
        _s[threadIdx.x] = (val); __syncthreads();                        \
        for (int _w = 128; _w > 0; _w >>= 1){                            \
            if (threadIdx.x < _w)                                        \
                _s[threadIdx.x] = fmaxf(_s[threadIdx.x], _s[threadIdx.x+_w]); \
            __syncthreads();                                             \
        }                                                                \
        if (threadIdx.x == 0) atomic_max_pos((dst), _s[0]); }

// ---------------- pass1 (+fused B-fragment weight prep in extra blocks) ----------
__global__ __launch_bounds__(256) void k_pass1(
        const int* __restrict__ ei, const float* __restrict__ pos,
        float* m1, int* gtot, int* bb,
        const float* __restrict__ W2, const float* __restrict__ W3,
        const float* __restrict__ root2, const float* __restrict__ root3,
        unsigned int* __restrict__ w2q, unsigned int* __restrict__ w3q,
        unsigned int* __restrict__ rt2q, unsigned int* __restrict__ rt3q){
    __shared__ int h[256];
    if (blockIdx.x >= 256){
        int idx = (blockIdx.x - 256)*256 + threadIdx.x;
        if (idx < 25600){                                   // W2: 4 tiles x 25 kslots
            int tt = idx/6400, r = idx%6400, i = r/256, r2 = r%256;
            int l = r2>>2, j = r2&3;
            int o = tt*16 + (l&15);
            int Kb = i*32 + (l>>4)*8 + 2*j;
            w2q[idx] = pack2(W2[Kb*64 + o], W2[(Kb+1)*64 + o]);
        } else if (idx < 128000){                           // W3: 8 tiles x 50 chunks
            int d = idx - 25600;
            int tt = d/12800, r = d%12800, kc = r/256, r2 = r%256;
            int l = r2>>2, j = r2&3;
            int o = tt*16 + (l&15);
            int Kb = kc*32 + (l>>4)*8 + 2*j;
            w3q[d] = pack2(W3[Kb*128 + o], W3[(Kb+1)*128 + o]);
        } else if (idx < 129024){                           // root2: 4 tiles x 1 chunk
            int d = idx - 128000;
            int tt = d/256, r2 = d%256, l = r2>>2, j = r2&3;
            int o = tt*16 + (l&15);
            int k = (l>>4)*8 + 2*j;
            rt2q[d] = pack2(root2[k*64 + o], root2[(k+1)*64 + o]);
        } else if (idx < 133120){                           // root3: 8 tiles x 2 chunks
            int d = idx - 129024;
            int tt = d/512, kc = (d/256)&1, r2 = d%256, l = r2>>2, j = r2&3;
            int o = tt*16 + (l&15);
            int k = kc*32 + (l>>4)*8 + 2*j;
            rt3q[d] = pack2(root3[k*128 + o], root3[(k+1)*128 + o]);
        }
        return;
    }
    h[threadIdx.x] = 0; __syncthreads();
    int base = blockIdx.x * EPB;
    float loc = 0.f;
    for (int i = threadIdx.x; i < EPB; i += 256){
        int e = base + i;
        int r = ei[e], c = ei[EE + e];
        float dx = pos[2*c]   - pos[2*r];
        float dy = pos[2*c+1] - pos[2*r+1];
        loc = fmaxf(loc, fmaxf(fabsf(dx), fabsf(dy)));
        atomicAdd(&h[r >> 8], 1);
    }
    __syncthreads();
    bb[blockIdx.x*256 + threadIdx.x] = atomicAdd(&gtot[threadIdx.x], h[threadIdx.x]);
    BLOCK_MAX_AND_ATOMIC(loc, m1);
}

__global__ void k_gscan(const int* __restrict__ gtot, int* goff){
    __shared__ int s[256];
    int t = threadIdx.x;
    int v0 = gtot[t];
    s[t] = v0; __syncthreads();
    for (int d = 1; d < 256; d <<= 1){
        int u = (t >= d) ? s[t-d] : 0;
        __syncthreads();
        s[t] += u;
        __syncthreads();
    }
    goff[t] = s[t] - v0;
    if (t == 255) goff[256] = s[t];
}

__global__ __launch_bounds__(256) void k_pass2(const int* __restrict__ ei,
                                               const int* __restrict__ goff,
                                               const int* __restrict__ bb,
                                               unsigned short* __restrict__ be){
    __shared__ int cur[256];
    cur[threadIdx.x] = 0; __syncthreads();
    int base = blockIdx.x * EPB;
    for (int i = threadIdx.x; i < EPB; i += 256){
        int e = base + i;
        int r = ei[e], c = ei[EE + e];
        int g = r >> 8;
        int l = atomicAdd(&cur[g], 1);
        be[goff[g] + bb[blockIdx.x*256 + g] + l] =
            (unsigned short)((r & 255) | ((c & 255) << 8));
    }
}

// ---------------- graph1: conv1 + pool1 + lvl2 dedup/CSR + m2 (1024 thr) --------
__global__ __launch_bounds__(1024) void k_graph1(
        const unsigned short* __restrict__ be, const int* __restrict__ goff,
        const float* __restrict__ pos, const float* __restrict__ x,
        const float* __restrict__ m1p, const float* __restrict__ W1,
        const float* __restrict__ root1, const float* __restrict__ b1,
        float* __restrict__ xp1, float* __restrict__ pos1g, float* __restrict__ nv1,
        unsigned char* __restrict__ adj2b, int* __restrict__ off2s,
        int* __restrict__ deg2i, float* m2p){
    __shared__ float acc[256*25];
    __shared__ float posx[256], posy[256], xL[256];
    __shared__ int   cl1L[256], degL[256];
    __shared__ float sW[800];
    __shared__ unsigned int bitL[128];
    __shared__ float xmL[64*32];
    __shared__ int   cntL[64];
    __shared__ float psx[64], psy[64];
    __shared__ float p1x[64], p1y[64];
    __shared__ int   rpre[64];
    __shared__ float mred[64];

    int t = threadIdx.x, g = blockIdx.x;
    if (t < 800) sW[t] = W1[t];
    for (int i = t; i < 6400; i += 1024) acc[i] = 0.f;
    if (t < 256){
        float px = pos[2*(g*256 + t)], py = pos[2*(g*256 + t) + 1];
        posx[t] = px; posy[t] = py;
        xL[t]   = x[g*256 + t];
        degL[t] = 0;
        int cx = min(max((int)floorf(px*0.25f), 0), 7);
        int cy = min(max((int)floorf(py*0.25f), 0), 7);
        cl1L[t] = cx*8 + cy;
    }
    if (t < 128) bitL[t] = 0u;
    if (t < 64){ cntL[t] = 0; psx[t] = 0.f; psy[t] = 0.f; }
    for (int i = t; i < 2048; i += 1024) xmL[i] = -INFINITY;
    __syncthreads();

    float mm = *m1p;
    int e1 = goff[g+1];
    for (int p = goff[g] + t; p < e1; p += 1024){
        unsigned int b = be[p];
        int rl = b & 255, cl = (b >> 8) & 255;
        float dx = posx[cl] - posx[rl], dy = posy[cl] - posy[rl];
        Crn cr = mk_corners(dx, dy, mm);
        float xin = xL[cl];
        int ab = rl*25 + cr.ix*5 + cr.iy;
        atomicAdd(&acc[ab],   (1.f-cr.fx)*(1.f-cr.fy)*xin);
        atomicAdd(&acc[ab+1], (1.f-cr.fx)*cr.fy*xin);
        atomicAdd(&acc[ab+5], cr.fx*(1.f-cr.fy)*xin);
        atomicAdd(&acc[ab+6], cr.fx*cr.fy*xin);
        atomicAdd(&degL[rl], 1);
        int r2 = cl1L[rl], c2 = cl1L[cl];
        if (r2 != c2){
            int bit = r2*64 + c2;
            atomicOr(&bitL[bit >> 5], 1u << (bit & 31));
        }
    }
    __syncthreads();

    {
        int n = t >> 2, q = t & 3;
        float accR[25];
        #pragma unroll
        for (int k = 0; k < 25; k++) accR[k] = acc[n*25 + k];
        float inv = 1.f / fmaxf((float)degL[n], 1.f);
        float xr  = xL[n];
        int   cl  = cl1L[n];
        if (q == 0){
            atomicAdd(&cntL[cl], 1);
            atomicAdd(&psx[cl], posx[n]);
            atomicAdd(&psy[cl], posy[n]);
        }
        #pragma unroll
        for (int oo = 0; oo < 8; oo++){
            int o = q*8 + oo;
            float s = 0.f;
            #pragma unroll
            for (int k = 0; k < 25; k++) s += accR[k]*sW[k*32 + o];
            float out = eluf(s*inv + xr*root1[o] + b1[o]);
            atomic_max_f32(&xmL[cl*32 + o], out);
        }
    }
    __syncthreads();

    if (t < 64){
        float cnt = (float)cntL[t];
        float inv = 1.f / fmaxf(cnt, 1.f);
        p1x[t] = psx[t]*inv; p1y[t] = psy[t]*inv;
        pos1g[2*(g*64 + t)]     = p1x[t];
        pos1g[2*(g*64 + t) + 1] = p1y[t];
        nv1[g*64 + t] = (cnt > 0.f) ? 1.f : 0.f;
    }
    __syncthreads();
    for (int i = t; i < 2048; i += 1024){
        int c = i >> 5;
        xp1[g*2048 + i] = (cntL[c] > 0) ? xmL[i] : 0.f;
    }

    if (t < 64) rpre[t] = __popc(bitL[2*t]) + __popc(bitL[2*t+1]);
    __syncthreads();
    for (int d = 1; d < 64; d <<= 1){
        int v = 0;
        if (t < 64 && t >= d) v = rpre[t-d];
        __syncthreads();
        if (t < 64) rpre[t] += v;
        __syncthreads();
    }
    float m2loc = 0.f;
    if (t < 64){
        unsigned int w0 = bitL[2*t], w1 = bitL[2*t+1];
        int dg = __popc(w0) + __popc(w1);
        int baseo = rpre[t] - dg;
        off2s[g*64 + t] = g*4096 + baseo;
        deg2i[g*64 + t] = dg;
        int j = g*4096 + baseo;
        float rx = p1x[t], ry = p1y[t];
        while (w0){
            int b = __ffs(w0) - 1; w0 &= w0 - 1;
            adj2b[j++] = (unsigned char)b;
            m2loc = fmaxf(m2loc, fmaxf(fabsf(p1x[b]-rx), fabsf(p1y[b]-ry)));
        }
        while (w1){
            int b = __ffs(w1) - 1; w1 &= w1 - 1;
            int c = 32 + b;
            adj2b[j++] = (unsigned char)c;
            m2loc = fmaxf(m2loc, fmaxf(fabsf(p1x[c]-rx), fabsf(p1y[c]-ry)));
        }
        mred[t] = m2loc;
    }
    __syncthreads();
    if (t == 0){
        float v = mred[0];
        for (int i = 1; i < 64; i++) v = fmaxf(v, mred[i]);
        atomic_max_pos(m2p, v);
    }
}

// ---------------- conv2: phase-split gather (row-wbuf) + MFMA GEMM + pool2 ------
// 512 threads = 8 waves, 16 clusters/block, 1024 blocks.
__global__ __launch_bounds__(512) void k_conv2(
        const int* __restrict__ off2s, const int* __restrict__ deg2i,
        const unsigned char* __restrict__ adj2b, const float* __restrict__ pos1g,
        const float* __restrict__ m2p, const float* __restrict__ xp1,
        const unsigned int* __restrict__ wq2, const unsigned int* __restrict__ rt2q,
        const float* __restrict__ b2, const float* __restrict__ nv1,
        int* __restrict__ cl2, float* cnt2, float* ps2, float* xm2){
    __shared__ unsigned int amu[16*404];          // packed f16 acc, stride pad +4
    __shared__ float xpL[64*32];
    __shared__ unsigned int xq[16*20];            // packed f16 xp of own 16 clusters
    __shared__ __align__(16) unsigned int wbuf[512][8];  // row-per-edge SoA (32B rows)
    __shared__ float p1x[64], p1y[64];
    int t = threadIdx.x;
    int g = blockIdx.x >> 2, sub = blockIdx.x & 3;
    for (int i = t; i < 2048; i += 512) xpL[i] = xp1[g*2048 + i];
    if (t < 64){ p1x[t] = pos1g[2*(g*64+t)]; p1y[t] = pos1g[2*(g*64+t)+1]; }
    __syncthreads();
    if (t < 256){
        int m = t >> 4, jj = t & 15;
        int c = sub*16 + m;
        xq[m*20 + jj] = pack2(xpL[c*32 + 2*jj], xpL[c*32 + 2*jj + 1]);
    }
    int grp = t >> 5, lane = t & 31;       // 16 groups x 32 lanes (= feature)
    int rl = sub*16 + grp;
    int r  = g*64 + rl;
    int s0 = off2s[r], nd = deg2i[r];
    float rx = p1x[rl], ry = p1y[rl];
    float invm = 1.0f / (2.0f*(*m2p) + 1e-12f);
    float acc[25];
    #pragma unroll
    for (int k = 0; k < 25; k++) acc[k] = 0.f;
    #pragma unroll
    for (int chunk = 0; chunk < 2; ++chunk){
        int base = chunk*32;
        {   // phase A: one thread per edge precomputes packed weights into its row
            int e = base + lane;
            unsigned int u0=0,u1=0,u2=0,u3=0,u4=0,uc=0;
            if (e < nd){
                int cc = adj2b[s0 + e];
                float vx = ((p1x[cc]-rx)*invm + 0.5f)*4.0f;
                float vy = ((p1y[cc]-ry)*invm + 0.5f)*4.0f;
                float wx[5], wy[5];
                #pragma unroll
                for (int k = 0; k < 5; k++){
                    wx[k] = fmaxf(0.f, 1.f - fabsf(vx - (float)k));
                    wy[k] = fmaxf(0.f, 1.f - fabsf(vy - (float)k));
                }
                u0 = pack2(wx[0], wx[1]); u1 = pack2(wx[2], wx[3]);
                u2 = pack2(wx[4], wy[0]); u3 = pack2(wy[1], wy[2]);
                u4 = pack2(wy[3], wy[4]); uc = (unsigned int)cc;
            }
            uint4 wv = {u0, u1, u2, u3};
            *(uint4*)&wbuf[t][0] = wv;
            uint2 wv2 = {u4, uc};
            *(uint2*)&wbuf[t][4] = wv2;
        }
        __syncthreads();
        int cnt = min(32, nd - base);
        int j = 0;
        for (; j + 1 < cnt; j += 2){
            int i0 = grp*32 + j, i1 = i0 + 1;
            uint4 wa = *(const uint4*)&wbuf[i0][0];
            uint2 wb = *(const uint2*)&wbuf[i0][4];
            uint4 wc = *(const uint4*)&wbuf[i1][0];
            uint2 wd = *(const uint2*)&wbuf[i1][4];
            float x0 = xpL[((int)wb.y)*32 + lane];
            float x1 = xpL[((int)wd.y)*32 + lane];
            {
                float2 a0 = unpk(wa.x), a1 = unpk(wa.y), a2 = unpk(wa.z);
                float2 a3 = unpk(wa.w), a4 = unpk(wb.x);
                float xv[5] = {a0.x*x0, a0.y*x0, a1.x*x0, a1.y*x0, a2.x*x0};
                float yv[5] = {a2.y, a3.x, a3.y, a4.x, a4.y};
                #pragma unroll
                for (int kx = 0; kx < 5; kx++)
                    #pragma unroll
                    for (int ky = 0; ky < 5; ky++)
                        acc[kx*5+ky] = fmaf(xv[kx], yv[ky], acc[kx*5+ky]);
            }
            {
                float2 a0 = unpk(wc.x), a1 = unpk(wc.y), a2 = unpk(wc.z);
                float2 a3 = unpk(wc.w), a4 = unpk(wd.x);
                float xv[5] = {a0.x*x1, a0.y*x1, a1.x*x1, a1.y*x1, a2.x*x1};
                float yv[5] = {a2.y, a3.x, a3.y, a4.x, a4.y};
                #pragma unroll
                for (int kx = 0; kx < 5; kx++)
                    #pragma unroll
                    for (int ky = 0; ky < 5; ky++)
                        acc[kx*5+ky] = fmaf(xv[kx], yv[ky], acc[kx*5+ky]);
            }
        }
        if (j < cnt){
            int i0 = grp*32 + j;
            uint4 wa = *(const uint4*)&wbuf[i0][0];
            uint2 wb = *(const uint2*)&wbuf[i0][4];
            float x0 = xpL[((int)wb.y)*32 + lane];
            float2 a0 = unpk(wa.x), a1 = unpk(wa.y), a2 = unpk(wa.z);
            float2 a3 = unpk(wa.w), a4 = unpk(wb.x);
            float xv[5] = {a0.x*x0, a0.y*x0, a1.x*x0, a1.y*x0, a2.x*x0};
            float yv[5] = {a2.y, a3.x, a3.y, a4.x, a4.y};
            #pragma unroll
            for (int kx = 0; kx < 5; kx++)
                #pragma unroll
                for (int ky = 0; ky < 5; ky++)
                    acc[kx*5+ky] = fmaf(xv[kx], yv[ky], acc[kx*5+ky]);
        }
        __syncthreads();
    }
    {   // scale by 1/deg and pack pairs (features) into amu
        float invd = 1.f / fmaxf((float)nd, 1.f);
        unsigned int* dst = &amu[grp*404];
        #pragma unroll
        for (int k = 0; k < 25; k++){
            float a = acc[k]*invd;
            float o2 = __shfl_xor(a, 1, 64);
            if (!(lane & 1)) dst[k*16 + (lane >> 1)] = pack2(a, o2);
        }
    }
    __syncthreads();
    // MFMA: 4 waves, full K (25 slots + root); direct-register epilogue
    if (t < 256){
        int w = t >> 6, l = t & 63;
        int m = l & 15, kb = l >> 4;
        f32x4 cacc = {0.f, 0.f, 0.f, 0.f};
        for (int i = 0; i < 25; ++i){
            uint4 au = *(const uint4*)&amu[m*404 + i*16 + kb*4];
            uint4 bu = *(const uint4*)&wq2[((w*25 + i)*64 + l)*4];
            cacc = mfma16(au, bu, cacc);
        }
        {
            uint4 au = *(const uint4*)&xq[m*20 + kb*4];
            uint4 bu = *(const uint4*)&rt2q[(w*64 + l)*4];
            cacc = mfma16(au, bu, cacc);
        }
        int o = w*16 + (l & 15);
        float bb = b2[o];
        #pragma unroll
        for (int r_ = 0; r_ < 4; ++r_){
            int mrow = (l >> 4)*4 + r_;
            float val = eluf(cacc[r_] + bb);
            int rl2 = sub*16 + mrow;
            int rr = g*64 + rl2;
            float px = p1x[rl2], py = p1y[rl2];
            int cx = min(max((int)floorf(px*0.125f), 0), 3);
            int cy = min(max((int)floorf(py*0.125f), 0), 3);
            int cl = g*16 + cx*4 + cy;
            float nv = nv1[rr];
            if (o == 0){
                cl2[rr] = cl;
                if (nv > 0.f){
                    atomicAdd(&cnt2[cl], 1.f);
                    atomicAdd(&ps2[2*cl],   px);
                    atomicAdd(&ps2[2*cl+1], py);
                }
            }
            if (nv > 0.f) atomic_max_f32(&xm2[cl*64 + o], val);
        }
    }
}

// ---------------- lvl3: pool2-finish + lvl3 dedup/CSR + m3, per graph ----------------
__global__ __launch_bounds__(256) void k_lvl3(
        const int* __restrict__ off2s, const int* __restrict__ deg2i,
        const unsigned char* __restrict__ adj2b, const int* __restrict__ cl2,
        const float* __restrict__ cnt2, const float* __restrict__ ps2,
        const float* __restrict__ xm2,
        float* __restrict__ xp2, float* __restrict__ pos2g, float* __restrict__ nv2,
        unsigned char* __restrict__ adj3b, int* __restrict__ off3s,
        int* __restrict__ deg3i, float* m3p){
    __shared__ int cl2L[64];
    __shared__ unsigned int bit3[8];
    __shared__ float p2x[16], p2y[16];
    __shared__ int rpre[16];
    int t = threadIdx.x, g = blockIdx.x;
    if (t < 64) cl2L[t] = cl2[g*64 + t] & 15;
    if (t < 8)  bit3[t] = 0u;
    if (t < 16){
        float cnt = cnt2[g*16 + t];
        float inv = 1.f / fmaxf(cnt, 1.f);
        p2x[t] = ps2[2*(g*16+t)]*inv;
        p2y[t] = ps2[2*(g*16+t)+1]*inv;
        pos2g[2*(g*16+t)]   = p2x[t];
        pos2g[2*(g*16+t)+1] = p2y[t];
        nv2[g*16 + t] = (cnt > 0.f) ? 1.f : 0.f;
    }
    for (int i = t; i < 1024; i += 256){
        int c = i >> 6;
        xp2[g*1024 + i] = (cnt2[g*16 + c] > 0.f) ? xm2[g*1024 + i] : 0.f;
    }
    __syncthreads();
    if (t < 64){
        int s0 = off2s[g*64 + t], n = deg2i[g*64 + t];
        int r3 = cl2L[t];
        for (int j = 0; j < n; ++j){
            int c3 = cl2L[adj2b[s0 + j]];
            if (r3 != c3){
                int bit = r3*16 + c3;
                atomicOr(&bit3[bit >> 5], 1u << (bit & 31));
            }
        }
    }
    __syncthreads();
    if (t < 16)
        rpre[t] = __popc((bit3[t >> 1] >> ((t & 1)*16)) & 0xFFFFu);
    __syncthreads();
    for (int d = 1; d < 16; d <<= 1){
        int v = 0;
        if (t < 16 && t >= d) v = rpre[t-d];
        __syncthreads();
        if (t < 16) rpre[t] += v;
        __syncthreads();
    }
    float m3loc = 0.f;
    if (t < 16){
        unsigned int w = (bit3[t >> 1] >> ((t & 1)*16)) & 0xFFFFu;
        int dg = __popc(w);
        int baseo = rpre[t] - dg;
        off3s[g*16 + t] = g*256 + baseo;
        deg3i[g*16 + t] = dg;
        int j = g*256 + baseo;
        float rx = p2x[t], ry = p2y[t];
        while (w){
            int b = __ffs(w) - 1; w &= w - 1;
            adj3b[j++] = (unsigned char)b;
            m3loc = fmaxf(m3loc, fmaxf(fabsf(p2x[b]-rx), fabsf(p2y[b]-ry)));
        }
    }
    BLOCK_MAX_AND_ATOMIC(m3loc, m3p);
}

// ---------------- conv3: phase-split gather (row-wbuf) + MFMA GEMM ----------------
// 512 threads = 8 waves, 8 clusters/block (half graph), 512 blocks.
__global__ __launch_bounds__(512) void k_conv3(
        const int* __restrict__ off3s, const int* __restrict__ deg3i,
        const unsigned char* __restrict__ adj3b, const float* __restrict__ pos2g,
        const float* __restrict__ m3p, const float* __restrict__ xp2,
        const unsigned int* __restrict__ wq3, const unsigned int* __restrict__ rt3q,
        const float* __restrict__ b3, float* __restrict__ h3){
    __shared__ unsigned int amu[8*804];
    __shared__ float xpL[16*64];
    __shared__ unsigned int xq[8*36];
    __shared__ __align__(16) unsigned int wbuf[128][8];
    __shared__ float p2x[16], p2y[16];
    int t = threadIdx.x;
    int g = blockIdx.x >> 1, sub = blockIdx.x & 1;
    for (int i = t; i < 1024; i += 512) xpL[i] = xp2[g*1024 + i];
    if (t < 16){ p2x[t] = pos2g[2*(g*16+t)]; p2y[t] = pos2g[2*(g*16+t)+1]; }
    __syncthreads();
    if (t < 256){
        int m = t >> 5, jj = t & 31;
        int c = sub*8 + m;
        xq[m*36 + jj] = pack2(xpL[c*64 + 2*jj], xpL[c*64 + 2*jj + 1]);
    }
    int grp = t >> 6, lane = t & 63;       // 8 groups x 64 lanes (= feature)
    int rl = sub*8 + grp;
    int r  = g*16 + rl;
    int s0 = off3s[r], nd = deg3i[r];      // nd <= 15
    float rx = p2x[rl], ry = p2y[rl];
    float invm = 1.0f / (2.0f*(*m3p) + 1e-12f);
    if (lane < 16){   // phase A
        int e = lane;
        unsigned int u0=0,u1=0,u2=0,u3=0,u4=0,uc=0;
        if (e < nd){
            int cc = adj3b[s0 + e];
            float vx = ((p2x[cc]-rx)*invm + 0.5f)*4.0f;
            float vy = ((p2y[cc]-ry)*invm + 0.5f)*4.0f;
            float wx[5], wy[5];
            #pragma unroll
            for (int k = 0; k < 5; k++){
                wx[k] = fmaxf(0.f, 1.f - fabsf(vx - (float)k));
                wy[k] = fmaxf(0.f, 1.f - fabsf(vy - (float)k));
            }
            u0 = pack2(wx[0], wx[1]); u1 = pack2(wx[2], wx[3]);
            u2 = pack2(wx[4], wy[0]); u3 = pack2(wy[1], wy[2]);
            u4 = pack2(wy[3], wy[4]); uc = (unsigned int)cc;
        }
        int idx = grp*16 + e;
        uint4 wv = {u0, u1, u2, u3};
        *(uint4*)&wbuf[idx][0] = wv;
        uint2 wv2 = {u4, uc};
        *(uint2*)&wbuf[idx][4] = wv2;
    }
    __syncthreads();
    float acc[25];
    #pragma unroll
    for (int k = 0; k < 25; k++) acc[k] = 0.f;
    int j = 0;
    for (; j + 1 < nd; j += 2){
        int i0 = grp*16 + j, i1 = i0 + 1;
        uint4 wa = *(const uint4*)&wbuf[i0][0];
        uint2 wb = *(const uint2*)&wbuf[i0][4];
        uint4 wc = *(const uint4*)&wbuf[i1][0];
        uint2 wd = *(const uint2*)&wbuf[i1][4];
        float x0 = xpL[((int)wb.y)*64 + lane];
        float x1 = xpL[((int)wd.y)*64 + lane];
        {
            float2 a0 = unpk(wa.x), a1 = unpk(wa.y), a2 = unpk(wa.z);
            float2 a3 = unpk(wa.w), a4 = unpk(wb.x);
            float xv[5] = {a0.x*x0, a0.y*x0, a1.x*x0, a1.y*x0, a2.x*x0};
            float yv[5] = {a2.y, a3.x, a3.y, a4.x, a4.y};
            #pragma unroll
            for (int kx = 0; kx < 5; kx++)
                #pragma unroll
                for (int ky = 0; ky < 5; ky++)
                    acc[kx*5+ky] = fmaf(xv[kx], yv[ky], acc[kx*5+ky]);
        }
        {
            float2 a0 = unpk(wc.x), a1 = unpk(wc.y), a2 = unpk(wc.z);
            float2 a3 = unpk(wc.w), a4 = unpk(wd.x);
            float xv[5] = {a0.x*x1, a0.y*x1, a1.x*x1, a1.y*x1, a2.x*x1};
            float yv[5] = {a2.y, a3.x, a3.y, a4.x, a4.y};
            #pragma unroll
            for (int kx = 0; kx < 5; kx++)
                #pragma unroll
                for (int ky = 0; ky < 5; ky++)
                    acc[kx*5+ky] = fmaf(xv[kx], yv[ky], acc[kx*5+ky]);
        }
    }
    if (j < nd){
        int i0 = grp*16 + j;
        uint4 wa = *(const uint4*)&wbuf[i0][0];
        uint2 wb = *(const uint2*)&wbuf[i0][4];
        float x0 = xpL[((int)wb.y)*64 + lane];
        float2 a0 = unpk(wa.x), a1 = unpk(wa.y), a2 = unpk(wa.z);
        float2 a3 = unpk(wa.w), a4 = unpk(wb.x);
        float xv[5] = {a0.x*x0, a0.y*x0, a1.x*x0, a1.y*x0, a2.x*x0};
        float yv[5] = {a2.y, a3.x, a3.y, a4.x, a4.y};
        #pragma unroll
        for (int kx = 0; kx < 5; kx++)
            #pragma unroll
            for (int ky = 0; ky < 5; ky++)
                acc[kx*5+ky] = fmaf(xv[kx], yv[ky], acc[kx*5+ky]);
    }
    {
        float invd = 1.f / fmaxf((float)nd, 1.f);
        unsigned int* dst = &amu[grp*804];
        #pragma unroll
        for (int k = 0; k < 25; k++){
            float a = acc[k]*invd;
            float o2 = __shfl_xor(a, 1, 64);
            if (!(lane & 1)) dst[k*32 + (lane >> 1)] = pack2(a, o2);
        }
    }
    __syncthreads();
    // MFMA: 8 waves = 8 N-tiles (128 outputs), full K; rows 8-15 zero via reg-select
    {
        int w = t >> 6, l = t & 63;
        int m = l & 15, kb = l >> 4;
        f32x4 cacc = {0.f, 0.f, 0.f, 0.f};
        for (int kc = 0; kc < 50; ++kc){
            uint4 au = {0u,0u,0u,0u};
            if (m < 8) au = *(const uint4*)&amu[m*804 + kc*16 + kb*4];
            uint4 bu = *(const uint4*)&wq3[((w*50 + kc)*64 + l)*4];
            cacc = mfma16(au, bu, cacc);
        }
        #pragma unroll
        for (int kc = 0; kc < 2; ++kc){
            uint4 au = {0u,0u,0u,0u};
            if (m < 8) au = *(const uint4*)&xq[m*36 + kc*16 + kb*4];
            uint4 bu = *(const uint4*)&rt3q[((w*2 + kc)*64 + l)*4];
            cacc = mfma16(au, bu, cacc);
        }
        int o = w*16 + (l & 15);
        float bb = b3[o];
        #pragma unroll
        for (int r_ = 0; r_ < 4; ++r_){
            int mrow = (l >> 4)*4 + r_;
            if (mrow < 8)
                h3[(g*16 + sub*8 + mrow)*128 + o] = eluf(cacc[r_] + bb);
        }
    }
}

__global__ void k_readout(const float* __restrict__ h3, const float* __restrict__ nv2,
                          const float* __restrict__ fcw, const float* __restrict__ fcb,
                          float* out){
    int g = blockIdx.x, t = threadIdx.x;     // 128 threads
    __shared__ float gf[128];
    __shared__ float lg[10];
    __shared__ float lse;
    float s = 0.f, cnt = 0.f;
    for (int j = 0; j < 16; j++){
        int c = g*16 + j;
        float nv = nv2[c];
        s += h3[c*128 + t] * nv;
        cnt += nv;
    }
    gf[t] = s / fmaxf(cnt, 1.f);
    __syncthreads();
    if (t < 10){
        float l = fcb[t];
        for (int f = 0; f < 128; f++) l += gf[f]*fcw[f*10 + t];
        lg[t] = l;
    }
    __syncthreads();
    if (t == 0){
        float mx = -INFINITY;
        for (int o = 0; o < 10; o++) mx = fmaxf(mx, lg[o]);
        float ss = 0.f;
        for (int o = 0; o < 10; o++) ss += expf(lg[o] - mx);
        lse = mx + logf(ss);
    }
    __syncthreads();
    if (t < 10) out[g*10 + t] = lg[t] - lse;
}

// ---------------- launch ----------------
extern "C" void kernel_launch(void* const* d_in, const int* in_sizes, int n_in,
                              void* d_out, int out_size, void* d_ws, size_t ws_size,
                              hipStream_t stream){
    const float* x     = (const float*)d_in[0];
    const float* posi  = (const float*)d_in[1];
    const int*   ei    = (const int*)  d_in[2];
    const float* W1    = (const float*)d_in[4];
    const float* root1 = (const float*)d_in[5];
    const float* b1    = (const float*)d_in[6];
    const float* W2    = (const float*)d_in[7];
    const float* root2 = (const float*)d_in[8];
    const float* b2    = (const float*)d_in[9];
    const float* W3    = (const float*)d_in[10];
    const float* root3 = (const float*)d_in[11];
    const float* b3    = (const float*)d_in[12];
    const float* fcw   = (const float*)d_in[13];
    const float* fcb   = (const float*)d_in[14];
    float* out = (float*)d_out;

    char* ws = (char*)d_ws;
    float*          m1    = (float*)(ws + O_SCAL);
    float*          m2    = m1 + 1;
    float*          m3    = m1 + 2;
    int*            gtot  = (int*)  (ws + O_GTOT);
    float*          cnt2  = (float*)(ws + O_CNT2);
    float*          ps2   = (float*)(ws + O_PS2);
    float*          xm2   = (float*)(ws + O_XM2);
    int*            goff  = (int*)  (ws + O_GOFF);
    int*            bb    = (int*)  (ws + O_BB);
    unsigned short* be    = (unsigned short*)(ws + O_BE);
    float*          xp1   = (float*)(ws + O_XP1);
    float*          pos1g = (float*)(ws + O_POS1);
    float*          nv1   = (float*)(ws + O_NV1);
    unsigned char*  adj2b = (unsigned char*)(ws + O_ADJ2);
    int*            off2s = (int*)  (ws + O_OFF2S);
    int*            deg2i = (int*)  (ws + O_DEG2I);
    int*            cl2   = (int*)  (ws + O_CL2);
    float*          xp2   = (float*)(ws + O_XP2);
    float*          pos2g = (float*)(ws + O_POS2);
    float*          nv2   = (float*)(ws + O_NV2);
    unsigned char*  adj3b = (unsigned char*)(ws + O_ADJ3);
    int*            off3s = (int*)  (ws + O_OFF3S);
    int*            deg3i = (int*)  (ws + O_DEG3I);
    float*          h3    = (float*)(ws + O_H3);
    unsigned int*   w2q   = (unsigned int*)(ws + O_W2Q);
    unsigned int*   w3q   = (unsigned int*)(ws + O_W3Q);
    unsigned int*   rt2q  = (unsigned int*)(ws + O_RT2);
    unsigned int*   rt3q  = (unsigned int*)(ws + O_RT3);

    hipMemsetAsync(ws, 0, Z_END, stream);
    hipMemsetAsync(xm2, 0xFF, (size_t)NC2*64*4, stream);   // identity for atomic max

    k_pass1<<<256 + 520, 256, 0, stream>>>(ei, posi, m1, gtot, bb,
                                           W2, W3, root2, root3, w2q, w3q, rt2q, rt3q);
    k_gscan<<<1, 256, 0, stream>>>(gtot, goff);
    k_pass2<<<256, 256, 0, stream>>>(ei, goff, bb, be);

    k_graph1<<<NG, 1024, 0, stream>>>(be, goff, posi, x, m1, W1, root1, b1,
                                      xp1, pos1g, nv1, adj2b, off2s, deg2i, m2);

    k_conv2<<<NC1/16, 512, 0, stream>>>(off2s, deg2i, adj2b, pos1g, m2, xp1,
                                        w2q, rt2q, b2, nv1, cl2, cnt2, ps2, xm2);

    k_lvl3<<<NG, 256, 0, stream>>>(off2s, deg2i, adj2b, cl2, cnt2, ps2, xm2,
                                   xp2, pos2g, nv2, adj3b, off3s, deg3i, m3);

    k_conv3<<<NG*2, 512, 0, stream>>>(off3s, deg3i, adj3b, pos2g, m3, xp2,
                                      w3q, rt3q, b3, h3);

    k_readout<<<256, 128, 0, stream>>>(h3, nv2, fcw, fcb, out);
}